// Round 2
// baseline (607.443 us; speedup 1.0000x reference)
//
#include <hip/hip_runtime.h>

typedef short bf16x8 __attribute__((ext_vector_type(8)));
typedef float f32x4 __attribute__((ext_vector_type(4)));
typedef unsigned int u32x4 __attribute__((ext_vector_type(4)));
typedef unsigned short u16;

#define MFMA(a, b, c) __builtin_amdgcn_mfma_f32_16x16x32_bf16(a, b, c, 0, 0, 0)

// ---------- helpers ----------
__device__ __forceinline__ u16 f2b(float f) {
    union { float f; unsigned u; } x{f};
    unsigned r = (x.u + 0x7FFFu + ((x.u >> 16) & 1u)) >> 16;
    return (u16)r;
}
__device__ __forceinline__ float b2f(u16 h) {
    union { unsigned u; float f; } x{((unsigned)h) << 16};
    return x.f;
}
__device__ __forceinline__ float red64_sum(float v) {
#pragma unroll
    for (int m = 1; m < 64; m <<= 1) v += __shfl_xor(v, m, 64);
    return v;
}
__device__ __forceinline__ float red16_sum(float v) {
#pragma unroll
    for (int m = 1; m < 16; m <<= 1) v += __shfl_xor(v, m, 64);
    return v;
}
__device__ __forceinline__ float red16_max(float v) {
#pragma unroll
    for (int m = 1; m < 16; m <<= 1) v = fmaxf(v, __shfl_xor(v, m, 64));
    return v;
}

// dims: B=4, C=64, N=8, V=32, W=32, D=256 ; BN=32, S=1024, tokens M=32768

// ---------- K0: weight convert/transpose to bf16 ----------
__global__ __launch_bounds__(256) void wconv_kernel(
    const float* __restrict__ W1, const float* __restrict__ W2,
    const float* __restrict__ Wo, u16* __restrict__ w1T,
    u16* __restrict__ w2T, u16* __restrict__ woT) {
    int id = blockIdx.x * 256 + threadIdx.x;
    if (id < 131072) {                       // W1: (256,512) -> (512,256)
        int n = id >> 8, k = id & 255;
        w1T[id] = f2b(W1[k * 512 + n]);
    } else if (id < 262144) {                // W2: (512,256) -> (256,512)
        int j = id - 131072;
        int n = j >> 9, k = j & 511;
        w2T[j] = f2b(W2[k * 256 + n]);
    } else if (id < 278528) {                // W_out: (256,64) -> (64,256)
        int j = id - 262144;
        int n = j >> 8, k = j & 255;
        woT[j] = f2b(Wo[k * 64 + n]);
    }
}

// ---------- K1: token gather + Q/KV projection + shared LN ----------
// qh/ql, kh/kl: (BN*S, 256) bf16 hi/lo split.  vT: (BN, 256, 1024) bf16.
__global__ __launch_bounds__(256) void proj_kernel(
    const float* __restrict__ lf, const float* __restrict__ hf,
    const float* __restrict__ Win, const float* __restrict__ Wkv,
    const float* __restrict__ gamma, const float* __restrict__ beta,
    u16* __restrict__ qh_, u16* __restrict__ ql_,
    u16* __restrict__ kh_, u16* __restrict__ kl_, u16* __restrict__ vT) {
    __shared__ float lq[512], lk[512];   // [c][t]: addr = c*8+t
    __shared__ float red[4][8][4];
    const int tid = threadIdx.x;
    const int g0 = blockIdx.x * 8;           // first token index
    const int bn = g0 >> 10, s0 = g0 & 1023;
    const int b = bn >> 3, n = bn & 7;
    const size_t base = (size_t)b * 524288 + (size_t)n * 1024 + s0;
    {
        int c = tid >> 3, t = tid & 7;
        lq[tid]       = lf[base + (size_t)c * 8192 + t];
        lk[tid]       = hf[base + (size_t)c * 8192 + t];
        lq[tid + 256] = lf[base + (size_t)(c + 32) * 8192 + t];
        lk[tid + 256] = hf[base + (size_t)(c + 32) * 8192 + t];
    }
    __syncthreads();
    const int d = tid;
    float aq[8] = {}, ak[8] = {}, av[8] = {};
#pragma unroll 4
    for (int c = 0; c < 64; c++) {
        float wq = Win[c * 256 + d];
        float wk = Wkv[c * 512 + d];
        float wv = Wkv[c * 512 + 256 + d];
#pragma unroll
        for (int t = 0; t < 8; t++) {
            aq[t] = fmaf(lq[c * 8 + t], wq, aq[t]);
            ak[t] = fmaf(lk[c * 8 + t], wk, ak[t]);
            av[t] = fmaf(lk[c * 8 + t], wv, av[t]);
        }
    }
    const int wave = tid >> 6, lane = tid & 63;
#pragma unroll
    for (int t = 0; t < 8; t++) {
        float s1q = red64_sum(aq[t]);
        float s2q = red64_sum(aq[t] * aq[t]);
        float s1k = red64_sum(ak[t]);
        float s2k = red64_sum(ak[t] * ak[t]);
        if (lane == 0) {
            red[wave][t][0] = s1q; red[wave][t][1] = s2q;
            red[wave][t][2] = s1k; red[wave][t][3] = s2k;
        }
    }
    __syncthreads();
    const float gd = gamma[d], bd = beta[d];
    u16 vs[8];
#pragma unroll
    for (int t = 0; t < 8; t++) {
        float s1q = red[0][t][0] + red[1][t][0] + red[2][t][0] + red[3][t][0];
        float s2q = red[0][t][1] + red[1][t][1] + red[2][t][1] + red[3][t][1];
        float s1k = red[0][t][2] + red[1][t][2] + red[2][t][2] + red[3][t][2];
        float s2k = red[0][t][3] + red[1][t][3] + red[2][t][3] + red[3][t][3];
        float mq = s1q * (1.f / 256.f);
        float vq = s2q * (1.f / 256.f) - mq * mq;
        float rq = rsqrtf(vq + 1e-5f);
        float mk = s1k * (1.f / 256.f);
        float vk = s2k * (1.f / 256.f) - mk * mk;
        float rk = rsqrtf(vk + 1e-5f);
        size_t idx = (size_t)(g0 + t) * 256 + d;
        float qv = (aq[t] - mq) * rq * gd + bd;
        float kv = (ak[t] - mk) * rk * gd + bd;
        u16 qhv = f2b(qv), khv = f2b(kv);
        qh_[idx] = qhv;
        ql_[idx] = f2b(qv - b2f(qhv));
        kh_[idx] = khv;
        kl_[idx] = f2b(kv - b2f(khv));
        vs[t] = f2b(av[t]);
    }
    u32x4 pk;
    pk[0] = (unsigned)vs[0] | ((unsigned)vs[1] << 16);
    pk[1] = (unsigned)vs[2] | ((unsigned)vs[3] << 16);
    pk[2] = (unsigned)vs[4] | ((unsigned)vs[5] << 16);
    pk[3] = (unsigned)vs[6] | ((unsigned)vs[7] << 16);
    *(u32x4*)(vT + ((size_t)bn * 256 + d) * 1024 + s0) = pk;
}

// ---------- K2: causal flash attention (split-precision QK) + fused LN ----------
// grid (16 qtiles, 32 bn), 256 threads = 4 waves, each wave = 16 q rows.
__global__ __launch_bounds__(256) void attn_kernel(
    const u16* __restrict__ qh_, const u16* __restrict__ ql_,
    const u16* __restrict__ kh_, const u16* __restrict__ kl_,
    const u16* __restrict__ vT, const float* __restrict__ g2,
    const float* __restrict__ b2, u16* __restrict__ lnatt) {
    __shared__ __align__(16) u16 Pl[4][16][32];
    __shared__ float sg[256], sb[256];
    const int tid = threadIdx.x;
    sg[tid] = g2[tid];
    sb[tid] = b2[tid];
    const int wave = tid >> 6, lane = tid & 63, lr = lane & 15, lg = lane >> 4;
    const int bn = blockIdx.y, qt = blockIdx.x;
    const int qr0 = qt * 64 + wave * 16;
    bf16x8 qh[8], ql[8];
    {
        const size_t off = ((size_t)(bn * 1024 + qr0 + lr)) * 256 + lg * 8;
#pragma unroll
        for (int ck = 0; ck < 8; ck++) {
            qh[ck] = *(const bf16x8*)(qh_ + off + ck * 32);
            ql[ck] = *(const bf16x8*)(ql_ + off + ck * 32);
        }
    }
    f32x4 o[16];
#pragma unroll
    for (int i = 0; i < 16; i++) o[i] = (f32x4){0.f, 0.f, 0.f, 0.f};
    float m[4] = {-INFINITY, -INFINITY, -INFINITY, -INFINITY};
    float l[4] = {0.f, 0.f, 0.f, 0.f};
    const int nk = qt * 2 + 2;
    for (int kt = 0; kt < nk; kt++) {
        f32x4 sc0 = (f32x4){0.f, 0.f, 0.f, 0.f};
        f32x4 sc1 = (f32x4){0.f, 0.f, 0.f, 0.f};
        const size_t koff = ((size_t)(bn * 1024 + kt * 32 + lr)) * 256 + lg * 8;
#pragma unroll
        for (int ck = 0; ck < 8; ck++) {
            bf16x8 kh0 = *(const bf16x8*)(kh_ + koff + ck * 32);
            bf16x8 kh1 = *(const bf16x8*)(kh_ + koff + 4096 + ck * 32);
            bf16x8 kl0 = *(const bf16x8*)(kl_ + koff + ck * 32);
            bf16x8 kl1 = *(const bf16x8*)(kl_ + koff + 4096 + ck * 32);
            sc0 = MFMA(qh[ck], kh0, sc0);
            sc1 = MFMA(qh[ck], kh1, sc1);
            sc0 = MFMA(ql[ck], kh0, sc0);
            sc1 = MFMA(ql[ck], kh1, sc1);
            sc0 = MFMA(qh[ck], kl0, sc0);
            sc1 = MFMA(qh[ck], kl1, sc1);
        }
        float scl[4];
#pragma unroll
        for (int r = 0; r < 4; r++) {
            int qi = qr0 + lg * 4 + r;
            float s0v = (kt * 32 + lr > qi) ? -1e30f : sc0[r];
            float s1v = (kt * 32 + 16 + lr > qi) ? -1e30f : sc1[r];
            float tm = red16_max(fmaxf(s0v, s1v));
            float mn = fmaxf(m[r], tm);
            float esc = __expf(m[r] - mn);
            float p0 = __expf(s0v - mn);
            float p1 = __expf(s1v - mn);
            float ts = red16_sum(p0 + p1);
            l[r] = l[r] * esc + ts;
            m[r] = mn;
            scl[r] = esc;
            Pl[wave][lg * 4 + r][lr] = f2b(p0);
            Pl[wave][lg * 4 + r][16 + lr] = f2b(p1);
        }
#pragma unroll
        for (int f = 0; f < 16; f++) {
            f32x4 t = o[f];
            t[0] *= scl[0]; t[1] *= scl[1]; t[2] *= scl[2]; t[3] *= scl[3];
            o[f] = t;
        }
        bf16x8 pa = *(const bf16x8*)&Pl[wave][lr][lg * 8];
        const u16* vp = vT + ((size_t)(bn * 256 + lr)) * 1024 + kt * 32 + lg * 8;
#pragma unroll
        for (int db = 0; db < 16; db++) {
            bf16x8 vf = *(const bf16x8*)(vp + (size_t)db * 16 * 1024);
            o[db] = MFMA(pa, vf, o[db]);
        }
    }
    float inv[4];
#pragma unroll
    for (int r = 0; r < 4; r++) inv[r] = 1.f / l[r];
#pragma unroll
    for (int f = 0; f < 16; f++) {
        o[f][0] *= inv[0]; o[f][1] *= inv[1]; o[f][2] *= inv[2]; o[f][3] *= inv[3];
    }
#pragma unroll
    for (int r = 0; r < 4; r++) {
        float s1 = 0.f, s2 = 0.f;
#pragma unroll
        for (int f = 0; f < 16; f++) { float x = o[f][r]; s1 += x; s2 += x * x; }
        s1 = red16_sum(s1);
        s2 = red16_sum(s2);
        float mean = s1 * (1.f / 256.f);
        float var = s2 * (1.f / 256.f) - mean * mean;
        float rs = rsqrtf(var + 1e-5f);
        size_t row = (size_t)(bn * 1024 + qr0 + lg * 4 + r) * 256;
#pragma unroll
        for (int f = 0; f < 16; f++) {
            int dc = f * 16 + lr;
            lnatt[row + dc] = f2b((o[f][r] - mean) * rs * sg[dc] + sb[dc]);
        }
    }
}

// ---------- K3/K4/K5: simple MFMA GEMM, A(MxK) bf16 row-major, BT(NxK) bf16 ----------
// MODE 0: relu -> bf16 out (ldOut)          (FFN gemm1)
// MODE 1: + vT residual -> bf16 out (ld256) (FFN gemm2 + epi add)
// MODE 2: scatter f32 to (B,C,N,V,W) output (out projection)
template <int MODE>
__global__ __launch_bounds__(256) void gemm_kernel(
    const u16* __restrict__ A, const u16* __restrict__ BT,
    u16* __restrict__ outb, const u16* __restrict__ vT,
    float* __restrict__ outf, int K, int ldOut) {
    const int tid = threadIdx.x;
    const int wave = tid >> 6, lane = tid & 63, lr = lane & 15, lg = lane >> 4;
    const int m0 = blockIdx.x * 64 + wave * 16;
    const int n0 = blockIdx.y * 64;
    f32x4 acc[4];
#pragma unroll
    for (int nb = 0; nb < 4; nb++) acc[nb] = (f32x4){0.f, 0.f, 0.f, 0.f};
    const u16* ap = A + (size_t)(m0 + lr) * K + lg * 8;
    for (int kc = 0; kc < K; kc += 32) {
        bf16x8 a = *(const bf16x8*)(ap + kc);
#pragma unroll
        for (int nb = 0; nb < 4; nb++) {
            bf16x8 bv = *(const bf16x8*)(BT + (size_t)(n0 + nb * 16 + lr) * K + kc + lg * 8);
            acc[nb] = MFMA(a, bv, acc[nb]);
        }
    }
    const int g = m0 + lg * 4;
    if (MODE == 0) {
#pragma unroll
        for (int nb = 0; nb < 4; nb++)
#pragma unroll
            for (int r = 0; r < 4; r++)
                outb[(size_t)(g + r) * ldOut + n0 + nb * 16 + lr] =
                    f2b(fmaxf(acc[nb][r], 0.f));
    } else if (MODE == 1) {
        int bn = g >> 10, s = g & 1023;
#pragma unroll
        for (int nb = 0; nb < 4; nb++) {
            int dd = n0 + nb * 16 + lr;
            const u16* vp = vT + ((size_t)bn * 256 + dd) * 1024 + s;
#pragma unroll
            for (int r = 0; r < 4; r++)
                outb[(size_t)(g + r) * ldOut + dd] = f2b(acc[nb][r] + b2f(vp[r]));
        }
    } else {
        int bn = g >> 10, s = g & 1023;
        int bb = bn >> 3, nn = bn & 7;
#pragma unroll
        for (int nb = 0; nb < 4; nb++) {
            int cc = n0 + nb * 16 + lr;
            *(f32x4*)(outf + (size_t)bb * 524288 + (size_t)cc * 8192 +
                      (size_t)nn * 1024 + s) = acc[nb];
        }
    }
}

extern "C" void kernel_launch(void* const* d_in, const int* in_sizes, int n_in,
                              void* d_out, int out_size, void* d_ws, size_t ws_size,
                              hipStream_t stream) {
    const float* lf    = (const float*)d_in[0];
    const float* hf    = (const float*)d_in[1];
    const float* Win   = (const float*)d_in[2];
    const float* Wkv   = (const float*)d_in[3];
    const float* gamma = (const float*)d_in[4];
    const float* beta  = (const float*)d_in[5];
    const float* g2    = (const float*)d_in[6];
    const float* b2    = (const float*)d_in[7];
    const float* W1    = (const float*)d_in[8];
    const float* W2    = (const float*)d_in[9];
    const float* Wo    = (const float*)d_in[10];
    float* out = (float*)d_out;

    char* w = (char*)d_ws;
    const size_t MB16 = 16777216;
    u16* qh  = (u16*)(w);
    u16* ql  = (u16*)(w + MB16);
    u16* kh  = (u16*)(w + 2 * MB16);
    u16* kl  = (u16*)(w + 3 * MB16);
    u16* vT  = (u16*)(w + 4 * MB16);
    u16* hb  = (u16*)(w + 5 * MB16);            // 33.55 MB
    u16* w1T = (u16*)(w + 5 * MB16 + 33554432);
    u16* w2T = w1T + 131072;
    u16* woT = w2T + 131072;
    u16* lnatt = qh;   // reuse: block-private q rows are consumed before LN write
    u16* epib  = kh;   // reuse: k dead after attention

    wconv_kernel<<<dim3(1088), dim3(256), 0, stream>>>(W1, W2, Wo, w1T, w2T, woT);
    proj_kernel<<<dim3(4096), dim3(256), 0, stream>>>(lf, hf, Win, Wkv, gamma, beta,
                                                      qh, ql, kh, kl, vT);
    attn_kernel<<<dim3(16, 32), dim3(256), 0, stream>>>(qh, ql, kh, kl, vT, g2, b2,
                                                        lnatt);
    gemm_kernel<0><<<dim3(512, 8), dim3(256), 0, stream>>>(lnatt, w1T, hb, nullptr,
                                                           nullptr, 256, 512);
    gemm_kernel<1><<<dim3(512, 4), dim3(256), 0, stream>>>(hb, w2T, epib, vT,
                                                           nullptr, 512, 256);
    gemm_kernel<2><<<dim3(512, 1), dim3(256), 0, stream>>>(epib, woT, nullptr,
                                                           nullptr, out, 256, 64);
}

// Round 4
// 351.228 us; speedup vs baseline: 1.7295x; 1.7295x over previous
//
#include <hip/hip_runtime.h>

typedef short bf16x8 __attribute__((ext_vector_type(8)));
typedef float f32x4 __attribute__((ext_vector_type(4)));
typedef unsigned int u32x4 __attribute__((ext_vector_type(4)));
typedef unsigned short u16;

#define MFMA(a, b, c) __builtin_amdgcn_mfma_f32_16x16x32_bf16(a, b, c, 0, 0, 0)

// ---------- helpers ----------
__device__ __forceinline__ u16 f2b(float f) {
    union { float f; unsigned u; } x{f};
    unsigned r = (x.u + 0x7FFFu + ((x.u >> 16) & 1u)) >> 16;
    return (u16)r;
}
__device__ __forceinline__ float b2f(u16 h) {
    union { unsigned u; float f; } x{((unsigned)h) << 16};
    return x.f;
}
__device__ __forceinline__ float red64_sum(float v) {
#pragma unroll
    for (int m = 1; m < 64; m <<= 1) v += __shfl_xor(v, m, 64);
    return v;
}
__device__ __forceinline__ float red16_sum(float v) {
#pragma unroll
    for (int m = 1; m < 16; m <<= 1) v += __shfl_xor(v, m, 64);
    return v;
}
__device__ __forceinline__ float red16_max(float v) {
#pragma unroll
    for (int m = 1; m < 16; m <<= 1) v = fmaxf(v, __shfl_xor(v, m, 64));
    return v;
}
__device__ __forceinline__ void gl_lds16(const void* g, void* l) {
    __builtin_amdgcn_global_load_lds(
        (const __attribute__((address_space(1))) unsigned int*)(g),
        (__attribute__((address_space(3))) unsigned int*)(l), 16, 0, 0);
}

// dims: B=4, C=64, N=8, V=32, W=32, D=256 ; BN=32, S=1024, tokens M=32768

// ---------- K0: weight convert/transpose to bf16 ----------
__global__ __launch_bounds__(256) void wconv_kernel(
    const float* __restrict__ W1, const float* __restrict__ W2,
    const float* __restrict__ Wo, u16* __restrict__ w1T,
    u16* __restrict__ w2T, u16* __restrict__ woT) {
    int id = blockIdx.x * 256 + threadIdx.x;
    if (id < 131072) {                       // W1: (256,512) -> (512,256)
        int n = id >> 8, k = id & 255;
        w1T[id] = f2b(W1[k * 512 + n]);
    } else if (id < 262144) {                // W2: (512,256) -> (256,512)
        int j = id - 131072;
        int n = j >> 9, k = j & 511;
        w2T[j] = f2b(W2[k * 256 + n]);
    } else if (id < 278528) {                // W_out: (256,64) -> (64,256)
        int j = id - 262144;
        int n = j >> 8, k = j & 255;
        woT[j] = f2b(Wo[k * 64 + n]);
    }
}

// ---------- K1: token gather + Q/KV projection + shared LN ----------
// qh/ql, kh/kl: (BN*S, 256) bf16 hi/lo split.  vT: (BN, 256, 1024) bf16.
__global__ __launch_bounds__(256) void proj_kernel(
    const float* __restrict__ lf, const float* __restrict__ hf,
    const float* __restrict__ Win, const float* __restrict__ Wkv,
    const float* __restrict__ gamma, const float* __restrict__ beta,
    u16* __restrict__ qh_, u16* __restrict__ ql_,
    u16* __restrict__ kh_, u16* __restrict__ kl_, u16* __restrict__ vT) {
    __shared__ float lq[512], lk[512];   // [c][t]: addr = c*8+t
    __shared__ float red[4][8][4];
    const int tid = threadIdx.x;
    const int g0 = blockIdx.x * 8;           // first token index
    const int bn = g0 >> 10, s0 = g0 & 1023;
    const int b = bn >> 3, n = bn & 7;
    const size_t base = (size_t)b * 524288 + (size_t)n * 1024 + s0;
    {
        int c = tid >> 3, t = tid & 7;
        lq[tid]       = lf[base + (size_t)c * 8192 + t];
        lk[tid]       = hf[base + (size_t)c * 8192 + t];
        lq[tid + 256] = lf[base + (size_t)(c + 32) * 8192 + t];
        lk[tid + 256] = hf[base + (size_t)(c + 32) * 8192 + t];
    }
    __syncthreads();
    const int d = tid;
    float aq[8] = {}, ak[8] = {}, av[8] = {};
#pragma unroll 4
    for (int c = 0; c < 64; c++) {
        float wq = Win[c * 256 + d];
        float wk = Wkv[c * 512 + d];
        float wv = Wkv[c * 512 + 256 + d];
#pragma unroll
        for (int t = 0; t < 8; t++) {
            aq[t] = fmaf(lq[c * 8 + t], wq, aq[t]);
            ak[t] = fmaf(lk[c * 8 + t], wk, ak[t]);
            av[t] = fmaf(lk[c * 8 + t], wv, av[t]);
        }
    }
    const int wave = tid >> 6, lane = tid & 63;
#pragma unroll
    for (int t = 0; t < 8; t++) {
        float s1q = red64_sum(aq[t]);
        float s2q = red64_sum(aq[t] * aq[t]);
        float s1k = red64_sum(ak[t]);
        float s2k = red64_sum(ak[t] * ak[t]);
        if (lane == 0) {
            red[wave][t][0] = s1q; red[wave][t][1] = s2q;
            red[wave][t][2] = s1k; red[wave][t][3] = s2k;
        }
    }
    __syncthreads();
    const float gd = gamma[d], bd = beta[d];
    u16 vs[8];
#pragma unroll
    for (int t = 0; t < 8; t++) {
        float s1q = red[0][t][0] + red[1][t][0] + red[2][t][0] + red[3][t][0];
        float s2q = red[0][t][1] + red[1][t][1] + red[2][t][1] + red[3][t][1];
        float s1k = red[0][t][2] + red[1][t][2] + red[2][t][2] + red[3][t][2];
        float s2k = red[0][t][3] + red[1][t][3] + red[2][t][3] + red[3][t][3];
        float mq = s1q * (1.f / 256.f);
        float vq = s2q * (1.f / 256.f) - mq * mq;
        float rq = rsqrtf(vq + 1e-5f);
        float mk = s1k * (1.f / 256.f);
        float vk = s2k * (1.f / 256.f) - mk * mk;
        float rk = rsqrtf(vk + 1e-5f);
        size_t idx = (size_t)(g0 + t) * 256 + d;
        float qv = (aq[t] - mq) * rq * gd + bd;
        float kv = (ak[t] - mk) * rk * gd + bd;
        u16 qhv = f2b(qv), khv = f2b(kv);
        qh_[idx] = qhv;
        ql_[idx] = f2b(qv - b2f(qhv));
        kh_[idx] = khv;
        kl_[idx] = f2b(kv - b2f(khv));
        vs[t] = f2b(av[t]);
    }
    u32x4 pk;
    pk[0] = (unsigned)vs[0] | ((unsigned)vs[1] << 16);
    pk[1] = (unsigned)vs[2] | ((unsigned)vs[3] << 16);
    pk[2] = (unsigned)vs[4] | ((unsigned)vs[5] << 16);
    pk[3] = (unsigned)vs[6] | ((unsigned)vs[7] << 16);
    *(u32x4*)(vT + ((size_t)bn * 256 + d) * 1024 + s0) = pk;
}

// ---------- K2: causal flash attention, LDS-staged + pipelined ----------
// grid: 256 blocks = (bn 0..31) x (qt 0..7), 512 threads = 8 waves.
// Each wave owns 16 q rows; QBLK=128, KVBLK=32.
// LDS (104KB dynamic): khkl dbuf 2x32KB @0; V dbuf 2x16KB @65536; P @98304.
// Schedule (T3-minimum): prologue stage(0)+sync; per iter:
//   stage(buf^1, kt+1) -> compute(buf) -> __syncthreads()
// The end-of-iteration sync both drains our 6 staging loads (vmcnt) and
// guarantees no wave still reads buf^1 when its new contents land.
__global__ __launch_bounds__(512) void attn_kernel(
    const u16* __restrict__ qh_, const u16* __restrict__ ql_,
    const u16* __restrict__ kh_, const u16* __restrict__ kl_,
    const u16* __restrict__ vT, const float* __restrict__ g2,
    const float* __restrict__ b2, u16* __restrict__ lnatt) {
    extern __shared__ char smem[];
    const int tid = threadIdx.x;
    const int wave = tid >> 6, lane = tid & 63, lr = lane & 15, lg = lane >> 4;
    const int bn = blockIdx.x & 31, qt = blockIdx.x >> 5;
    const int qr0 = qt * 128 + wave * 16;
    const int nk = 4 * (qt + 1);
    u16* Pw = (u16*)(smem + 98304 + wave * 1024);

    // Q fragments (hi/lo split)
    bf16x8 qh[8], ql[8];
    {
        const size_t off = ((size_t)(bn * 1024 + qr0 + lr)) * 256 + lg * 8;
#pragma unroll
        for (int ck = 0; ck < 8; ck++) {
            qh[ck] = *(const bf16x8*)(qh_ + off + ck * 32);
            ql[ck] = *(const bf16x8*)(ql_ + off + ck * 32);
        }
    }
    bf16x8 onesb;   // B-fragment of ones-column (row-sum via MFMA)
    {
        short v1 = (lr == 0) ? (short)0x3F80 : (short)0;
#pragma unroll
        for (int j = 0; j < 8; j++) onesb[j] = v1;
    }

    const int srl = lane >> 5, ss = lane & 31;   // khkl staging: subrow, slot
    const int vdl = lane >> 2, vg = lane & 3;    // V staging: d-local, group
    // stage tile kt into buffer buf: 6 global_load_lds(16B) per wave.
    // LDS layouts (source pre-swizzled so linear dest = swizzled tile):
    //  kh/kl: [32 rows][512B], 16B slot s holds logical slot s^(row&7)
    //  V:     [256 d][64B],   16B slot g holds logical slot g^((d>>1)&3)
    auto stage = [&](int buf, int kt) {
        const int kv0 = kt << 5;
        char* baseK = smem + buf * 32768;
        char* baseV = smem + 65536 + buf * 16384;
#pragma unroll
        for (int ii = 0; ii < 2; ii++) {
            int j = wave * 2 + ii;
            int r = j * 2 + srl;
            size_t go = (((size_t)((bn << 10) + kv0 + r)) << 8) +
                        (unsigned)((ss ^ (r & 7)) << 3);
            gl_lds16(kh_ + go, baseK + j * 1024);
            gl_lds16(kl_ + go, baseK + 16384 + j * 1024);
            int d = j * 16 + vdl;
            size_t gv = (((size_t)((bn << 8) + d)) << 10) + kv0 +
                        (unsigned)((vg ^ ((d >> 1) & 3)) << 3);
            gl_lds16(vT + gv, baseV + j * 1024);
        }
    };

    f32x4 o[16];
#pragma unroll
    for (int i = 0; i < 16; i++) o[i] = (f32x4){0.f, 0.f, 0.f, 0.f};
    f32x4 ol = (f32x4){0.f, 0.f, 0.f, 0.f};
    float m[4] = {-INFINITY, -INFINITY, -INFINITY, -INFINITY};

    stage(0, 0);
    __syncthreads();
    for (int kt = 0; kt < nk; kt++) {
        const int cur = kt & 1;
        if (kt + 1 < nk) stage(cur ^ 1, kt + 1);
        if ((kt << 5) <= qr0 + 15) {   // not fully masked for this wave
            const char* kbK = smem + cur * 32768;
            f32x4 sc0 = (f32x4){0.f, 0.f, 0.f, 0.f};
            f32x4 sc1 = (f32x4){0.f, 0.f, 0.f, 0.f};
#pragma unroll
            for (int ck = 0; ck < 8; ck++) {
                int sw = ((ck * 4 + lg) ^ (lr & 7)) << 4;
                int a0 = lr * 512 + sw;
                int a1 = a0 + 16 * 512;
                bf16x8 kh0 = *(const bf16x8*)(kbK + a0);
                bf16x8 kh1 = *(const bf16x8*)(kbK + a1);
                bf16x8 kl0 = *(const bf16x8*)(kbK + 16384 + a0);
                bf16x8 kl1 = *(const bf16x8*)(kbK + 16384 + a1);
                sc0 = MFMA(qh[ck], kh0, sc0);
                sc1 = MFMA(qh[ck], kh1, sc1);
                sc0 = MFMA(ql[ck], kh0, sc0);
                sc1 = MFMA(ql[ck], kh1, sc1);
                sc0 = MFMA(qh[ck], kl0, sc0);
                sc1 = MFMA(qh[ck], kl1, sc1);
            }
            float scl[4];
            const int kvb = kt << 5;
#pragma unroll
            for (int r = 0; r < 4; r++) {
                int qi = qr0 + lg * 4 + r;
                float s0v = (kvb + lr > qi) ? -1e30f : sc0[r];
                float s1v = (kvb + 16 + lr > qi) ? -1e30f : sc1[r];
                float tm = red16_max(fmaxf(s0v, s1v));
                float mn = fmaxf(m[r], tm);
                scl[r] = __expf(m[r] - mn);
                m[r] = mn;
                Pw[(lg * 4 + r) * 32 + lr] = f2b(__expf(s0v - mn));
                Pw[(lg * 4 + r) * 32 + 16 + lr] = f2b(__expf(s1v - mn));
            }
#pragma unroll
            for (int f = 0; f < 16; f++) {
                f32x4 t = o[f];
                t[0] *= scl[0]; t[1] *= scl[1]; t[2] *= scl[2]; t[3] *= scl[3];
                o[f] = t;
            }
            ol[0] *= scl[0]; ol[1] *= scl[1]; ol[2] *= scl[2]; ol[3] *= scl[3];
            bf16x8 pa = *(const bf16x8*)((const char*)Pw + lr * 64 + lg * 16);
            const char* vb = smem + 65536 + cur * 16384;
#pragma unroll
            for (int db = 0; db < 16; db++) {
                int d = db * 16 + lr;
                bf16x8 vf = *(const bf16x8*)(vb + d * 64 +
                                             ((lg ^ ((lr >> 1) & 3)) << 4));
                o[db] = MFMA(pa, vf, o[db]);
            }
            ol = MFMA(pa, onesb, ol);
        }
        __syncthreads();
    }
    // epilogue: 1/l from ones-column (col 0 lanes), then fused LayerNorm
    float linv[4];
#pragma unroll
    for (int r = 0; r < 4; r++) linv[r] = 1.f / __shfl(ol[r], lane & 48, 64);
#pragma unroll
    for (int f = 0; f < 16; f++) {
        o[f][0] *= linv[0]; o[f][1] *= linv[1];
        o[f][2] *= linv[2]; o[f][3] *= linv[3];
    }
    float gv[16], bv[16];
#pragma unroll
    for (int f = 0; f < 16; f++) {
        gv[f] = g2[f * 16 + lr];
        bv[f] = b2[f * 16 + lr];
    }
#pragma unroll
    for (int r = 0; r < 4; r++) {
        float s1 = 0.f, s2 = 0.f;
#pragma unroll
        for (int f = 0; f < 16; f++) { float x = o[f][r]; s1 += x; s2 += x * x; }
        s1 = red16_sum(s1);
        s2 = red16_sum(s2);
        float mean = s1 * (1.f / 256.f);
        float var = s2 * (1.f / 256.f) - mean * mean;
        float rs = rsqrtf(var + 1e-5f);
        size_t row = (size_t)(bn * 1024 + qr0 + lg * 4 + r) * 256;
#pragma unroll
        for (int f = 0; f < 16; f++)
            lnatt[row + f * 16 + lr] = f2b((o[f][r] - mean) * rs * gv[f] + bv[f]);
    }
}

// ---------- K3/K4/K5: simple MFMA GEMM, A(MxK) bf16 row-major, BT(NxK) bf16 ----------
// MODE 0: relu -> bf16 out (ldOut)          (FFN gemm1)
// MODE 1: + vT residual -> bf16 out (ld256) (FFN gemm2 + epi add)
// MODE 2: scatter f32 to (B,C,N,V,W) output (out projection)
template <int MODE>
__global__ __launch_bounds__(256) void gemm_kernel(
    const u16* __restrict__ A, const u16* __restrict__ BT,
    u16* __restrict__ outb, const u16* __restrict__ vT,
    float* __restrict__ outf, int K, int ldOut) {
    const int tid = threadIdx.x;
    const int wave = tid >> 6, lane = tid & 63, lr = lane & 15, lg = lane >> 4;
    const int m0 = blockIdx.x * 64 + wave * 16;
    const int n0 = blockIdx.y * 64;
    f32x4 acc[4];
#pragma unroll
    for (int nb = 0; nb < 4; nb++) acc[nb] = (f32x4){0.f, 0.f, 0.f, 0.f};
    const u16* ap = A + (size_t)(m0 + lr) * K + lg * 8;
    for (int kc = 0; kc < K; kc += 32) {
        bf16x8 a = *(const bf16x8*)(ap + kc);
#pragma unroll
        for (int nb = 0; nb < 4; nb++) {
            bf16x8 bv = *(const bf16x8*)(BT + (size_t)(n0 + nb * 16 + lr) * K + kc + lg * 8);
            acc[nb] = MFMA(a, bv, acc[nb]);
        }
    }
    const int g = m0 + lg * 4;
    if (MODE == 0) {
#pragma unroll
        for (int nb = 0; nb < 4; nb++)
#pragma unroll
            for (int r = 0; r < 4; r++)
                outb[(size_t)(g + r) * ldOut + n0 + nb * 16 + lr] =
                    f2b(fmaxf(acc[nb][r], 0.f));
    } else if (MODE == 1) {
        int bn = g >> 10, s = g & 1023;
#pragma unroll
        for (int nb = 0; nb < 4; nb++) {
            int dd = n0 + nb * 16 + lr;
            const u16* vp = vT + ((size_t)bn * 256 + dd) * 1024 + s;
#pragma unroll
            for (int r = 0; r < 4; r++)
                outb[(size_t)(g + r) * ldOut + dd] = f2b(acc[nb][r] + b2f(vp[r]));
        }
    } else {
        int bn = g >> 10, s = g & 1023;
        int bb = bn >> 3, nn = bn & 7;
#pragma unroll
        for (int nb = 0; nb < 4; nb++) {
            int cc = n0 + nb * 16 + lr;
            *(f32x4*)(outf + (size_t)bb * 524288 + (size_t)cc * 8192 +
                      (size_t)nn * 1024 + s) = acc[nb];
        }
    }
}

extern "C" void kernel_launch(void* const* d_in, const int* in_sizes, int n_in,
                              void* d_out, int out_size, void* d_ws, size_t ws_size,
                              hipStream_t stream) {
    const float* lf    = (const float*)d_in[0];
    const float* hf    = (const float*)d_in[1];
    const float* Win   = (const float*)d_in[2];
    const float* Wkv   = (const float*)d_in[3];
    const float* gamma = (const float*)d_in[4];
    const float* beta  = (const float*)d_in[5];
    const float* g2    = (const float*)d_in[6];
    const float* b2    = (const float*)d_in[7];
    const float* W1    = (const float*)d_in[8];
    const float* W2    = (const float*)d_in[9];
    const float* Wo    = (const float*)d_in[10];
    float* out = (float*)d_out;

    char* w = (char*)d_ws;
    const size_t MB16 = 16777216;
    u16* qh  = (u16*)(w);
    u16* ql  = (u16*)(w + MB16);
    u16* kh  = (u16*)(w + 2 * MB16);
    u16* kl  = (u16*)(w + 3 * MB16);
    u16* vT  = (u16*)(w + 4 * MB16);
    u16* hb  = (u16*)(w + 5 * MB16);            // 33.55 MB
    u16* w1T = (u16*)(w + 5 * MB16 + 33554432);
    u16* w2T = w1T + 131072;
    u16* woT = w2T + 131072;
    u16* lnatt = qh;   // reuse: q rows consumed before LN write
    u16* epib  = kh;   // reuse: k dead after attention

    wconv_kernel<<<dim3(1088), dim3(256), 0, stream>>>(W1, W2, Wo, w1T, w2T, woT);
    proj_kernel<<<dim3(4096), dim3(256), 0, stream>>>(lf, hf, Win, Wkv, gamma, beta,
                                                      qh, ql, kh, kl, vT);
    attn_kernel<<<dim3(256), dim3(512), 106496, stream>>>(qh, ql, kh, kl, vT, g2, b2,
                                                          lnatt);
    gemm_kernel<0><<<dim3(512, 8), dim3(256), 0, stream>>>(lnatt, w1T, hb, nullptr,
                                                           nullptr, 256, 512);
    gemm_kernel<1><<<dim3(512, 4), dim3(256), 0, stream>>>(hb, w2T, epib, vT,
                                                           nullptr, 512, 256);
    gemm_kernel<2><<<dim3(512, 1), dim3(256), 0, stream>>>(epib, woT, nullptr,
                                                           nullptr, out, 256, 64);
}

// Round 5
// 219.148 us; speedup vs baseline: 2.7718x; 1.6027x over previous
//
#include <hip/hip_runtime.h>

typedef short bf16x8 __attribute__((ext_vector_type(8)));
typedef float f32x4 __attribute__((ext_vector_type(4)));
typedef unsigned int u32x4 __attribute__((ext_vector_type(4)));
typedef unsigned short u16;
typedef unsigned short u16x4 __attribute__((ext_vector_type(4)));

#define MFMA(a, b, c) __builtin_amdgcn_mfma_f32_16x16x32_bf16(a, b, c, 0, 0, 0)

// ---------- helpers ----------
__device__ __forceinline__ u16 f2b(float f) {
    union { float f; unsigned u; } x{f};
    unsigned r = (x.u + 0x7FFFu + ((x.u >> 16) & 1u)) >> 16;
    return (u16)r;
}
__device__ __forceinline__ float b2f(u16 h) {
    union { unsigned u; float f; } x{((unsigned)h) << 16};
    return x.f;
}
__device__ __forceinline__ float red64_sum(float v) {
#pragma unroll
    for (int m = 1; m < 64; m <<= 1) v += __shfl_xor(v, m, 64);
    return v;
}
__device__ __forceinline__ float red16_sum(float v) {
#pragma unroll
    for (int m = 1; m < 16; m <<= 1) v += __shfl_xor(v, m, 64);
    return v;
}
__device__ __forceinline__ float red16_max(float v) {
#pragma unroll
    for (int m = 1; m < 16; m <<= 1) v = fmaxf(v, __shfl_xor(v, m, 64));
    return v;
}
__device__ __forceinline__ void gl_lds16(const void* g, void* l) {
    __builtin_amdgcn_global_load_lds(
        (const __attribute__((address_space(1))) unsigned int*)(g),
        (__attribute__((address_space(3))) unsigned int*)(l), 16, 0, 0);
}

// dims: B=4, C=64, N=8, V=32, W=32, D=256 ; BN=32, S=1024, tokens M=32768

// ---------- K0: weight convert/transpose to bf16 ----------
__global__ __launch_bounds__(256) void wconv_kernel(
    const float* __restrict__ W1, const float* __restrict__ W2,
    const float* __restrict__ Wo, u16* __restrict__ w1T,
    u16* __restrict__ w2T, u16* __restrict__ woT) {
    int id = blockIdx.x * 256 + threadIdx.x;
    if (id < 131072) {                       // W1: (256,512) -> (512,256)
        int n = id >> 8, k = id & 255;
        w1T[id] = f2b(W1[k * 512 + n]);
    } else if (id < 262144) {                // W2: (512,256) -> (256,512)
        int j = id - 131072;
        int n = j >> 9, k = j & 511;
        w2T[j] = f2b(W2[k * 256 + n]);
    } else if (id < 278528) {                // W_out: (256,64) -> (64,256)
        int j = id - 262144;
        int n = j >> 8, k = j & 255;
        woT[j] = f2b(Wo[k * 64 + n]);
    }
}

// ---------- K1: token gather + Q/KV projection + shared LN ----------
// qh/ql, kh/kl: (BN*S, 256) bf16 hi/lo split.  vT: (BN, 256, 1024) bf16.
__global__ __launch_bounds__(256) void proj_kernel(
    const float* __restrict__ lf, const float* __restrict__ hf,
    const float* __restrict__ Win, const float* __restrict__ Wkv,
    const float* __restrict__ gamma, const float* __restrict__ beta,
    u16* __restrict__ qh_, u16* __restrict__ ql_,
    u16* __restrict__ kh_, u16* __restrict__ kl_, u16* __restrict__ vT) {
    __shared__ float lq[512], lk[512];   // [c][t]: addr = c*8+t
    __shared__ float red[4][8][4];
    const int tid = threadIdx.x;
    const int g0 = blockIdx.x * 8;           // first token index
    const int bn = g0 >> 10, s0 = g0 & 1023;
    const int b = bn >> 3, n = bn & 7;
    const size_t base = (size_t)b * 524288 + (size_t)n * 1024 + s0;
    {
        int c = tid >> 3, t = tid & 7;
        lq[tid]       = lf[base + (size_t)c * 8192 + t];
        lk[tid]       = hf[base + (size_t)c * 8192 + t];
        lq[tid + 256] = lf[base + (size_t)(c + 32) * 8192 + t];
        lk[tid + 256] = hf[base + (size_t)(c + 32) * 8192 + t];
    }
    __syncthreads();
    const int d = tid;
    float aq[8] = {}, ak[8] = {}, av[8] = {};
#pragma unroll 4
    for (int c = 0; c < 64; c++) {
        float wq = Win[c * 256 + d];
        float wk = Wkv[c * 512 + d];
        float wv = Wkv[c * 512 + 256 + d];
#pragma unroll
        for (int t = 0; t < 8; t++) {
            aq[t] = fmaf(lq[c * 8 + t], wq, aq[t]);
            ak[t] = fmaf(lk[c * 8 + t], wk, ak[t]);
            av[t] = fmaf(lk[c * 8 + t], wv, av[t]);
        }
    }
    const int wave = tid >> 6, lane = tid & 63;
#pragma unroll
    for (int t = 0; t < 8; t++) {
        float s1q = red64_sum(aq[t]);
        float s2q = red64_sum(aq[t] * aq[t]);
        float s1k = red64_sum(ak[t]);
        float s2k = red64_sum(ak[t] * ak[t]);
        if (lane == 0) {
            red[wave][t][0] = s1q; red[wave][t][1] = s2q;
            red[wave][t][2] = s1k; red[wave][t][3] = s2k;
        }
    }
    __syncthreads();
    const float gd = gamma[d], bd = beta[d];
    u16 vs[8];
#pragma unroll
    for (int t = 0; t < 8; t++) {
        float s1q = red[0][t][0] + red[1][t][0] + red[2][t][0] + red[3][t][0];
        float s2q = red[0][t][1] + red[1][t][1] + red[2][t][1] + red[3][t][1];
        float s1k = red[0][t][2] + red[1][t][2] + red[2][t][2] + red[3][t][2];
        float s2k = red[0][t][3] + red[1][t][3] + red[2][t][3] + red[3][t][3];
        float mq = s1q * (1.f / 256.f);
        float vq = s2q * (1.f / 256.f) - mq * mq;
        float rq = rsqrtf(vq + 1e-5f);
        float mk = s1k * (1.f / 256.f);
        float vk = s2k * (1.f / 256.f) - mk * mk;
        float rk = rsqrtf(vk + 1e-5f);
        size_t idx = (size_t)(g0 + t) * 256 + d;
        float qv = (aq[t] - mq) * rq * gd + bd;
        float kv = (ak[t] - mk) * rk * gd + bd;
        u16 qhv = f2b(qv), khv = f2b(kv);
        qh_[idx] = qhv;
        ql_[idx] = f2b(qv - b2f(qhv));
        kh_[idx] = khv;
        kl_[idx] = f2b(kv - b2f(khv));
        vs[t] = f2b(av[t]);
    }
    u32x4 pk;
    pk[0] = (unsigned)vs[0] | ((unsigned)vs[1] << 16);
    pk[1] = (unsigned)vs[2] | ((unsigned)vs[3] << 16);
    pk[2] = (unsigned)vs[4] | ((unsigned)vs[5] << 16);
    pk[3] = (unsigned)vs[6] | ((unsigned)vs[7] << 16);
    *(u32x4*)(vT + ((size_t)bn * 256 + d) * 1024 + s0) = pk;
}

// ---------- K2: causal flash attention, strip-paired for load balance ----------
// grid: 256 blocks = (bn 0..31) x (pair p 0..7), 512 threads = 8 waves.
// Waves 0-3 -> strip p (rows p*64..), waves 4-7 -> strip 15-p.
// Per-block wave-iters = 132, uniform across blocks (tail-balance).
// LDS (104KB dynamic): khkl dbuf 2x32KB @0; V dbuf 2x16KB @65536; P @98304.
__global__ __launch_bounds__(512) void attn_kernel(
    const u16* __restrict__ qh_, const u16* __restrict__ ql_,
    const u16* __restrict__ kh_, const u16* __restrict__ kl_,
    const u16* __restrict__ vT, const float* __restrict__ g2,
    const float* __restrict__ b2, u16* __restrict__ lnatt) {
    extern __shared__ char smem[];
    const int tid = threadIdx.x;
    const int wave = tid >> 6, lane = tid & 63, lr = lane & 15, lg = lane >> 4;
    const int bn = blockIdx.x >> 3, p = blockIdx.x & 7;
    const int strip = (wave < 4) ? p : (15 - p);
    const int qr0 = strip * 64 + (wave & 3) * 16;
    const int nk = 32 - 2 * p;            // deep strip's tile count (max)
    u16* Pw = (u16*)(smem + 98304 + wave * 1024);

    // Q fragments (hi/lo split)
    bf16x8 qh[8], ql[8];
    {
        const size_t off = ((size_t)(bn * 1024 + qr0 + lr)) * 256 + lg * 8;
#pragma unroll
        for (int ck = 0; ck < 8; ck++) {
            qh[ck] = *(const bf16x8*)(qh_ + off + ck * 32);
            ql[ck] = *(const bf16x8*)(ql_ + off + ck * 32);
        }
    }
    bf16x8 onesb;   // B-fragment of ones-column (row-sum via MFMA)
    {
        short v1 = (lr == 0) ? (short)0x3F80 : (short)0;
#pragma unroll
        for (int j = 0; j < 8; j++) onesb[j] = v1;
    }

    const int srl = lane >> 5, ss = lane & 31;   // khkl staging: subrow, slot
    const int vdl = lane >> 2, vg = lane & 3;    // V staging: d-local, group
    // stage tile kt into buffer buf: 6 global_load_lds(16B) per wave.
    // LDS layouts (source pre-swizzled so linear dest = swizzled tile):
    //  kh/kl: [32 rows][512B], 16B slot s holds logical slot s^(row&7)
    //  V:     [256 d][64B],   16B slot g holds logical slot g^((d>>1)&3)
    auto stage = [&](int buf, int kt) {
        const int kv0 = kt << 5;
        char* baseK = smem + buf * 32768;
        char* baseV = smem + 65536 + buf * 16384;
#pragma unroll
        for (int ii = 0; ii < 2; ii++) {
            int j = wave * 2 + ii;
            int r = j * 2 + srl;
            size_t go = (((size_t)((bn << 10) + kv0 + r)) << 8) +
                        (unsigned)((ss ^ (r & 7)) << 3);
            gl_lds16(kh_ + go, baseK + j * 1024);
            gl_lds16(kl_ + go, baseK + 16384 + j * 1024);
            int d = j * 16 + vdl;
            size_t gv = (((size_t)((bn << 8) + d)) << 10) + kv0 +
                        (unsigned)((vg ^ ((d >> 1) & 3)) << 3);
            gl_lds16(vT + gv, baseV + j * 1024);
        }
    };

    f32x4 o[16];
#pragma unroll
    for (int i = 0; i < 16; i++) o[i] = (f32x4){0.f, 0.f, 0.f, 0.f};
    f32x4 ol = (f32x4){0.f, 0.f, 0.f, 0.f};
    float m[4] = {-INFINITY, -INFINITY, -INFINITY, -INFINITY};

    stage(0, 0);
    __syncthreads();
    for (int kt = 0; kt < nk; kt++) {
        const int cur = kt & 1;
        if (kt + 1 < nk) stage(cur ^ 1, kt + 1);
        if ((kt << 5) <= qr0 + 15) {   // this wave's strip still in range
            const char* kbK = smem + cur * 32768;
            f32x4 sc0 = (f32x4){0.f, 0.f, 0.f, 0.f};
            f32x4 sc1 = (f32x4){0.f, 0.f, 0.f, 0.f};
#pragma unroll
            for (int ck = 0; ck < 8; ck++) {
                int sw = ((ck * 4 + lg) ^ (lr & 7)) << 4;
                int a0 = lr * 512 + sw;
                int a1 = a0 + 16 * 512;
                bf16x8 kh0 = *(const bf16x8*)(kbK + a0);
                bf16x8 kh1 = *(const bf16x8*)(kbK + a1);
                bf16x8 kl0 = *(const bf16x8*)(kbK + 16384 + a0);
                bf16x8 kl1 = *(const bf16x8*)(kbK + 16384 + a1);
                sc0 = MFMA(qh[ck], kh0, sc0);
                sc1 = MFMA(qh[ck], kh1, sc1);
                sc0 = MFMA(ql[ck], kh0, sc0);
                sc1 = MFMA(ql[ck], kh1, sc1);
                sc0 = MFMA(qh[ck], kl0, sc0);
                sc1 = MFMA(qh[ck], kl1, sc1);
            }
            float scl[4];
            const int kvb = kt << 5;
#pragma unroll
            for (int r = 0; r < 4; r++) {
                int qi = qr0 + lg * 4 + r;
                float s0v = (kvb + lr > qi) ? -1e30f : sc0[r];
                float s1v = (kvb + 16 + lr > qi) ? -1e30f : sc1[r];
                float tm = red16_max(fmaxf(s0v, s1v));
                float mn = fmaxf(m[r], tm);
                scl[r] = __expf(m[r] - mn);
                m[r] = mn;
                Pw[(lg * 4 + r) * 32 + lr] = f2b(__expf(s0v - mn));
                Pw[(lg * 4 + r) * 32 + 16 + lr] = f2b(__expf(s1v - mn));
            }
#pragma unroll
            for (int f = 0; f < 16; f++) {
                f32x4 t = o[f];
                t[0] *= scl[0]; t[1] *= scl[1]; t[2] *= scl[2]; t[3] *= scl[3];
                o[f] = t;
            }
            ol[0] *= scl[0]; ol[1] *= scl[1]; ol[2] *= scl[2]; ol[3] *= scl[3];
            bf16x8 pa = *(const bf16x8*)((const char*)Pw + lr * 64 + lg * 16);
            const char* vb = smem + 65536 + cur * 16384;
#pragma unroll
            for (int db = 0; db < 16; db++) {
                int d = db * 16 + lr;
                bf16x8 vf = *(const bf16x8*)(vb + d * 64 +
                                             ((lg ^ ((lr >> 1) & 3)) << 4));
                o[db] = MFMA(pa, vf, o[db]);
            }
            ol = MFMA(pa, onesb, ol);
        }
        __syncthreads();
    }
    // epilogue: 1/l from ones-column (col 0 lanes), then fused LayerNorm
    float linv[4];
#pragma unroll
    for (int r = 0; r < 4; r++) linv[r] = 1.f / __shfl(ol[r], lane & 48, 64);
#pragma unroll
    for (int f = 0; f < 16; f++) {
        o[f][0] *= linv[0]; o[f][1] *= linv[1];
        o[f][2] *= linv[2]; o[f][3] *= linv[3];
    }
    float gv[16], bv[16];
#pragma unroll
    for (int f = 0; f < 16; f++) {
        gv[f] = g2[f * 16 + lr];
        bv[f] = b2[f * 16 + lr];
    }
#pragma unroll
    for (int r = 0; r < 4; r++) {
        float s1 = 0.f, s2 = 0.f;
#pragma unroll
        for (int f = 0; f < 16; f++) { float x = o[f][r]; s1 += x; s2 += x * x; }
        s1 = red16_sum(s1);
        s2 = red16_sum(s2);
        float mean = s1 * (1.f / 256.f);
        float var = s2 * (1.f / 256.f) - mean * mean;
        float rs = rsqrtf(var + 1e-5f);
        size_t row = (size_t)(bn * 1024 + qr0 + lg * 4 + r) * 256;
#pragma unroll
        for (int f = 0; f < 16; f++)
            lnatt[row + f * 16 + lr] = f2b((o[f][r] - mean) * rs * gv[f] + bv[f]);
    }
}

// ---------- K3/K4/K5: LDS-staged GEMM, A(Mx K) bf16, BT(N x K) bf16 ----------
// Block: 128 rows (8 waves x 16) x BN=NB*16 cols. Whole B tile staged once in
// LDS via global_load_lds with XOR-slot swizzle (conflict-free ds_read_b128).
// MODE 0: relu -> bf16 (ldOut)   MODE 1: +vT residual -> bf16 (ld 256)
// MODE 2: scatter f32 to (B,C,N,V,W)
template <int K, int NB, int MODE>
__global__ __launch_bounds__(512) void gemmB_kernel(
    const u16* __restrict__ A, const u16* __restrict__ BT,
    u16* __restrict__ outb, const u16* __restrict__ vTr,
    float* __restrict__ outf, int ldOut) {
    extern __shared__ char bsm[];
    const int tid = threadIdx.x;
    const int wave = tid >> 6, lane = tid & 63, lr = lane & 15, lg = lane >> 4;
    constexpr int K2 = K * 2;           // bytes per B column
    constexpr int BN = NB * 16;
    constexpr int TILE = BN * K2;
    const int m0 = blockIdx.x * 128 + wave * 16;
    const int n0 = blockIdx.y * BN;
    {   // stage B tile; source pre-swizzled: phys slot s holds logical s^(col&7)
        const char* bsrc = (const char*)(BT + (size_t)n0 * K);
        constexpr int ITER = TILE / (512 * 16);
#pragma unroll
        for (int it = 0; it < ITER; it++) {
            int o = (it * 512 + tid) * 16;
            int col = o / K2;
            int slot = (o % K2) >> 4;
            int src = col * K2 + ((slot ^ (col & 7)) << 4);
            gl_lds16(bsrc + src, bsm + o);
        }
    }
    __syncthreads();
    f32x4 acc[NB];
#pragma unroll
    for (int nb = 0; nb < NB; nb++) acc[nb] = (f32x4){0.f, 0.f, 0.f, 0.f};
    const u16* ap = A + (size_t)(m0 + lr) * K + lg * 8;
#pragma unroll
    for (int kc = 0; kc < K; kc += 32) {
        bf16x8 a = *(const bf16x8*)(ap + kc);
        int ks = (kc >> 3) + lg;
#pragma unroll
        for (int nb = 0; nb < NB; nb++) {
            int c = nb * 16 + lr;
            bf16x8 bv = *(const bf16x8*)(bsm + c * K2 + ((ks ^ (c & 7)) << 4));
            acc[nb] = MFMA(a, bv, acc[nb]);
        }
    }
    const int g = m0 + lg * 4;
    if (MODE == 0) {
#pragma unroll
        for (int nb = 0; nb < NB; nb++)
#pragma unroll
            for (int r = 0; r < 4; r++)
                outb[(size_t)(g + r) * ldOut + n0 + nb * 16 + lr] =
                    f2b(fmaxf(acc[nb][r], 0.f));
    } else if (MODE == 1) {
        int bn = g >> 10, s = g & 1023;
#pragma unroll
        for (int nb = 0; nb < NB; nb++) {
            int dd = n0 + nb * 16 + lr;
            u16x4 vv = *(const u16x4*)(vTr + ((size_t)bn * 256 + dd) * 1024 + s);
#pragma unroll
            for (int r = 0; r < 4; r++)
                outb[(size_t)(g + r) * 256 + dd] = f2b(acc[nb][r] + b2f(vv[r]));
        }
    } else {
        int bn = g >> 10, s = g & 1023;
        int bb = bn >> 3, nn = bn & 7;
#pragma unroll
        for (int nb = 0; nb < NB; nb++) {
            int cc = n0 + nb * 16 + lr;
            *(f32x4*)(outf + (size_t)bb * 524288 + (size_t)cc * 8192 +
                      (size_t)nn * 1024 + s) = acc[nb];
        }
    }
}

extern "C" void kernel_launch(void* const* d_in, const int* in_sizes, int n_in,
                              void* d_out, int out_size, void* d_ws, size_t ws_size,
                              hipStream_t stream) {
    const float* lf    = (const float*)d_in[0];
    const float* hf    = (const float*)d_in[1];
    const float* Win   = (const float*)d_in[2];
    const float* Wkv   = (const float*)d_in[3];
    const float* gamma = (const float*)d_in[4];
    const float* beta  = (const float*)d_in[5];
    const float* g2    = (const float*)d_in[6];
    const float* b2    = (const float*)d_in[7];
    const float* W1    = (const float*)d_in[8];
    const float* W2    = (const float*)d_in[9];
    const float* Wo    = (const float*)d_in[10];
    float* out = (float*)d_out;

    char* w = (char*)d_ws;
    const size_t MB16 = 16777216;
    u16* qh  = (u16*)(w);
    u16* ql  = (u16*)(w + MB16);
    u16* kh  = (u16*)(w + 2 * MB16);
    u16* kl  = (u16*)(w + 3 * MB16);
    u16* vT  = (u16*)(w + 4 * MB16);
    u16* hb  = (u16*)(w + 5 * MB16);            // 33.55 MB
    u16* w1T = (u16*)(w + 5 * MB16 + 33554432);
    u16* w2T = w1T + 131072;
    u16* woT = w2T + 131072;
    u16* lnatt = qh;   // reuse: q rows consumed before LN write
    u16* epib  = kh;   // reuse: k dead after attention

    wconv_kernel<<<dim3(1088), dim3(256), 0, stream>>>(W1, W2, Wo, w1T, w2T, woT);
    proj_kernel<<<dim3(4096), dim3(256), 0, stream>>>(lf, hf, Win, Wkv, gamma, beta,
                                                      qh, ql, kh, kl, vT);
    attn_kernel<<<dim3(256), dim3(512), 106496, stream>>>(qh, ql, kh, kl, vT, g2, b2,
                                                          lnatt);
    gemmB_kernel<256, 8, 0><<<dim3(256, 4), dim3(512), 65536, stream>>>(
        lnatt, w1T, hb, nullptr, nullptr, 512);
    gemmB_kernel<512, 8, 1><<<dim3(256, 2), dim3(512), 131072, stream>>>(
        hb, w2T, epib, vT, nullptr, 256);
    gemmB_kernel<256, 4, 2><<<dim3(256, 1), dim3(512), 32768, stream>>>(
        epib, woT, nullptr, nullptr, out, 64);
}

// Round 7
// 166.127 us; speedup vs baseline: 3.6565x; 1.3192x over previous
//
#include <hip/hip_runtime.h>

typedef short bf16x8 __attribute__((ext_vector_type(8)));
typedef float f32x4 __attribute__((ext_vector_type(4)));
typedef unsigned int u32x4 __attribute__((ext_vector_type(4)));
typedef unsigned short u16;
typedef unsigned short u16x4 __attribute__((ext_vector_type(4)));

#define MFMA(a, b, c) __builtin_amdgcn_mfma_f32_16x16x32_bf16(a, b, c, 0, 0, 0)

// ---------- helpers ----------
__device__ __forceinline__ u16 f2b(float f) {
    union { float f; unsigned u; } x{f};
    unsigned r = (x.u + 0x7FFFu + ((x.u >> 16) & 1u)) >> 16;
    return (u16)r;
}
__device__ __forceinline__ float b2f(u16 h) {
    union { unsigned u; float f; } x{((unsigned)h) << 16};
    return x.f;
}
__device__ __forceinline__ float red16_sum(float v) {
#pragma unroll
    for (int m = 1; m < 16; m <<= 1) v += __shfl_xor(v, m, 64);
    return v;
}
__device__ __forceinline__ float red16_max(float v) {
#pragma unroll
    for (int m = 1; m < 16; m <<= 1) v = fmaxf(v, __shfl_xor(v, m, 64));
    return v;
}
__device__ __forceinline__ void gl_lds16(const void* g, void* l) {
    __builtin_amdgcn_global_load_lds(
        (const __attribute__((address_space(1))) unsigned int*)(g),
        (__attribute__((address_space(3))) unsigned int*)(l), 16, 0, 0);
}

// dims: B=4, C=64, N=8, V=32, W=32, D=256 ; BN=32, S=1024, tokens M=32768

// ---------- K0: weight convert: gemm weights + fragment-packed proj weights ----------
// wfrag: 6 arrays x 16384 u16 (32KB each): wqh,wql,wkh,wkl,wvh,wvl,
// layout [ntck 0..31][lane 0..63][8].
__global__ __launch_bounds__(256) void wconv_kernel(
    const float* __restrict__ W1, const float* __restrict__ W2,
    const float* __restrict__ Wo, const float* __restrict__ Win,
    const float* __restrict__ Wkv, u16* __restrict__ w1T,
    u16* __restrict__ w2T, u16* __restrict__ woT, u16* __restrict__ wfrag) {
    int id = blockIdx.x * 256 + threadIdx.x;
    if (id < 131072) {                       // W1: (256,512) -> (512,256)
        int n = id >> 8, k = id & 255;
        w1T[id] = f2b(W1[k * 512 + n]);
    } else if (id < 262144) {                // W2: (512,256) -> (256,512)
        int j = id - 131072;
        int n = j >> 9, k = j & 511;
        w2T[j] = f2b(W2[k * 256 + n]);
    } else if (id < 278528) {                // W_out: (256,64) -> (64,256)
        int j = id - 262144;
        int n = j >> 8, k = j & 255;
        woT[j] = f2b(Wo[k * 64 + n]);
    } else if (id < 290816) {                // fragment-packed proj weights
        int fid = id - 278528;
        int arr = fid >> 11;                 // 0..5
        int e = fid & 2047;
        int ntck = e >> 6, ln = e & 63;
        int lr = ln & 15, lg2 = ln >> 4;
        int nt = ntck >> 1, ck = ntck & 1;
        int d = nt * 16 + lr;
#pragma unroll
        for (int j = 0; j < 8; j++) {
            int c = ck * 32 + lg2 * 8 + j;
            float x;
            if (arr < 2)       x = Win[c * 256 + d];
            else if (arr < 4)  x = Wkv[c * 512 + d];
            else               x = Wkv[c * 512 + 256 + d];
            u16 h = f2b(x);
            u16 v = (arr & 1) ? f2b(x - b2f(h)) : h;
            wfrag[arr * 16384 + e * 8 + j] = v;
        }
    }
}

// ---------- K1: MFMA projection + shared LN, hi/lo split ----------
// grid (8 st, 32 bn), 512 threads = 8 waves; each wave owns 16 tokens.
// LDS 128KB: A hi 0..16K, A lo 16K..32K (token-major bf16 fragments,
// XOR-slot swizzle); WREG 32K..96K (weight frags: hi 32KB || lo 32KB);
// WORK 96K..128K (16KB fp32 staging / 8x4KB emit bounce).
#define PJ_AH 0
#define PJ_AL 16384
#define PJ_WREG 32768
#define PJ_WORK 98304
__global__ __launch_bounds__(512, 1) void proj_kernel(
    const float* __restrict__ lf, const float* __restrict__ hf,
    const u16* __restrict__ wqg, const u16* __restrict__ wkg,
    const u16* __restrict__ wvg, const float* __restrict__ gamma,
    const float* __restrict__ beta, u16* __restrict__ qh_,
    u16* __restrict__ ql_, u16* __restrict__ kh_, u16* __restrict__ kl_,
    u16* __restrict__ vT) {
    extern __shared__ char sm[];
    const int tid = threadIdx.x;
    const int wave = tid >> 6, lane = tid & 63, lr = lane & 15, lg = lane >> 4;
    const int st = blockIdx.x, bn = blockIdx.y;
    const int b = bn >> 3, n = bn & 7;
    const int s0 = st * 128;
    const size_t baseF = (size_t)b * 524288 + (size_t)n * 1024 + s0;

    float gam[16], bet[16];
#pragma unroll
    for (int nt = 0; nt < 16; nt++) {
        gam[nt] = gamma[nt * 16 + lr];
        bet[nt] = beta[nt * 16 + lr];
    }

    // stage 32 c-rows x 128 s (16KB fp32) into WORK: [c_local][512B]
    auto stage32 = [&](const float* srcbase, int chalf) {
#pragma unroll
        for (int call = 0; call < 2; call++) {
            int unit = call * 8 + wave;                // 0..15, 1KB each
            int obase = unit << 10;
            int e = unit * 256 + lane * 4;             // float index in WORK
            int cl = e >> 7, si = e & 127;             // cl 0..31
            gl_lds16(srcbase + (size_t)(chalf * 32 + cl) * 8192 + si,
                     sm + PJ_WORK + obase);
        }
    };
    // stage 64KB of fragment-packed weights (hi 32KB || lo 32KB) into WREG
    auto stageW = [&](const u16* wsrc) {
#pragma unroll
        for (int call = 0; call < 8; call++) {
            int obase = (call * 8 + wave) << 10;       // 0..63KB
            gl_lds16((const char*)wsrc + obase + lane * 16, sm + PJ_WREG + obase);
        }
    };
    // transpose+convert WORK fp32 -> A hi/lo, logical slots slotbase..+3
    auto buildA = [&](int slotbase) {
        int g = wave >> 1;                             // 0..3
        int s = ((wave & 1) << 6) | lane;              // token 0..127
        float x[8];
#pragma unroll
        for (int cc = 0; cc < 8; cc++)
            x[cc] = *(const float*)(sm + PJ_WORK + ((g * 8 + cc) << 9) + (s << 2));
        bf16x8 ph, pl;
#pragma unroll
        for (int cc = 0; cc < 8; cc++) {
            u16 h = f2b(x[cc]);
            ph[cc] = (short)h;
            pl[cc] = (short)f2b(x[cc] - b2f(h));
        }
        int slp = (slotbase + g) ^ (s & 7);
        *(bf16x8*)(sm + PJ_AH + (s << 7) + (slp << 4)) = ph;
        *(bf16x8*)(sm + PJ_AL + (s << 7) + (slp << 4)) = pl;
    };
    // load this wave's A fragments (2 k-chunks) from A hi/lo
    auto loadA = [&](bf16x8* aH, bf16x8* aL) {
        int tl = wave * 16 + lr;
#pragma unroll
        for (int ck = 0; ck < 2; ck++) {
            int off = (tl << 7) + ((((ck << 2) | lg) ^ (tl & 7)) << 4);
            aH[ck] = *(const bf16x8*)(sm + PJ_AH + off);
            aL[ck] = *(const bf16x8*)(sm + PJ_AL + off);
        }
    };
    // 3-MFMA split-precision pass over K=64: Ah*Bh + Al*Bh + Ah*Bl
    auto pass3 = [&](const bf16x8* aH, const bf16x8* aL, f32x4* acc) {
#pragma unroll
        for (int nt = 0; nt < 16; nt++) acc[nt] = (f32x4){0.f, 0.f, 0.f, 0.f};
#pragma unroll
        for (int nt = 0; nt < 16; nt++) {
#pragma unroll
            for (int ck = 0; ck < 2; ck++) {
                int wo = (((nt << 1) | ck) << 10) + (lane << 4);
                bf16x8 bh = *(const bf16x8*)(sm + PJ_WREG + wo);
                bf16x8 bl = *(const bf16x8*)(sm + PJ_WREG + 32768 + wo);
                acc[nt] = MFMA(aH[ck], bh, acc[nt]);
                acc[nt] = MFMA(aL[ck], bh, acc[nt]);
                acc[nt] = MFMA(aH[ck], bl, acc[nt]);
            }
        }
    };
    auto lnstats = [&](const f32x4* acc, float* mean, float* rs) {
#pragma unroll
        for (int r = 0; r < 4; r++) {
            float s1 = 0.f, s2 = 0.f;
#pragma unroll
            for (int nt = 0; nt < 16; nt++) {
                float xv = acc[nt][r];
                s1 += xv; s2 += xv * xv;
            }
            s1 = red16_sum(s1);
            s2 = red16_sum(s2);
            float mn = s1 * (1.f / 256.f);
            float var = s2 * (1.f / 256.f) - mn * mn;
            mean[r] = mn;
            rs[r] = rsqrtf(var + 1e-5f);
        }
    };
    // LN + hi/lo emission via per-wave 4KB bounce, 16B-coalesced stores
    auto emit = [&](const f32x4* acc, const float* mean, const float* rs,
                    u16* dstH, u16* dstL) {
        char* bw = sm + PJ_WORK + wave * 4096;
        const int gtok = bn * 1024 + s0 + wave * 16;
#pragma unroll
        for (int hh = 0; hh < 2; hh++) {
#pragma unroll
            for (int sel = 0; sel < 2; sel++) {
#pragma unroll
                for (int ntl = 0; ntl < 8; ntl++) {
                    int nt = hh * 8 + ntl;
#pragma unroll
                    for (int r = 0; r < 4; r++) {
                        float y = (acc[nt][r] - mean[r]) * rs[r] * gam[nt] + bet[nt];
                        u16 hv = f2b(y);
                        u16 vv = sel ? f2b(y - b2f(hv)) : hv;
                        int tl = lg * 4 + r;
                        int dl = ntl * 16 + lr;
                        int sl = dl >> 3;
                        *(u16*)(bw + tl * 256 + ((sl ^ ((tl >> 2) & 3)) << 4) +
                                (dl & 7) * 2) = vv;
                    }
                }
                u16* dst = sel ? dstL : dstH;
#pragma unroll
                for (int p = 0; p < 4; p++) {
                    int row = lane >> 2, slq = (lane & 3) + p * 4;
                    bf16x8 v8 = *(const bf16x8*)(bw + row * 256 +
                                                 ((slq ^ ((row >> 2) & 3)) << 4));
                    *(bf16x8*)(dst + (size_t)(gtok + row) * 256 + hh * 128 +
                               slq * 8) = v8;
                }
            }
        }
    };

    f32x4 acc[16];
    float mean[4], rs[4];
    bf16x8 aH[2], aL[2];

    // ---- lf -> q ----
    stage32(lf + baseF, 0);  __syncthreads();     // P0
    buildA(0);               __syncthreads();     // P1
    stage32(lf + baseF, 1);
    stageW(wqg);             __syncthreads();     // P2
    buildA(4);               __syncthreads();     // P3
    loadA(aH, aL);
    pass3(aH, aL, acc);
    lnstats(acc, mean, rs);  __syncthreads();     // P4 (all done reading WREG)
    stageW(wkg);                                  // P5: overwrite WREG w/ k
    emit(acc, mean, rs, qh_, ql_);
    __syncthreads();                              // (drains stageW + emit)
    // ---- hf -> k, v ----
    stage32(hf + baseF, 0);  __syncthreads();     // P6
    buildA(0);               __syncthreads();     // P7
    stage32(hf + baseF, 1);  __syncthreads();     // P8
    buildA(4);               __syncthreads();     // P9
    loadA(aH, aL);
    pass3(aH, aL, acc);
    lnstats(acc, mean, rs);  __syncthreads();     // P10 (done reading WREG k)
    stageW(wvg);                                  // P11: overwrite WREG w/ v
    emit(acc, mean, rs, kh_, kl_);
    __syncthreads();                              // (drains stageW + emit)
    pass3(aH, aL, acc);                           // P12: v (same hf A-frags)
#pragma unroll
    for (int nt = 0; nt < 16; nt++) {
        u16x4 pv;
#pragma unroll
        for (int r = 0; r < 4; r++) pv[r] = f2b(acc[nt][r]);
        *(u16x4*)(vT + ((size_t)(bn * 256) + nt * 16 + lr) * 1024 + s0 +
                  wave * 16 + lg * 4) = pv;
    }
}

// ---------- K2: causal flash attention, strip-paired for load balance ----------
// grid: 256 blocks = (bn 0..31) x (pair p 0..7), 512 threads = 8 waves.
// Waves 0-3 -> strip p (rows p*64..), waves 4-7 -> strip 15-p.
// LDS (104KB dynamic): khkl dbuf 2x32KB @0; V dbuf 2x16KB @65536; P @98304.
__global__ __launch_bounds__(512) void attn_kernel(
    const u16* __restrict__ qh_, const u16* __restrict__ ql_,
    const u16* __restrict__ kh_, const u16* __restrict__ kl_,
    const u16* __restrict__ vT, const float* __restrict__ g2,
    const float* __restrict__ b2, u16* __restrict__ lnatt) {
    extern __shared__ char smem[];
    const int tid = threadIdx.x;
    const int wave = tid >> 6, lane = tid & 63, lr = lane & 15, lg = lane >> 4;
    const int bn = blockIdx.x >> 3, p = blockIdx.x & 7;
    const int strip = (wave < 4) ? p : (15 - p);
    const int qr0 = strip * 64 + (wave & 3) * 16;
    const int nk = 32 - 2 * p;            // deep strip's tile count (max)
    u16* Pw = (u16*)(smem + 98304 + wave * 1024);

    // Q fragments (hi/lo split)
    bf16x8 qh[8], ql[8];
    {
        const size_t off = ((size_t)(bn * 1024 + qr0 + lr)) * 256 + lg * 8;
#pragma unroll
        for (int ck = 0; ck < 8; ck++) {
            qh[ck] = *(const bf16x8*)(qh_ + off + ck * 32);
            ql[ck] = *(const bf16x8*)(ql_ + off + ck * 32);
        }
    }
    bf16x8 onesb;   // B-fragment of ones-column (row-sum via MFMA)
    {
        short v1 = (lr == 0) ? (short)0x3F80 : (short)0;
#pragma unroll
        for (int j = 0; j < 8; j++) onesb[j] = v1;
    }

    const int srl = lane >> 5, ss = lane & 31;   // khkl staging: subrow, slot
    const int vdl = lane >> 2, vg = lane & 3;    // V staging: d-local, group
    auto stage = [&](int buf, int kt) {
        const int kv0 = kt << 5;
        char* baseK = smem + buf * 32768;
        char* baseV = smem + 65536 + buf * 16384;
#pragma unroll
        for (int ii = 0; ii < 2; ii++) {
            int j = wave * 2 + ii;
            int r = j * 2 + srl;
            size_t go = (((size_t)((bn << 10) + kv0 + r)) << 8) +
                        (unsigned)((ss ^ (r & 7)) << 3);
            gl_lds16(kh_ + go, baseK + j * 1024);
            gl_lds16(kl_ + go, baseK + 16384 + j * 1024);
            int d = j * 16 + vdl;
            size_t gv = (((size_t)((bn << 8) + d)) << 10) + kv0 +
                        (unsigned)((vg ^ ((d >> 1) & 3)) << 3);
            gl_lds16(vT + gv, baseV + j * 1024);
        }
    };

    f32x4 o[16];
#pragma unroll
    for (int i = 0; i < 16; i++) o[i] = (f32x4){0.f, 0.f, 0.f, 0.f};
    f32x4 ol = (f32x4){0.f, 0.f, 0.f, 0.f};
    float m[4] = {-INFINITY, -INFINITY, -INFINITY, -INFINITY};

    stage(0, 0);
    __syncthreads();
    for (int kt = 0; kt < nk; kt++) {
        const int cur = kt & 1;
        if (kt + 1 < nk) stage(cur ^ 1, kt + 1);
        if ((kt << 5) <= qr0 + 15) {   // this wave's strip still in range
            const char* kbK = smem + cur * 32768;
            f32x4 sc0 = (f32x4){0.f, 0.f, 0.f, 0.f};
            f32x4 sc1 = (f32x4){0.f, 0.f, 0.f, 0.f};
#pragma unroll
            for (int ck = 0; ck < 8; ck++) {
                int sw = ((ck * 4 + lg) ^ (lr & 7)) << 4;
                int a0 = lr * 512 + sw;
                int a1 = a0 + 16 * 512;
                bf16x8 kh0 = *(const bf16x8*)(kbK + a0);
                bf16x8 kh1 = *(const bf16x8*)(kbK + a1);
                bf16x8 kl0 = *(const bf16x8*)(kbK + 16384 + a0);
                bf16x8 kl1 = *(const bf16x8*)(kbK + 16384 + a1);
                sc0 = MFMA(qh[ck], kh0, sc0);
                sc1 = MFMA(qh[ck], kh1, sc1);
                sc0 = MFMA(ql[ck], kh0, sc0);
                sc1 = MFMA(ql[ck], kh1, sc1);
                sc0 = MFMA(qh[ck], kl0, sc0);
                sc1 = MFMA(qh[ck], kl1, sc1);
            }
            float scl[4];
            const int kvb = kt << 5;
#pragma unroll
            for (int r = 0; r < 4; r++) {
                int qi = qr0 + lg * 4 + r;
                float s0v = (kvb + lr > qi) ? -1e30f : sc0[r];
                float s1v = (kvb + 16 + lr > qi) ? -1e30f : sc1[r];
                float tm = red16_max(fmaxf(s0v, s1v));
                float mn = fmaxf(m[r], tm);
                scl[r] = __expf(m[r] - mn);
                m[r] = mn;
                Pw[(lg * 4 + r) * 32 + lr] = f2b(__expf(s0v - mn));
                Pw[(lg * 4 + r) * 32 + 16 + lr] = f2b(__expf(s1v - mn));
            }
#pragma unroll
            for (int f = 0; f < 16; f++) {
                f32x4 t = o[f];
                t[0] *= scl[0]; t[1] *= scl[1]; t[2] *= scl[2]; t[3] *= scl[3];
                o[f] = t;
            }
            ol[0] *= scl[0]; ol[1] *= scl[1]; ol[2] *= scl[2]; ol[3] *= scl[3];
            bf16x8 pa = *(const bf16x8*)((const char*)Pw + lr * 64 + lg * 16);
            const char* vb = smem + 65536 + cur * 16384;
#pragma unroll
            for (int db = 0; db < 16; db++) {
                int d = db * 16 + lr;
                bf16x8 vf = *(const bf16x8*)(vb + d * 64 +
                                             ((lg ^ ((lr >> 1) & 3)) << 4));
                o[db] = MFMA(pa, vf, o[db]);
            }
            ol = MFMA(pa, onesb, ol);
        }
        __syncthreads();
    }
    // epilogue: 1/l from ones-column (col 0 lanes), then fused LayerNorm
    float linv[4];
#pragma unroll
    for (int r = 0; r < 4; r++) linv[r] = 1.f / __shfl(ol[r], lane & 48, 64);
#pragma unroll
    for (int f = 0; f < 16; f++) {
        o[f][0] *= linv[0]; o[f][1] *= linv[1];
        o[f][2] *= linv[2]; o[f][3] *= linv[3];
    }
    float gv[16], bv[16];
#pragma unroll
    for (int f = 0; f < 16; f++) {
        gv[f] = g2[f * 16 + lr];
        bv[f] = b2[f * 16 + lr];
    }
#pragma unroll
    for (int r = 0; r < 4; r++) {
        float s1 = 0.f, s2 = 0.f;
#pragma unroll
        for (int f = 0; f < 16; f++) { float x = o[f][r]; s1 += x; s2 += x * x; }
        s1 = red16_sum(s1);
        s2 = red16_sum(s2);
        float mean = s1 * (1.f / 256.f);
        float var = s2 * (1.f / 256.f) - mean * mean;
        float rsv = rsqrtf(var + 1e-5f);
        size_t row = (size_t)(bn * 1024 + qr0 + lg * 4 + r) * 256;
#pragma unroll
        for (int f = 0; f < 16; f++)
            lnatt[row + f * 16 + lr] = f2b((o[f][r] - mean) * rsv * gv[f] + bv[f]);
    }
}

// ---------- K3/K4/K5: LDS-staged GEMM, A(MxK) bf16, BT(NxK) bf16 ----------
template <int K, int NB, int MODE>
__global__ __launch_bounds__(512) void gemmB_kernel(
    const u16* __restrict__ A, const u16* __restrict__ BT,
    u16* __restrict__ outb, const u16* __restrict__ vTr,
    float* __restrict__ outf, int ldOut) {
    extern __shared__ char bsm[];
    const int tid = threadIdx.x;
    const int wave = tid >> 6, lane = tid & 63, lr = lane & 15, lg = lane >> 4;
    constexpr int K2 = K * 2;           // bytes per B column
    constexpr int BN = NB * 16;
    constexpr int TILE = BN * K2;
    const int m0 = blockIdx.x * 128 + wave * 16;
    const int n0 = blockIdx.y * BN;
    {   // stage B tile; source pre-swizzled: phys slot s holds logical s^(col&7)
        const char* bsrc = (const char*)(BT + (size_t)n0 * K);
        constexpr int ITER = TILE / (512 * 16);
#pragma unroll
        for (int it = 0; it < ITER; it++) {
            int o = (it * 512 + tid) * 16;
            int col = o / K2;
            int slot = (o % K2) >> 4;
            int src = col * K2 + ((slot ^ (col & 7)) << 4);
            gl_lds16(bsrc + src, bsm + o);
        }
    }
    __syncthreads();
    f32x4 acc[NB];
#pragma unroll
    for (int nb = 0; nb < NB; nb++) acc[nb] = (f32x4){0.f, 0.f, 0.f, 0.f};
    const u16* ap = A + (size_t)(m0 + lr) * K + lg * 8;
#pragma unroll
    for (int kc = 0; kc < K; kc += 32) {
        bf16x8 a = *(const bf16x8*)(ap + kc);
        int ks = (kc >> 3) + lg;
#pragma unroll
        for (int nb = 0; nb < NB; nb++) {
            int c = nb * 16 + lr;
            bf16x8 bv = *(const bf16x8*)(bsm + c * K2 + ((ks ^ (c & 7)) << 4));
            acc[nb] = MFMA(a, bv, acc[nb]);
        }
    }
    const int g = m0 + lg * 4;
    if (MODE == 0) {
#pragma unroll
        for (int nb = 0; nb < NB; nb++)
#pragma unroll
            for (int r = 0; r < 4; r++)
                outb[(size_t)(g + r) * ldOut + n0 + nb * 16 + lr] =
                    f2b(fmaxf(acc[nb][r], 0.f));
    } else if (MODE == 1) {
        int bn = g >> 10, s = g & 1023;
#pragma unroll
        for (int nb = 0; nb < NB; nb++) {
            int dd = n0 + nb * 16 + lr;
            u16x4 vv = *(const u16x4*)(vTr + ((size_t)bn * 256 + dd) * 1024 + s);
#pragma unroll
            for (int r = 0; r < 4; r++)
                outb[(size_t)(g + r) * 256 + dd] = f2b(acc[nb][r] + b2f(vv[r]));
        }
    } else {
        int bn = g >> 10, s = g & 1023;
        int bb = bn >> 3, nn = bn & 7;
#pragma unroll
        for (int nb = 0; nb < NB; nb++) {
            int cc = n0 + nb * 16 + lr;
            *(f32x4*)(outf + (size_t)bb * 524288 + (size_t)cc * 8192 +
                      (size_t)nn * 1024 + s) = acc[nb];
        }
    }
}

extern "C" void kernel_launch(void* const* d_in, const int* in_sizes, int n_in,
                              void* d_out, int out_size, void* d_ws, size_t ws_size,
                              hipStream_t stream) {
    const float* lf    = (const float*)d_in[0];
    const float* hf    = (const float*)d_in[1];
    const float* Win   = (const float*)d_in[2];
    const float* Wkv   = (const float*)d_in[3];
    const float* gamma = (const float*)d_in[4];
    const float* beta  = (const float*)d_in[5];
    const float* g2    = (const float*)d_in[6];
    const float* b2    = (const float*)d_in[7];
    const float* W1    = (const float*)d_in[8];
    const float* W2    = (const float*)d_in[9];
    const float* Wo    = (const float*)d_in[10];
    float* out = (float*)d_out;

    char* w = (char*)d_ws;
    const size_t MB16 = 16777216;
    u16* qh  = (u16*)(w);
    u16* ql  = (u16*)(w + MB16);
    u16* kh  = (u16*)(w + 2 * MB16);
    u16* kl  = (u16*)(w + 3 * MB16);
    u16* vT  = (u16*)(w + 4 * MB16);
    u16* hb  = (u16*)(w + 5 * MB16);            // 33.55 MB
    u16* w1T = (u16*)(w + 5 * MB16 + 33554432);
    u16* w2T = w1T + 131072;
    u16* woT = w2T + 131072;
    u16* wfrag = woT + 16384;                   // 6 x 16384 u16 fragment weights
    u16* wqg = wfrag;
    u16* wkg = wfrag + 32768;
    u16* wvg = wfrag + 65536;
    u16* lnatt = qh;   // reuse: q rows consumed before LN write
    u16* epib  = kh;   // reuse: k dead after attention

    wconv_kernel<<<dim3(1136), dim3(256), 0, stream>>>(W1, W2, Wo, Win, Wkv,
                                                       w1T, w2T, woT, wfrag);
    proj_kernel<<<dim3(8, 32), dim3(512), 131072, stream>>>(
        lf, hf, wqg, wkg, wvg, gamma, beta, qh, ql, kh, kl, vT);
    attn_kernel<<<dim3(256), dim3(512), 106496, stream>>>(qh, ql, kh, kl, vT, g2, b2,
                                                          lnatt);
    gemmB_kernel<256, 8, 0><<<dim3(256, 4), dim3(512), 65536, stream>>>(
        lnatt, w1T, hb, nullptr, nullptr, 512);
    gemmB_kernel<512, 8, 1><<<dim3(256, 2), dim3(512), 131072, stream>>>(
        hb, w2T, epib, vT, nullptr, 256);
    gemmB_kernel<256, 4, 2><<<dim3(256, 1), dim3(512), 32768, stream>>>(
        epib, woT, nullptr, nullptr, out, 64);
}

// Round 8
// 164.150 us; speedup vs baseline: 3.7005x; 1.0120x over previous
//
#include <hip/hip_runtime.h>

typedef short bf16x8 __attribute__((ext_vector_type(8)));
typedef float f32x4 __attribute__((ext_vector_type(4)));
typedef unsigned int u32x4 __attribute__((ext_vector_type(4)));
typedef unsigned short u16;
typedef unsigned short u16x4 __attribute__((ext_vector_type(4)));

#define MFMA(a, b, c) __builtin_amdgcn_mfma_f32_16x16x32_bf16(a, b, c, 0, 0, 0)

// ---------- helpers ----------
__device__ __forceinline__ u16 f2b(float f) {
    union { float f; unsigned u; } x{f};
    unsigned r = (x.u + 0x7FFFu + ((x.u >> 16) & 1u)) >> 16;
    return (u16)r;
}
__device__ __forceinline__ float b2f(u16 h) {
    union { unsigned u; float f; } x{((unsigned)h) << 16};
    return x.f;
}
__device__ __forceinline__ float red16_sum(float v) {
#pragma unroll
    for (int m = 1; m < 16; m <<= 1) v += __shfl_xor(v, m, 64);
    return v;
}
__device__ __forceinline__ float red16_max(float v) {
#pragma unroll
    for (int m = 1; m < 16; m <<= 1) v = fmaxf(v, __shfl_xor(v, m, 64));
    return v;
}
__device__ __forceinline__ void gl_lds16(const void* g, void* l) {
    __builtin_amdgcn_global_load_lds(
        (const __attribute__((address_space(1))) unsigned int*)(g),
        (__attribute__((address_space(3))) unsigned int*)(l), 16, 0, 0);
}

// dims: B=4, C=64, N=8, V=32, W=32, D=256 ; BN=32, S=1024, tokens M=32768

// ---------- K0: weight convert: gemm weights + fragment-packed proj weights ----------
// wfrag: 6 arrays x 16384 u16 (32KB each): wqh,wql,wkh,wkl,wvh,wvl,
// layout [ntck 0..31][lane 0..63][8].
__global__ __launch_bounds__(256) void wconv_kernel(
    const float* __restrict__ W1, const float* __restrict__ W2,
    const float* __restrict__ Wo, const float* __restrict__ Win,
    const float* __restrict__ Wkv, u16* __restrict__ w1T,
    u16* __restrict__ w2T, u16* __restrict__ woT, u16* __restrict__ wfrag) {
    int id = blockIdx.x * 256 + threadIdx.x;
    if (id < 131072) {                       // W1: (256,512) -> (512,256)
        int n = id >> 8, k = id & 255;
        w1T[id] = f2b(W1[k * 512 + n]);
    } else if (id < 262144) {                // W2: (512,256) -> (256,512)
        int j = id - 131072;
        int n = j >> 9, k = j & 511;
        w2T[j] = f2b(W2[k * 256 + n]);
    } else if (id < 278528) {                // W_out: (256,64) -> (64,256)
        int j = id - 262144;
        int n = j >> 8, k = j & 255;
        woT[j] = f2b(Wo[k * 64 + n]);
    } else if (id < 290816) {                // fragment-packed proj weights
        int fid = id - 278528;
        int arr = fid >> 11;                 // 0..5
        int e = fid & 2047;
        int ntck = e >> 6, ln = e & 63;
        int lr = ln & 15, lg2 = ln >> 4;
        int nt = ntck >> 1, ck = ntck & 1;
        int d = nt * 16 + lr;
#pragma unroll
        for (int j = 0; j < 8; j++) {
            int c = ck * 32 + lg2 * 8 + j;
            float x;
            if (arr < 2)       x = Win[c * 256 + d];
            else if (arr < 4)  x = Wkv[c * 512 + d];
            else               x = Wkv[c * 512 + 256 + d];
            u16 h = f2b(x);
            u16 v = (arr & 1) ? f2b(x - b2f(h)) : h;
            wfrag[arr * 16384 + e * 8 + j] = v;
        }
    }
}

// ---------- K1: MFMA projection + shared LN, hi/lo split ----------
// grid (8 st, 32 bn), 512 threads = 8 waves; each wave owns 16 tokens.
// LDS 128KB: A hi 0..16K, A lo 16K..32K (token-major bf16 fragments,
// XOR-slot swizzle); WREG 32K..96K (weight frags: hi 32KB || lo 32KB);
// WORK 96K..128K (16KB fp32 staging / 8x4KB emit bounce).
#define PJ_AH 0
#define PJ_AL 16384
#define PJ_WREG 32768
#define PJ_WORK 98304
__global__ __launch_bounds__(512, 1) void proj_kernel(
    const float* __restrict__ lf, const float* __restrict__ hf,
    const u16* __restrict__ wqg, const u16* __restrict__ wkg,
    const u16* __restrict__ wvg, const float* __restrict__ gamma,
    const float* __restrict__ beta, u16* __restrict__ qh_,
    u16* __restrict__ ql_, u16* __restrict__ kh_, u16* __restrict__ kl_,
    u16* __restrict__ vT) {
    extern __shared__ char sm[];
    const int tid = threadIdx.x;
    const int wave = tid >> 6, lane = tid & 63, lr = lane & 15, lg = lane >> 4;
    const int st = blockIdx.x, bn = blockIdx.y;
    const int b = bn >> 3, n = bn & 7;
    const int s0 = st * 128;
    const size_t baseF = (size_t)b * 524288 + (size_t)n * 1024 + s0;

    float gam[16], bet[16];
#pragma unroll
    for (int nt = 0; nt < 16; nt++) {
        gam[nt] = gamma[nt * 16 + lr];
        bet[nt] = beta[nt * 16 + lr];
    }

    // stage 32 c-rows x 128 s (16KB fp32) into WORK: [c_local][512B]
    auto stage32 = [&](const float* srcbase, int chalf) {
#pragma unroll
        for (int call = 0; call < 2; call++) {
            int unit = call * 8 + wave;                // 0..15, 1KB each
            int obase = unit << 10;
            int e = unit * 256 + lane * 4;             // float index in WORK
            int cl = e >> 7, si = e & 127;             // cl 0..31
            gl_lds16(srcbase + (size_t)(chalf * 32 + cl) * 8192 + si,
                     sm + PJ_WORK + obase);
        }
    };
    // stage 64KB of fragment-packed weights (hi 32KB || lo 32KB) into WREG
    auto stageW = [&](const u16* wsrc) {
#pragma unroll
        for (int call = 0; call < 8; call++) {
            int obase = (call * 8 + wave) << 10;       // 0..63KB
            gl_lds16((const char*)wsrc + obase + lane * 16, sm + PJ_WREG + obase);
        }
    };
    // transpose+convert WORK fp32 -> A hi/lo, logical slots slotbase..+3
    auto buildA = [&](int slotbase) {
        int g = wave >> 1;                             // 0..3
        int s = ((wave & 1) << 6) | lane;              // token 0..127
        float x[8];
#pragma unroll
        for (int cc = 0; cc < 8; cc++)
            x[cc] = *(const float*)(sm + PJ_WORK + ((g * 8 + cc) << 9) + (s << 2));
        bf16x8 ph, pl;
#pragma unroll
        for (int cc = 0; cc < 8; cc++) {
            u16 h = f2b(x[cc]);
            ph[cc] = (short)h;
            pl[cc] = (short)f2b(x[cc] - b2f(h));
        }
        int slp = (slotbase + g) ^ (s & 7);
        *(bf16x8*)(sm + PJ_AH + (s << 7) + (slp << 4)) = ph;
        *(bf16x8*)(sm + PJ_AL + (s << 7) + (slp << 4)) = pl;
    };
    // load this wave's A fragments (2 k-chunks) from A hi/lo
    auto loadA = [&](bf16x8* aH, bf16x8* aL) {
        int tl = wave * 16 + lr;
#pragma unroll
        for (int ck = 0; ck < 2; ck++) {
            int off = (tl << 7) + ((((ck << 2) | lg) ^ (tl & 7)) << 4);
            aH[ck] = *(const bf16x8*)(sm + PJ_AH + off);
            aL[ck] = *(const bf16x8*)(sm + PJ_AL + off);
        }
    };
    // 3-MFMA split-precision pass over K=64: Ah*Bh + Al*Bh + Ah*Bl
    auto pass3 = [&](const bf16x8* aH, const bf16x8* aL, f32x4* acc) {
#pragma unroll
        for (int nt = 0; nt < 16; nt++) acc[nt] = (f32x4){0.f, 0.f, 0.f, 0.f};
#pragma unroll
        for (int nt = 0; nt < 16; nt++) {
#pragma unroll
            for (int ck = 0; ck < 2; ck++) {
                int wo = (((nt << 1) | ck) << 10) + (lane << 4);
                bf16x8 bh = *(const bf16x8*)(sm + PJ_WREG + wo);
                bf16x8 bl = *(const bf16x8*)(sm + PJ_WREG + 32768 + wo);
                acc[nt] = MFMA(aH[ck], bh, acc[nt]);
                acc[nt] = MFMA(aL[ck], bh, acc[nt]);
                acc[nt] = MFMA(aH[ck], bl, acc[nt]);
            }
        }
    };
    auto lnstats = [&](const f32x4* acc, float* mean, float* rs) {
#pragma unroll
        for (int r = 0; r < 4; r++) {
            float s1 = 0.f, s2 = 0.f;
#pragma unroll
            for (int nt = 0; nt < 16; nt++) {
                float xv = acc[nt][r];
                s1 += xv; s2 += xv * xv;
            }
            s1 = red16_sum(s1);
            s2 = red16_sum(s2);
            float mn = s1 * (1.f / 256.f);
            float var = s2 * (1.f / 256.f) - mn * mn;
            mean[r] = mn;
            rs[r] = rsqrtf(var + 1e-5f);
        }
    };
    // LN + hi/lo emission via per-wave 4KB bounce, 16B-coalesced stores
    auto emit = [&](const f32x4* acc, const float* mean, const float* rs,
                    u16* dstH, u16* dstL) {
        char* bw = sm + PJ_WORK + wave * 4096;
        const int gtok = bn * 1024 + s0 + wave * 16;
#pragma unroll
        for (int hh = 0; hh < 2; hh++) {
#pragma unroll
            for (int sel = 0; sel < 2; sel++) {
#pragma unroll
                for (int ntl = 0; ntl < 8; ntl++) {
                    int nt = hh * 8 + ntl;
#pragma unroll
                    for (int r = 0; r < 4; r++) {
                        float y = (acc[nt][r] - mean[r]) * rs[r] * gam[nt] + bet[nt];
                        u16 hv = f2b(y);
                        u16 vv = sel ? f2b(y - b2f(hv)) : hv;
                        int tl = lg * 4 + r;
                        int dl = ntl * 16 + lr;
                        int sl = dl >> 3;
                        *(u16*)(bw + tl * 256 + ((sl ^ ((tl >> 2) & 3)) << 4) +
                                (dl & 7) * 2) = vv;
                    }
                }
                u16* dst = sel ? dstL : dstH;
#pragma unroll
                for (int p = 0; p < 4; p++) {
                    int row = lane >> 2, slq = (lane & 3) + p * 4;
                    bf16x8 v8 = *(const bf16x8*)(bw + row * 256 +
                                                 ((slq ^ ((row >> 2) & 3)) << 4));
                    *(bf16x8*)(dst + (size_t)(gtok + row) * 256 + hh * 128 +
                               slq * 8) = v8;
                }
            }
        }
    };

    f32x4 acc[16];
    float mean[4], rs[4];
    bf16x8 aH[2], aL[2];

    // ---- lf -> q ----
    stage32(lf + baseF, 0);  __syncthreads();     // P0
    buildA(0);               __syncthreads();     // P1
    stage32(lf + baseF, 1);
    stageW(wqg);             __syncthreads();     // P2
    buildA(4);               __syncthreads();     // P3
    loadA(aH, aL);
    pass3(aH, aL, acc);
    lnstats(acc, mean, rs);  __syncthreads();     // P4 (all done reading WREG)
    stageW(wkg);                                  // P5: overwrite WREG w/ k
    emit(acc, mean, rs, qh_, ql_);
    __syncthreads();                              // (drains stageW + emit)
    // ---- hf -> k, v ----
    stage32(hf + baseF, 0);  __syncthreads();     // P6
    buildA(0);               __syncthreads();     // P7
    stage32(hf + baseF, 1);  __syncthreads();     // P8
    buildA(4);               __syncthreads();     // P9
    loadA(aH, aL);
    pass3(aH, aL, acc);
    lnstats(acc, mean, rs);  __syncthreads();     // P10 (done reading WREG k)
    stageW(wvg);                                  // P11: overwrite WREG w/ v
    emit(acc, mean, rs, kh_, kl_);
    __syncthreads();                              // (drains stageW + emit)
    pass3(aH, aL, acc);                           // P12: v (same hf A-frags)
#pragma unroll
    for (int nt = 0; nt < 16; nt++) {
        u16x4 pv;
#pragma unroll
        for (int r = 0; r < 4; r++) pv[r] = f2b(acc[nt][r]);
        *(u16x4*)(vT + ((size_t)(bn * 256) + nt * 16 + lr) * 1024 + s0 +
                  wave * 16 + lg * 4) = pv;
    }
}

// ---------- K2: causal flash attention, strip-paired, XCD-L2-shared ----------
// grid: 256 blocks; bn = idx%32, p = idx/32  =>  the 8 blocks sharing a bn sit
// at stride 32 => same XCD (dispatch round-robins idx%8) => K/V tiles are
// fetched from HBM once per XCD and then served from that XCD's L2.
// Waves 0-3 -> strip p (rows p*64..), waves 4-7 -> strip 15-p.
// LDS (106KB dyn): khkl dbuf 2x32KB @0; V dbuf 2x16KB @65536; P @98304,
// per-wave 1280B, row stride 80B (16B-aligned, write 2-way-free, b128 read
// slices cover all 32 banks exactly once).
__global__ __launch_bounds__(512) void attn_kernel(
    const u16* __restrict__ qh_, const u16* __restrict__ ql_,
    const u16* __restrict__ kh_, const u16* __restrict__ kl_,
    const u16* __restrict__ vT, const float* __restrict__ g2,
    const float* __restrict__ b2, u16* __restrict__ lnatt) {
    extern __shared__ char smem[];
    const int tid = threadIdx.x;
    const int wave = tid >> 6, lane = tid & 63, lr = lane & 15, lg = lane >> 4;
    const int bn = blockIdx.x & 31, p = blockIdx.x >> 5;
    const int strip = (wave < 4) ? p : (15 - p);
    const int qr0 = strip * 64 + (wave & 3) * 16;
    const int nk = 32 - 2 * p;            // deep strip's tile count (max)
    u16* Pw = (u16*)(smem + 98304 + wave * 1280);   // [16 rows][40 u16]

    // Q fragments (hi/lo split)
    bf16x8 qh[8], ql[8];
    {
        const size_t off = ((size_t)(bn * 1024 + qr0 + lr)) * 256 + lg * 8;
#pragma unroll
        for (int ck = 0; ck < 8; ck++) {
            qh[ck] = *(const bf16x8*)(qh_ + off + ck * 32);
            ql[ck] = *(const bf16x8*)(ql_ + off + ck * 32);
        }
    }
    bf16x8 onesb;   // B-fragment of ones-column (row-sum via MFMA)
    {
        short v1 = (lr == 0) ? (short)0x3F80 : (short)0;
#pragma unroll
        for (int j = 0; j < 8; j++) onesb[j] = v1;
    }

    const int srl = lane >> 5, ss = lane & 31;   // khkl staging: subrow, slot
    const int vdl = lane >> 2, vg = lane & 3;    // V staging: d-local, group
    auto stage = [&](int buf, int kt) {
        const int kv0 = kt << 5;
        char* baseK = smem + buf * 32768;
        char* baseV = smem + 65536 + buf * 16384;
#pragma unroll
        for (int ii = 0; ii < 2; ii++) {
            int j = wave * 2 + ii;
            int r = j * 2 + srl;
            size_t go = (((size_t)((bn << 10) + kv0 + r)) << 8) +
                        (unsigned)((ss ^ (r & 7)) << 3);
            gl_lds16(kh_ + go, baseK + j * 1024);
            gl_lds16(kl_ + go, baseK + 16384 + j * 1024);
            int d = j * 16 + vdl;
            size_t gv = (((size_t)((bn << 8) + d)) << 10) + kv0 +
                        (unsigned)((vg ^ ((d >> 1) & 3)) << 3);
            gl_lds16(vT + gv, baseV + j * 1024);
        }
    };

    f32x4 o[16];
#pragma unroll
    for (int i = 0; i < 16; i++) o[i] = (f32x4){0.f, 0.f, 0.f, 0.f};
    f32x4 ol = (f32x4){0.f, 0.f, 0.f, 0.f};
    float m[4] = {-INFINITY, -INFINITY, -INFINITY, -INFINITY};

    stage(0, 0);
    __syncthreads();
    for (int kt = 0; kt < nk; kt++) {
        const int cur = kt & 1;
        if (kt + 1 < nk) stage(cur ^ 1, kt + 1);
        if ((kt << 5) <= qr0 + 15) {   // this wave's strip still in range
            const char* kbK = smem + cur * 32768;
            f32x4 sc0 = (f32x4){0.f, 0.f, 0.f, 0.f};
            f32x4 sc1 = (f32x4){0.f, 0.f, 0.f, 0.f};
#pragma unroll
            for (int ck = 0; ck < 8; ck++) {
                int sw = ((ck * 4 + lg) ^ (lr & 7)) << 4;
                int a0 = lr * 512 + sw;
                int a1 = a0 + 16 * 512;
                bf16x8 kh0 = *(const bf16x8*)(kbK + a0);
                bf16x8 kh1 = *(const bf16x8*)(kbK + a1);
                bf16x8 kl0 = *(const bf16x8*)(kbK + 16384 + a0);
                bf16x8 kl1 = *(const bf16x8*)(kbK + 16384 + a1);
                sc0 = MFMA(qh[ck], kh0, sc0);
                sc1 = MFMA(qh[ck], kh1, sc1);
                sc0 = MFMA(ql[ck], kh0, sc0);
                sc1 = MFMA(ql[ck], kh1, sc1);
                sc0 = MFMA(qh[ck], kl0, sc0);
                sc1 = MFMA(qh[ck], kl1, sc1);
            }
            float scl[4];
            const int kvb = kt << 5;
#pragma unroll
            for (int r = 0; r < 4; r++) {
                int qi = qr0 + lg * 4 + r;
                float s0v = (kvb + lr > qi) ? -1e30f : sc0[r];
                float s1v = (kvb + 16 + lr > qi) ? -1e30f : sc1[r];
                float tm = red16_max(fmaxf(s0v, s1v));
                float mn = fmaxf(m[r], tm);
                scl[r] = __expf(m[r] - mn);
                m[r] = mn;
                int row = lg * 4 + r;
                Pw[row * 40 + lr] = f2b(__expf(s0v - mn));
                Pw[row * 40 + 16 + lr] = f2b(__expf(s1v - mn));
            }
#pragma unroll
            for (int f = 0; f < 16; f++) {
                f32x4 t = o[f];
                t[0] *= scl[0]; t[1] *= scl[1]; t[2] *= scl[2]; t[3] *= scl[3];
                o[f] = t;
            }
            ol[0] *= scl[0]; ol[1] *= scl[1]; ol[2] *= scl[2]; ol[3] *= scl[3];
            bf16x8 pa = *(const bf16x8*)((const char*)Pw + lr * 80 + lg * 16);
            const char* vb = smem + 65536 + cur * 16384;
#pragma unroll
            for (int db = 0; db < 16; db++) {
                int d = db * 16 + lr;
                bf16x8 vf = *(const bf16x8*)(vb + d * 64 +
                                             ((lg ^ ((lr >> 1) & 3)) << 4));
                o[db] = MFMA(pa, vf, o[db]);
            }
            ol = MFMA(pa, onesb, ol);
        }
        __syncthreads();
    }
    // epilogue: 1/l from ones-column (col 0 lanes), then fused LayerNorm
    float linv[4];
#pragma unroll
    for (int r = 0; r < 4; r++) linv[r] = 1.f / __shfl(ol[r], lane & 48, 64);
#pragma unroll
    for (int f = 0; f < 16; f++) {
        o[f][0] *= linv[0]; o[f][1] *= linv[1];
        o[f][2] *= linv[2]; o[f][3] *= linv[3];
    }
    float gv[16], bv[16];
#pragma unroll
    for (int f = 0; f < 16; f++) {
        gv[f] = g2[f * 16 + lr];
        bv[f] = b2[f * 16 + lr];
    }
#pragma unroll
    for (int r = 0; r < 4; r++) {
        float s1 = 0.f, s2 = 0.f;
#pragma unroll
        for (int f = 0; f < 16; f++) { float x = o[f][r]; s1 += x; s2 += x * x; }
        s1 = red16_sum(s1);
        s2 = red16_sum(s2);
        float mean = s1 * (1.f / 256.f);
        float var = s2 * (1.f / 256.f) - mean * mean;
        float rsv = rsqrtf(var + 1e-5f);
        size_t row = (size_t)(bn * 1024 + qr0 + lg * 4 + r) * 256;
#pragma unroll
        for (int f = 0; f < 16; f++)
            lnatt[row + f * 16 + lr] = f2b((o[f][r] - mean) * rsv * gv[f] + bv[f]);
    }
}

// ---------- K3/K4/K5: LDS-staged GEMM, A(MxK) bf16, BT(NxK) bf16 ----------
template <int K, int NB, int MODE>
__global__ __launch_bounds__(512) void gemmB_kernel(
    const u16* __restrict__ A, const u16* __restrict__ BT,
    u16* __restrict__ outb, const u16* __restrict__ vTr,
    float* __restrict__ outf, int ldOut) {
    extern __shared__ char bsm[];
    const int tid = threadIdx.x;
    const int wave = tid >> 6, lane = tid & 63, lr = lane & 15, lg = lane >> 4;
    constexpr int K2 = K * 2;           // bytes per B column
    constexpr int BN = NB * 16;
    constexpr int TILE = BN * K2;
    const int m0 = blockIdx.x * 128 + wave * 16;
    const int n0 = blockIdx.y * BN;
    {   // stage B tile; source pre-swizzled: phys slot s holds logical s^(col&7)
        const char* bsrc = (const char*)(BT + (size_t)n0 * K);
        constexpr int ITER = TILE / (512 * 16);
#pragma unroll
        for (int it = 0; it < ITER; it++) {
            int o = (it * 512 + tid) * 16;
            int col = o / K2;
            int slot = (o % K2) >> 4;
            int src = col * K2 + ((slot ^ (col & 7)) << 4);
            gl_lds16(bsrc + src, bsm + o);
        }
    }
    __syncthreads();
    f32x4 acc[NB];
#pragma unroll
    for (int nb = 0; nb < NB; nb++) acc[nb] = (f32x4){0.f, 0.f, 0.f, 0.f};
    const u16* ap = A + (size_t)(m0 + lr) * K + lg * 8;
#pragma unroll
    for (int kc = 0; kc < K; kc += 32) {
        bf16x8 a = *(const bf16x8*)(ap + kc);
        int ks = (kc >> 3) + lg;
#pragma unroll
        for (int nb = 0; nb < NB; nb++) {
            int c = nb * 16 + lr;
            bf16x8 bv = *(const bf16x8*)(bsm + c * K2 + ((ks ^ (c & 7)) << 4));
            acc[nb] = MFMA(a, bv, acc[nb]);
        }
    }
    const int g = m0 + lg * 4;
    if (MODE == 0) {
#pragma unroll
        for (int nb = 0; nb < NB; nb++)
#pragma unroll
            for (int r = 0; r < 4; r++)
                outb[(size_t)(g + r) * ldOut + n0 + nb * 16 + lr] =
                    f2b(fmaxf(acc[nb][r], 0.f));
    } else if (MODE == 1) {
        int bn = g >> 10, s = g & 1023;
#pragma unroll
        for (int nb = 0; nb < NB; nb++) {
            int dd = n0 + nb * 16 + lr;
            u16x4 vv = *(const u16x4*)(vTr + ((size_t)bn * 256 + dd) * 1024 + s);
#pragma unroll
            for (int r = 0; r < 4; r++)
                outb[(size_t)(g + r) * 256 + dd] = f2b(acc[nb][r] + b2f(vv[r]));
        }
    } else {
        int bn = g >> 10, s = g & 1023;
        int bb = bn >> 3, nn = bn & 7;
#pragma unroll
        for (int nb = 0; nb < NB; nb++) {
            int cc = n0 + nb * 16 + lr;
            *(f32x4*)(outf + (size_t)bb * 524288 + (size_t)cc * 8192 +
                      (size_t)nn * 1024 + s) = acc[nb];
        }
    }
}

extern "C" void kernel_launch(void* const* d_in, const int* in_sizes, int n_in,
                              void* d_out, int out_size, void* d_ws, size_t ws_size,
                              hipStream_t stream) {
    const float* lf    = (const float*)d_in[0];
    const float* hf    = (const float*)d_in[1];
    const float* Win   = (const float*)d_in[2];
    const float* Wkv   = (const float*)d_in[3];
    const float* gamma = (const float*)d_in[4];
    const float* beta  = (const float*)d_in[5];
    const float* g2    = (const float*)d_in[6];
    const float* b2    = (const float*)d_in[7];
    const float* W1    = (const float*)d_in[8];
    const float* W2    = (const float*)d_in[9];
    const float* Wo    = (const float*)d_in[10];
    float* out = (float*)d_out;

    char* w = (char*)d_ws;
    const size_t MB16 = 16777216;
    u16* qh  = (u16*)(w);
    u16* ql  = (u16*)(w + MB16);
    u16* kh  = (u16*)(w + 2 * MB16);
    u16* kl  = (u16*)(w + 3 * MB16);
    u16* vT  = (u16*)(w + 4 * MB16);
    u16* hb  = (u16*)(w + 5 * MB16);            // 33.55 MB
    u16* w1T = (u16*)(w + 5 * MB16 + 33554432);
    u16* w2T = w1T + 131072;
    u16* woT = w2T + 131072;
    u16* wfrag = woT + 16384;                   // 6 x 16384 u16 fragment weights
    u16* wqg = wfrag;
    u16* wkg = wfrag + 32768;
    u16* wvg = wfrag + 65536;
    u16* lnatt = qh;   // reuse: q rows consumed before LN write
    u16* epib  = kh;   // reuse: k dead after attention

    wconv_kernel<<<dim3(1136), dim3(256), 0, stream>>>(W1, W2, Wo, Win, Wkv,
                                                       w1T, w2T, woT, wfrag);
    proj_kernel<<<dim3(8, 32), dim3(512), 131072, stream>>>(
        lf, hf, wqg, wkg, wvg, gamma, beta, qh, ql, kh, kl, vT);
    attn_kernel<<<dim3(256), dim3(512), 108544, stream>>>(qh, ql, kh, kl, vT, g2, b2,
                                                          lnatt);
    gemmB_kernel<256, 8, 0><<<dim3(256, 4), dim3(512), 65536, stream>>>(
        lnatt, w1T, hb, nullptr, nullptr, 512);
    gemmB_kernel<512, 8, 1><<<dim3(256, 2), dim3(512), 131072, stream>>>(
        hb, w2T, epib, vT, nullptr, 256);
    gemmB_kernel<256, 4, 2><<<dim3(256, 1), dim3(512), 32768, stream>>>(
        epib, woT, nullptr, nullptr, out, 64);
}

// Round 9
// 149.745 us; speedup vs baseline: 4.0565x; 1.0962x over previous
//
#include <hip/hip_runtime.h>

typedef short bf16x8 __attribute__((ext_vector_type(8)));
typedef _Float16 f16x8 __attribute__((ext_vector_type(8)));
typedef float f32x4 __attribute__((ext_vector_type(4)));
typedef unsigned short u16;
typedef unsigned short u16x4 __attribute__((ext_vector_type(4)));

#define MFMA(a, b, c) __builtin_amdgcn_mfma_f32_16x16x32_bf16(a, b, c, 0, 0, 0)
#define MFMAH(a, b, c) __builtin_amdgcn_mfma_f32_16x16x32_f16(a, b, c, 0, 0, 0)

// ---------- helpers ----------
__device__ __forceinline__ u16 f2b(float f) {
    union { float f; unsigned u; } x{f};
    unsigned r = (x.u + 0x7FFFu + ((x.u >> 16) & 1u)) >> 16;
    return (u16)r;
}
__device__ __forceinline__ float b2f(u16 h) {
    union { unsigned u; float f; } x{((unsigned)h) << 16};
    return x.f;
}
__device__ __forceinline__ u16 f2h(float f) {
    _Float16 h = (_Float16)f;
    return *reinterpret_cast<u16*>(&h);
}
__device__ __forceinline__ float h2f(u16 h) {
    _Float16 v = *reinterpret_cast<_Float16*>(&h);
    return (float)v;
}
__device__ __forceinline__ float red16_sum(float v) {
#pragma unroll
    for (int m = 1; m < 16; m <<= 1) v += __shfl_xor(v, m, 64);
    return v;
}
__device__ __forceinline__ float red16_max(float v) {
#pragma unroll
    for (int m = 1; m < 16; m <<= 1) v = fmaxf(v, __shfl_xor(v, m, 64));
    return v;
}
__device__ __forceinline__ void gl_lds16(const void* g, void* l) {
    __builtin_amdgcn_global_load_lds(
        (const __attribute__((address_space(1))) unsigned int*)(g),
        (__attribute__((address_space(3))) unsigned int*)(l), 16, 0, 0);
}

// dims: B=4, C=64, N=8, V=32, W=32, D=256 ; BN=32, S=1024, tokens M=32768

// ---------- K0: weight convert: gemm weights + fragment-packed proj weights ----------
__global__ __launch_bounds__(256) void wconv_kernel(
    const float* __restrict__ W1, const float* __restrict__ W2,
    const float* __restrict__ Wo, const float* __restrict__ Win,
    const float* __restrict__ Wkv, u16* __restrict__ w1T,
    u16* __restrict__ w2T, u16* __restrict__ woT, u16* __restrict__ wfrag) {
    int id = blockIdx.x * 256 + threadIdx.x;
    if (id < 131072) {                       // W1: (256,512) -> (512,256)
        int n = id >> 8, k = id & 255;
        w1T[id] = f2b(W1[k * 512 + n]);
    } else if (id < 262144) {                // W2: (512,256) -> (256,512)
        int j = id - 131072;
        int n = j >> 9, k = j & 511;
        w2T[j] = f2b(W2[k * 256 + n]);
    } else if (id < 278528) {                // W_out: (256,64) -> (64,256)
        int j = id - 262144;
        int n = j >> 8, k = j & 255;
        woT[j] = f2b(Wo[k * 64 + n]);
    } else if (id < 290816) {                // fragment-packed proj weights
        int fid = id - 278528;
        int arr = fid >> 11;                 // 0..5
        int e = fid & 2047;
        int ntck = e >> 6, ln = e & 63;
        int lr = ln & 15, lg2 = ln >> 4;
        int nt = ntck >> 1, ck = ntck & 1;
        int d = nt * 16 + lr;
#pragma unroll
        for (int j = 0; j < 8; j++) {
            int c = ck * 32 + lg2 * 8 + j;
            float x;
            if (arr < 2)       x = Win[c * 256 + d];
            else if (arr < 4)  x = Wkv[c * 512 + d];
            else               x = Wkv[c * 512 + 256 + d];
            u16 h = f2b(x);
            u16 v = (arr & 1) ? f2b(x - b2f(h)) : h;
            wfrag[arr * 16384 + e * 8 + j] = v;
        }
    }
}

// ---------- K1: MFMA projection + shared LN (split-bf16 compute, fp16 emit) ----------
#define PJ_AH 0
#define PJ_AL 16384
#define PJ_WREG 32768
#define PJ_WORK 98304
__global__ __launch_bounds__(512, 1) void proj_kernel(
    const float* __restrict__ lf, const float* __restrict__ hf,
    const u16* __restrict__ wqg, const u16* __restrict__ wkg,
    const u16* __restrict__ wvg, const float* __restrict__ gamma,
    const float* __restrict__ beta, u16* __restrict__ qf_,
    u16* __restrict__ kf_, u16* __restrict__ vT) {
    extern __shared__ char sm[];
    const int tid = threadIdx.x;
    const int wave = tid >> 6, lane = tid & 63, lr = lane & 15, lg = lane >> 4;
    const int st = blockIdx.x, bn = blockIdx.y;
    const int b = bn >> 3, n = bn & 7;
    const int s0 = st * 128;
    const size_t baseF = (size_t)b * 524288 + (size_t)n * 1024 + s0;

    float gam[16], bet[16];
#pragma unroll
    for (int nt = 0; nt < 16; nt++) {
        gam[nt] = gamma[nt * 16 + lr];
        bet[nt] = beta[nt * 16 + lr];
    }

    auto stage32 = [&](const float* srcbase, int chalf) {
#pragma unroll
        for (int call = 0; call < 2; call++) {
            int unit = call * 8 + wave;
            int obase = unit << 10;
            int e = unit * 256 + lane * 4;
            int cl = e >> 7, si = e & 127;
            gl_lds16(srcbase + (size_t)(chalf * 32 + cl) * 8192 + si,
                     sm + PJ_WORK + obase);
        }
    };
    auto stageW = [&](const u16* wsrc) {
#pragma unroll
        for (int call = 0; call < 8; call++) {
            int obase = (call * 8 + wave) << 10;
            gl_lds16((const char*)wsrc + obase + lane * 16, sm + PJ_WREG + obase);
        }
    };
    auto buildA = [&](int slotbase) {
        int g = wave >> 1;
        int s = ((wave & 1) << 6) | lane;
        float x[8];
#pragma unroll
        for (int cc = 0; cc < 8; cc++)
            x[cc] = *(const float*)(sm + PJ_WORK + ((g * 8 + cc) << 9) + (s << 2));
        bf16x8 ph, pl;
#pragma unroll
        for (int cc = 0; cc < 8; cc++) {
            u16 h = f2b(x[cc]);
            ph[cc] = (short)h;
            pl[cc] = (short)f2b(x[cc] - b2f(h));
        }
        int slp = (slotbase + g) ^ (s & 7);
        *(bf16x8*)(sm + PJ_AH + (s << 7) + (slp << 4)) = ph;
        *(bf16x8*)(sm + PJ_AL + (s << 7) + (slp << 4)) = pl;
    };
    auto loadA = [&](bf16x8* aH, bf16x8* aL) {
        int tl = wave * 16 + lr;
#pragma unroll
        for (int ck = 0; ck < 2; ck++) {
            int off = (tl << 7) + ((((ck << 2) | lg) ^ (tl & 7)) << 4);
            aH[ck] = *(const bf16x8*)(sm + PJ_AH + off);
            aL[ck] = *(const bf16x8*)(sm + PJ_AL + off);
        }
    };
    auto pass3 = [&](const bf16x8* aH, const bf16x8* aL, f32x4* acc) {
#pragma unroll
        for (int nt = 0; nt < 16; nt++) acc[nt] = (f32x4){0.f, 0.f, 0.f, 0.f};
#pragma unroll
        for (int nt = 0; nt < 16; nt++) {
#pragma unroll
            for (int ck = 0; ck < 2; ck++) {
                int wo = (((nt << 1) | ck) << 10) + (lane << 4);
                bf16x8 bh = *(const bf16x8*)(sm + PJ_WREG + wo);
                bf16x8 bl = *(const bf16x8*)(sm + PJ_WREG + 32768 + wo);
                acc[nt] = MFMA(aH[ck], bh, acc[nt]);
                acc[nt] = MFMA(aL[ck], bh, acc[nt]);
                acc[nt] = MFMA(aH[ck], bl, acc[nt]);
            }
        }
    };
    auto lnstats = [&](const f32x4* acc, float* mean, float* rs) {
#pragma unroll
        for (int r = 0; r < 4; r++) {
            float s1 = 0.f, s2 = 0.f;
#pragma unroll
            for (int nt = 0; nt < 16; nt++) {
                float xv = acc[nt][r];
                s1 += xv; s2 += xv * xv;
            }
            s1 = red16_sum(s1);
            s2 = red16_sum(s2);
            float mn = s1 * (1.f / 256.f);
            float var = s2 * (1.f / 256.f) - mn * mn;
            mean[r] = mn;
            rs[r] = rsqrtf(var + 1e-5f);
        }
    };
    // LN + fp16 emission via per-wave 4KB bounce, 16B-coalesced stores
    auto emit = [&](const f32x4* acc, const float* mean, const float* rs,
                    u16* dst) {
        char* bw = sm + PJ_WORK + wave * 4096;
        const int gtok = bn * 1024 + s0 + wave * 16;
#pragma unroll
        for (int hh = 0; hh < 2; hh++) {
#pragma unroll
            for (int ntl = 0; ntl < 8; ntl++) {
                int nt = hh * 8 + ntl;
#pragma unroll
                for (int r = 0; r < 4; r++) {
                    float y = (acc[nt][r] - mean[r]) * rs[r] * gam[nt] + bet[nt];
                    int tl = lg * 4 + r;
                    int dl = ntl * 16 + lr;
                    int sl = dl >> 3;
                    *(u16*)(bw + tl * 256 + ((sl ^ ((tl >> 2) & 3)) << 4) +
                            (dl & 7) * 2) = f2h(y);
                }
            }
#pragma unroll
            for (int p = 0; p < 4; p++) {
                int row = lane >> 2, slq = (lane & 3) + p * 4;
                bf16x8 v8 = *(const bf16x8*)(bw + row * 256 +
                                             ((slq ^ ((row >> 2) & 3)) << 4));
                *(bf16x8*)(dst + (size_t)(gtok + row) * 256 + hh * 128 +
                           slq * 8) = v8;
            }
        }
    };

    f32x4 acc[16];
    float mean[4], rs[4];
    bf16x8 aH[2], aL[2];

    // ---- lf -> q ----
    stage32(lf + baseF, 0);  __syncthreads();     // P0
    buildA(0);               __syncthreads();     // P1
    stage32(lf + baseF, 1);
    stageW(wqg);             __syncthreads();     // P2
    buildA(4);               __syncthreads();     // P3
    loadA(aH, aL);
    pass3(aH, aL, acc);
    lnstats(acc, mean, rs);  __syncthreads();     // P4
    stageW(wkg);                                  // P5
    emit(acc, mean, rs, qf_);
    __syncthreads();
    // ---- hf -> k, v ----
    stage32(hf + baseF, 0);  __syncthreads();     // P6
    buildA(0);               __syncthreads();     // P7
    stage32(hf + baseF, 1);  __syncthreads();     // P8
    buildA(4);               __syncthreads();     // P9
    loadA(aH, aL);
    pass3(aH, aL, acc);
    lnstats(acc, mean, rs);  __syncthreads();     // P10
    stageW(wvg);                                  // P11
    emit(acc, mean, rs, kf_);
    __syncthreads();
    pass3(aH, aL, acc);                           // P12: v
#pragma unroll
    for (int nt = 0; nt < 16; nt++) {
        u16x4 pv;
#pragma unroll
        for (int r = 0; r < 4; r++) pv[r] = f2h(acc[nt][r]);
        *(u16x4*)(vT + ((size_t)(bn * 256) + nt * 16 + lr) * 1024 + s0 +
                  wave * 16 + lg * 4) = pv;
    }
}

// ---------- K2: causal flash attention, fp16, one 64-row strip per block ----------
// 512 blocks, 256 threads (4 waves x 16 q-rows). idx<256 -> strips 0..7,
// idx>=256 -> strips 15..8; bn = idx%32 keeps same-bn blocks on one XCD
// (idx%8 == bn%8). 2 blocks/CU (LDS 69KB) -> co-resident {s,15-s} pair,
// uniform 34 iters/CU, every wave active ~97% of its block's iterations.
// LDS: K dbuf 2x16KB @0; V dbuf 2x16KB @32768; P @65536 (4x1280B, 80B rows).
__global__ __launch_bounds__(256) void attn_kernel(
    const u16* __restrict__ qf_, const u16* __restrict__ kf_,
    const u16* __restrict__ vT, const float* __restrict__ g2,
    const float* __restrict__ b2, u16* __restrict__ lnatt) {
    extern __shared__ char smem[];
    const int tid = threadIdx.x;
    const int wave = tid >> 6, lane = tid & 63, lr = lane & 15, lg = lane >> 4;
    const int idx = blockIdx.x;
    const int j = idx & 255;
    const int bn = j & 31, si = j >> 5;
    const int strip = (idx >= 256) ? (15 - si) : si;
    const int qr0 = strip * 64 + wave * 16;
    const int nk = 2 * strip + 2;
    u16* Pw = (u16*)(smem + 65536 + wave * 1280);   // [16 rows][40 u16]

    // Q fragments (fp16)
    f16x8 qf[8];
    {
        const size_t off = ((size_t)(bn * 1024 + qr0 + lr)) * 256 + lg * 8;
#pragma unroll
        for (int ck = 0; ck < 8; ck++)
            qf[ck] = *(const f16x8*)(qf_ + off + ck * 32);
    }
    f16x8 onesb;   // B-fragment of ones-column (row-sum via MFMA)
    {
        _Float16 v1 = (lr == 0) ? (_Float16)1.0f : (_Float16)0.0f;
#pragma unroll
        for (int q = 0; q < 8; q++) onesb[q] = v1;
    }

    const int srl = lane >> 5, ss = lane & 31;   // K staging: subrow, slot
    const int vdl = lane >> 2, vg = lane & 3;    // V staging: d-local, group
    // stage tile kt: 8 gl_lds16 per wave (4 K + 4 V), source pre-swizzled.
    auto stage = [&](int buf, int kt) {
        const int kv0 = kt << 5;
        char* baseK = smem + buf * 16384;
        char* baseV = smem + 32768 + buf * 16384;
#pragma unroll
        for (int ii = 0; ii < 4; ii++) {
            int u = wave * 4 + ii;                 // 0..15, 1KB units
            int r = u * 2 + srl;                   // K row 0..31
            size_t go = (((size_t)((bn << 10) + kv0 + r)) << 8) +
                        (unsigned)((ss ^ (r & 7)) << 3);
            gl_lds16(kf_ + go, baseK + u * 1024);
            int d = u * 16 + vdl;                  // V d 0..255
            size_t gv = (((size_t)((bn << 8) + d)) << 10) + kv0 +
                        (unsigned)((vg ^ ((d >> 1) & 3)) << 3);
            gl_lds16(vT + gv, baseV + u * 1024);
        }
    };

    f32x4 o[16];
#pragma unroll
    for (int i = 0; i < 16; i++) o[i] = (f32x4){0.f, 0.f, 0.f, 0.f};
    f32x4 ol = (f32x4){0.f, 0.f, 0.f, 0.f};
    float m[4] = {-INFINITY, -INFINITY, -INFINITY, -INFINITY};

    stage(0, 0);
    __syncthreads();
    for (int kt = 0; kt < nk; kt++) {
        const int cur = kt & 1;
        if (kt + 1 < nk) stage(cur ^ 1, kt + 1);
        if ((kt << 5) <= qr0 + 15) {
            const char* kb = smem + cur * 16384;
            f32x4 sc0 = (f32x4){0.f, 0.f, 0.f, 0.f};
            f32x4 sc1 = (f32x4){0.f, 0.f, 0.f, 0.f};
#pragma unroll
            for (int ck = 0; ck < 8; ck++) {
                int sw = ((ck * 4 + lg) ^ (lr & 7)) << 4;
                int a0 = lr * 512 + sw;
                f16x8 k0 = *(const f16x8*)(kb + a0);
                f16x8 k1 = *(const f16x8*)(kb + a0 + 8192);
                sc0 = MFMAH(qf[ck], k0, sc0);
                sc1 = MFMAH(qf[ck], k1, sc1);
            }
            float scl[4];
            const int kvb = kt << 5;
#pragma unroll
            for (int r = 0; r < 4; r++) {
                int qi = qr0 + lg * 4 + r;
                float s0v = (kvb + lr > qi) ? -1e30f : sc0[r];
                float s1v = (kvb + 16 + lr > qi) ? -1e30f : sc1[r];
                float tm = red16_max(fmaxf(s0v, s1v));
                float mn = fmaxf(m[r], tm);
                scl[r] = __expf(m[r] - mn);
                m[r] = mn;
                int row = lg * 4 + r;
                Pw[row * 40 + lr] = f2h(__expf(s0v - mn));
                Pw[row * 40 + 16 + lr] = f2h(__expf(s1v - mn));
            }
#pragma unroll
            for (int f = 0; f < 16; f++) {
                f32x4 t = o[f];
                t[0] *= scl[0]; t[1] *= scl[1]; t[2] *= scl[2]; t[3] *= scl[3];
                o[f] = t;
            }
            ol[0] *= scl[0]; ol[1] *= scl[1]; ol[2] *= scl[2]; ol[3] *= scl[3];
            f16x8 pa = *(const f16x8*)((const char*)Pw + lr * 80 + lg * 16);
            const char* vb = smem + 32768 + cur * 16384;
#pragma unroll
            for (int db = 0; db < 16; db++) {
                int d = db * 16 + lr;
                f16x8 vf = *(const f16x8*)(vb + d * 64 +
                                           ((lg ^ ((lr >> 1) & 3)) << 4));
                o[db] = MFMAH(pa, vf, o[db]);
            }
            ol = MFMAH(pa, onesb, ol);
        }
        __syncthreads();
    }
    // epilogue: 1/l from ones-column, then fused LayerNorm -> bf16
    float linv[4];
#pragma unroll
    for (int r = 0; r < 4; r++) linv[r] = 1.f / __shfl(ol[r], lane & 48, 64);
#pragma unroll
    for (int f = 0; f < 16; f++) {
        o[f][0] *= linv[0]; o[f][1] *= linv[1];
        o[f][2] *= linv[2]; o[f][3] *= linv[3];
    }
    float gv[16], bv[16];
#pragma unroll
    for (int f = 0; f < 16; f++) {
        gv[f] = g2[f * 16 + lr];
        bv[f] = b2[f * 16 + lr];
    }
#pragma unroll
    for (int r = 0; r < 4; r++) {
        float s1 = 0.f, s2 = 0.f;
#pragma unroll
        for (int f = 0; f < 16; f++) { float x = o[f][r]; s1 += x; s2 += x * x; }
        s1 = red16_sum(s1);
        s2 = red16_sum(s2);
        float mean = s1 * (1.f / 256.f);
        float var = s2 * (1.f / 256.f) - mean * mean;
        float rsv = rsqrtf(var + 1e-5f);
        size_t row = (size_t)(bn * 1024 + qr0 + lg * 4 + r) * 256;
#pragma unroll
        for (int f = 0; f < 16; f++)
            lnatt[row + f * 16 + lr] = f2b((o[f][r] - mean) * rsv * gv[f] + bv[f]);
    }
}

// ---------- K3/K4/K5: LDS-staged GEMM, A(MxK) bf16, BT(NxK) bf16 ----------
template <int K, int NB, int MODE>
__global__ __launch_bounds__(512) void gemmB_kernel(
    const u16* __restrict__ A, const u16* __restrict__ BT,
    u16* __restrict__ outb, const u16* __restrict__ vTr,
    float* __restrict__ outf, int ldOut) {
    extern __shared__ char bsm[];
    const int tid = threadIdx.x;
    const int wave = tid >> 6, lane = tid & 63, lr = lane & 15, lg = lane >> 4;
    constexpr int K2 = K * 2;           // bytes per B column
    constexpr int BN = NB * 16;
    constexpr int TILE = BN * K2;
    const int m0 = blockIdx.x * 128 + wave * 16;
    const int n0 = blockIdx.y * BN;
    {
        const char* bsrc = (const char*)(BT + (size_t)n0 * K);
        constexpr int ITER = TILE / (512 * 16);
#pragma unroll
        for (int it = 0; it < ITER; it++) {
            int o = (it * 512 + tid) * 16;
            int col = o / K2;
            int slot = (o % K2) >> 4;
            int src = col * K2 + ((slot ^ (col & 7)) << 4);
            gl_lds16(bsrc + src, bsm + o);
        }
    }
    __syncthreads();
    f32x4 acc[NB];
#pragma unroll
    for (int nb = 0; nb < NB; nb++) acc[nb] = (f32x4){0.f, 0.f, 0.f, 0.f};
    const u16* ap = A + (size_t)(m0 + lr) * K + lg * 8;
#pragma unroll
    for (int kc = 0; kc < K; kc += 32) {
        bf16x8 a = *(const bf16x8*)(ap + kc);
        int ks = (kc >> 3) + lg;
#pragma unroll
        for (int nb = 0; nb < NB; nb++) {
            int c = nb * 16 + lr;
            bf16x8 bv = *(const bf16x8*)(bsm + c * K2 + ((ks ^ (c & 7)) << 4));
            acc[nb] = MFMA(a, bv, acc[nb]);
        }
    }
    const int g = m0 + lg * 4;
    if (MODE == 0) {
#pragma unroll
        for (int nb = 0; nb < NB; nb++)
#pragma unroll
            for (int r = 0; r < 4; r++)
                outb[(size_t)(g + r) * ldOut + n0 + nb * 16 + lr] =
                    f2b(fmaxf(acc[nb][r], 0.f));
    } else if (MODE == 1) {
        int bn = g >> 10, s = g & 1023;
#pragma unroll
        for (int nb = 0; nb < NB; nb++) {
            int dd = n0 + nb * 16 + lr;
            u16x4 vv = *(const u16x4*)(vTr + ((size_t)bn * 256 + dd) * 1024 + s);
#pragma unroll
            for (int r = 0; r < 4; r++)
                outb[(size_t)(g + r) * 256 + dd] = f2b(acc[nb][r] + h2f(vv[r]));
        }
    } else {
        int bn = g >> 10, s = g & 1023;
        int bb = bn >> 3, nn = bn & 7;
#pragma unroll
        for (int nb = 0; nb < NB; nb++) {
            int cc = n0 + nb * 16 + lr;
            *(f32x4*)(outf + (size_t)bb * 524288 + (size_t)cc * 8192 +
                      (size_t)nn * 1024 + s) = acc[nb];
        }
    }
}

extern "C" void kernel_launch(void* const* d_in, const int* in_sizes, int n_in,
                              void* d_out, int out_size, void* d_ws, size_t ws_size,
                              hipStream_t stream) {
    const float* lf    = (const float*)d_in[0];
    const float* hf    = (const float*)d_in[1];
    const float* Win   = (const float*)d_in[2];
    const float* Wkv   = (const float*)d_in[3];
    const float* gamma = (const float*)d_in[4];
    const float* beta  = (const float*)d_in[5];
    const float* g2    = (const float*)d_in[6];
    const float* b2    = (const float*)d_in[7];
    const float* W1    = (const float*)d_in[8];
    const float* W2    = (const float*)d_in[9];
    const float* Wo    = (const float*)d_in[10];
    float* out = (float*)d_out;

    char* w = (char*)d_ws;
    const size_t MB16 = 16777216;
    u16* qf  = (u16*)(w);                        // fp16 q (16.78 MB)
    u16* kf  = (u16*)(w + MB16);                 // fp16 k
    u16* vT  = (u16*)(w + 2 * MB16);             // fp16 v, (BN,256,1024)
    u16* hb  = (u16*)(w + 3 * MB16);             // bf16 FFN hidden (33.55 MB)
    u16* w1T = (u16*)(w + 3 * MB16 + 33554432);
    u16* w2T = w1T + 131072;
    u16* woT = w2T + 131072;
    u16* wfrag = woT + 16384;                    // 6 x 16384 u16
    u16* wqg = wfrag;
    u16* wkg = wfrag + 32768;
    u16* wvg = wfrag + 65536;
    u16* lnatt = qf;   // reuse: q rows consumed before LN write (bf16)
    u16* epib  = kf;   // reuse: k dead after attention (bf16)

    wconv_kernel<<<dim3(1136), dim3(256), 0, stream>>>(W1, W2, Wo, Win, Wkv,
                                                       w1T, w2T, woT, wfrag);
    proj_kernel<<<dim3(8, 32), dim3(512), 131072, stream>>>(
        lf, hf, wqg, wkg, wvg, gamma, beta, qf, kf, vT);
    attn_kernel<<<dim3(512), dim3(256), 70656, stream>>>(qf, kf, vT, g2, b2,
                                                         lnatt);
    gemmB_kernel<256, 8, 0><<<dim3(256, 4), dim3(512), 65536, stream>>>(
        lnatt, w1T, hb, nullptr, nullptr, 512);
    gemmB_kernel<512, 8, 1><<<dim3(256, 2), dim3(512), 131072, stream>>>(
        hb, w2T, epib, vT, nullptr, 256);
    gemmB_kernel<256, 4, 2><<<dim3(256, 1), dim3(512), 32768, stream>>>(
        epib, woT, nullptr, nullptr, out, 64);
}

// Round 10
// 135.089 us; speedup vs baseline: 4.4966x; 1.1085x over previous
//
#include <hip/hip_runtime.h>

typedef short bf16x8 __attribute__((ext_vector_type(8)));
typedef _Float16 f16x8 __attribute__((ext_vector_type(8)));
typedef float f32x4 __attribute__((ext_vector_type(4)));
typedef unsigned short u16;
typedef unsigned short u16x4 __attribute__((ext_vector_type(4)));

#define MFMA(a, b, c) __builtin_amdgcn_mfma_f32_16x16x32_bf16(a, b, c, 0, 0, 0)
#define MFMAH(a, b, c) __builtin_amdgcn_mfma_f32_16x16x32_f16(a, b, c, 0, 0, 0)

// ---------- helpers ----------
__device__ __forceinline__ u16 f2b(float f) {
    union { float f; unsigned u; } x{f};
    unsigned r = (x.u + 0x7FFFu + ((x.u >> 16) & 1u)) >> 16;
    return (u16)r;
}
__device__ __forceinline__ float b2f(u16 h) {
    union { unsigned u; float f; } x{((unsigned)h) << 16};
    return x.f;
}
__device__ __forceinline__ u16 f2h(float f) {
    _Float16 h = (_Float16)f;
    return *reinterpret_cast<u16*>(&h);
}
__device__ __forceinline__ float h2f(u16 h) {
    _Float16 v = *reinterpret_cast<_Float16*>(&h);
    return (float)v;
}
__device__ __forceinline__ float red16_sum(float v) {
#pragma unroll
    for (int m = 1; m < 16; m <<= 1) v += __shfl_xor(v, m, 64);
    return v;
}
__device__ __forceinline__ float red16_max(float v) {
#pragma unroll
    for (int m = 1; m < 16; m <<= 1) v = fmaxf(v, __shfl_xor(v, m, 64));
    return v;
}
__device__ __forceinline__ void gl_lds16(const void* g, void* l) {
    __builtin_amdgcn_global_load_lds(
        (const __attribute__((address_space(1))) unsigned int*)(g),
        (__attribute__((address_space(3))) unsigned int*)(l), 16, 0, 0);
}

// dims: B=4, C=64, N=8, V=32, W=32, D=256 ; BN=32, S=1024, tokens M=32768

// ---------- K0: weight convert: gemm weights + fragment-packed proj weights ----------
__global__ __launch_bounds__(256) void wconv_kernel(
    const float* __restrict__ W1, const float* __restrict__ W2,
    const float* __restrict__ Wo, const float* __restrict__ Win,
    const float* __restrict__ Wkv, u16* __restrict__ w1T,
    u16* __restrict__ w2T, u16* __restrict__ woT, u16* __restrict__ wfrag) {
    int id = blockIdx.x * 256 + threadIdx.x;
    if (id < 131072) {                       // W1: (256,512) -> (512,256)
        int n = id >> 8, k = id & 255;
        w1T[id] = f2b(W1[k * 512 + n]);
    } else if (id < 262144) {                // W2: (512,256) -> (256,512)
        int j = id - 131072;
        int n = j >> 9, k = j & 511;
        w2T[j] = f2b(W2[k * 256 + n]);
    } else if (id < 278528) {                // W_out: (256,64) -> (64,256)
        int j = id - 262144;
        int n = j >> 8, k = j & 255;
        woT[j] = f2b(Wo[k * 64 + n]);
    } else if (id < 290816) {                // fragment-packed proj weights
        int fid = id - 278528;
        int arr = fid >> 11;                 // 0..5
        int e = fid & 2047;
        int ntck = e >> 6, ln = e & 63;
        int lr = ln & 15, lg2 = ln >> 4;
        int nt = ntck >> 1, ck = ntck & 1;
        int d = nt * 16 + lr;
#pragma unroll
        for (int j = 0; j < 8; j++) {
            int c = ck * 32 + lg2 * 8 + j;
            float x;
            if (arr < 2)       x = Win[c * 256 + d];
            else if (arr < 4)  x = Wkv[c * 512 + d];
            else               x = Wkv[c * 512 + 256 + d];
            u16 h = f2b(x);
            u16 v = (arr & 1) ? f2b(x - b2f(h)) : h;
            wfrag[arr * 16384 + e * 8 + j] = v;
        }
    }
}

// ---------- K1: MFMA projection + shared LN (split-bf16 compute, fp16 emit) ----------
#define PJ_AH 0
#define PJ_AL 16384
#define PJ_WREG 32768
#define PJ_WORK 98304
__global__ __launch_bounds__(512, 1) void proj_kernel(
    const float* __restrict__ lf, const float* __restrict__ hf,
    const u16* __restrict__ wqg, const u16* __restrict__ wkg,
    const u16* __restrict__ wvg, const float* __restrict__ gamma,
    const float* __restrict__ beta, u16* __restrict__ qf_,
    u16* __restrict__ kf_, u16* __restrict__ vT) {
    extern __shared__ char sm[];
    const int tid = threadIdx.x;
    const int wave = tid >> 6, lane = tid & 63, lr = lane & 15, lg = lane >> 4;
    const int st = blockIdx.x, bn = blockIdx.y;
    const int b = bn >> 3, n = bn & 7;
    const int s0 = st * 128;
    const size_t baseF = (size_t)b * 524288 + (size_t)n * 1024 + s0;

    float gam[16], bet[16];
#pragma unroll
    for (int nt = 0; nt < 16; nt++) {
        gam[nt] = gamma[nt * 16 + lr];
        bet[nt] = beta[nt * 16 + lr];
    }

    auto stage32 = [&](const float* srcbase, int chalf) {
#pragma unroll
        for (int call = 0; call < 2; call++) {
            int unit = call * 8 + wave;
            int obase = unit << 10;
            int e = unit * 256 + lane * 4;
            int cl = e >> 7, si = e & 127;
            gl_lds16(srcbase + (size_t)(chalf * 32 + cl) * 8192 + si,
                     sm + PJ_WORK + obase);
        }
    };
    auto stageW = [&](const u16* wsrc) {
#pragma unroll
        for (int call = 0; call < 8; call++) {
            int obase = (call * 8 + wave) << 10;
            gl_lds16((const char*)wsrc + obase + lane * 16, sm + PJ_WREG + obase);
        }
    };
    auto buildA = [&](int slotbase) {
        int g = wave >> 1;
        int s = ((wave & 1) << 6) | lane;
        float x[8];
#pragma unroll
        for (int cc = 0; cc < 8; cc++)
            x[cc] = *(const float*)(sm + PJ_WORK + ((g * 8 + cc) << 9) + (s << 2));
        bf16x8 ph, pl;
#pragma unroll
        for (int cc = 0; cc < 8; cc++) {
            u16 h = f2b(x[cc]);
            ph[cc] = (short)h;
            pl[cc] = (short)f2b(x[cc] - b2f(h));
        }
        int slp = (slotbase + g) ^ (s & 7);
        *(bf16x8*)(sm + PJ_AH + (s << 7) + (slp << 4)) = ph;
        *(bf16x8*)(sm + PJ_AL + (s << 7) + (slp << 4)) = pl;
    };
    auto loadA = [&](bf16x8* aH, bf16x8* aL) {
        int tl = wave * 16 + lr;
#pragma unroll
        for (int ck = 0; ck < 2; ck++) {
            int off = (tl << 7) + ((((ck << 2) | lg) ^ (tl & 7)) << 4);
            aH[ck] = *(const bf16x8*)(sm + PJ_AH + off);
            aL[ck] = *(const bf16x8*)(sm + PJ_AL + off);
        }
    };
    auto pass3 = [&](const bf16x8* aH, const bf16x8* aL, f32x4* acc) {
#pragma unroll
        for (int nt = 0; nt < 16; nt++) acc[nt] = (f32x4){0.f, 0.f, 0.f, 0.f};
#pragma unroll
        for (int nt = 0; nt < 16; nt++) {
#pragma unroll
            for (int ck = 0; ck < 2; ck++) {
                int wo = (((nt << 1) | ck) << 10) + (lane << 4);
                bf16x8 bh = *(const bf16x8*)(sm + PJ_WREG + wo);
                bf16x8 bl = *(const bf16x8*)(sm + PJ_WREG + 32768 + wo);
                acc[nt] = MFMA(aH[ck], bh, acc[nt]);
                acc[nt] = MFMA(aL[ck], bh, acc[nt]);
                acc[nt] = MFMA(aH[ck], bl, acc[nt]);
            }
        }
    };
    auto lnstats = [&](const f32x4* acc, float* mean, float* rs) {
#pragma unroll
        for (int r = 0; r < 4; r++) {
            float s1 = 0.f, s2 = 0.f;
#pragma unroll
            for (int nt = 0; nt < 16; nt++) {
                float xv = acc[nt][r];
                s1 += xv; s2 += xv * xv;
            }
            s1 = red16_sum(s1);
            s2 = red16_sum(s2);
            float mn = s1 * (1.f / 256.f);
            float var = s2 * (1.f / 256.f) - mn * mn;
            mean[r] = mn;
            rs[r] = rsqrtf(var + 1e-5f);
        }
    };
    // LN + fp16 emission via per-wave 4KB bounce, 16B-coalesced stores
    auto emit = [&](const f32x4* acc, const float* mean, const float* rs,
                    u16* dst) {
        char* bw = sm + PJ_WORK + wave * 4096;
        const int gtok = bn * 1024 + s0 + wave * 16;
#pragma unroll
        for (int hh = 0; hh < 2; hh++) {
#pragma unroll
            for (int ntl = 0; ntl < 8; ntl++) {
                int nt = hh * 8 + ntl;
#pragma unroll
                for (int r = 0; r < 4; r++) {
                    float y = (acc[nt][r] - mean[r]) * rs[r] * gam[nt] + bet[nt];
                    int tl = lg * 4 + r;
                    int dl = ntl * 16 + lr;
                    int sl = dl >> 3;
                    *(u16*)(bw + tl * 256 + ((sl ^ ((tl >> 2) & 3)) << 4) +
                            (dl & 7) * 2) = f2h(y);
                }
            }
#pragma unroll
            for (int p = 0; p < 4; p++) {
                int row = lane >> 2, slq = (lane & 3) + p * 4;
                bf16x8 v8 = *(const bf16x8*)(bw + row * 256 +
                                             ((slq ^ ((row >> 2) & 3)) << 4));
                *(bf16x8*)(dst + (size_t)(gtok + row) * 256 + hh * 128 +
                           slq * 8) = v8;
            }
        }
    };

    f32x4 acc[16];
    float mean[4], rs[4];
    bf16x8 aH[2], aL[2];

    // ---- lf -> q ----
    stage32(lf + baseF, 0);  __syncthreads();     // P0
    buildA(0);               __syncthreads();     // P1
    stage32(lf + baseF, 1);
    stageW(wqg);             __syncthreads();     // P2
    buildA(4);               __syncthreads();     // P3
    loadA(aH, aL);
    pass3(aH, aL, acc);
    lnstats(acc, mean, rs);  __syncthreads();     // P4
    stageW(wkg);                                  // P5
    emit(acc, mean, rs, qf_);
    __syncthreads();
    // ---- hf -> k, v ----
    stage32(hf + baseF, 0);  __syncthreads();     // P6
    buildA(0);               __syncthreads();     // P7
    stage32(hf + baseF, 1);  __syncthreads();     // P8
    buildA(4);               __syncthreads();     // P9
    loadA(aH, aL);
    pass3(aH, aL, acc);
    lnstats(acc, mean, rs);  __syncthreads();     // P10
    stageW(wvg);                                  // P11
    emit(acc, mean, rs, kf_);
    __syncthreads();
    pass3(aH, aL, acc);                           // P12: v
#pragma unroll
    for (int nt = 0; nt < 16; nt++) {
        u16x4 pv;
#pragma unroll
        for (int r = 0; r < 4; r++) pv[r] = f2h(acc[nt][r]);
        *(u16x4*)(vT + ((size_t)(bn * 256) + nt * 16 + lr) * 1024 + s0 +
                  wave * 16 + lg * 4) = pv;
    }
}

// ---------- K2: causal flash attention, fp16, intra-block split-K ----------
// 512 blocks x 512 threads (8 waves). Block b: bn = b&31, strip = 15-(b>>5)
// (LPT: deep strips dispatch first). Wave-group 0 (waves 0-3) handles
// k-tiles [0, s+1), group 1 (waves 4-7) handles [s+1, 2s+2) with its own
// online softmax; partials merged in LDS at the end (flash-decoding style).
// Uniform loop length s+1 for all waves -> lockstep barriers, ~17 units/CU.
// LDS 138KB: grp0 K/V dbuf @0 (64KB), grp1 K/V dbuf @65536 (64KB; becomes
// o-partial buffer after the loop), P @131072 (8 x 1280B; first 512B become
// the m/l exchange buffer after the loop).
__global__ __launch_bounds__(512) void attn_kernel(
    const u16* __restrict__ qf_, const u16* __restrict__ kf_,
    const u16* __restrict__ vT, const float* __restrict__ g2,
    const float* __restrict__ b2, u16* __restrict__ lnatt) {
    extern __shared__ char smem[];
    const int tid = threadIdx.x;
    const int wave = tid >> 6, lane = tid & 63, lr = lane & 15, lg = lane >> 4;
    const int grp = wave >> 2, w4 = wave & 3;
    const int b = blockIdx.x;
    const int bn = b & 31;
    const int strip = 15 - (b >> 5);
    const int qr0 = strip * 64 + w4 * 16;
    const int ni = strip + 1;                 // iterations per group
    const int ktbase = grp * ni;
    char* myK = smem + grp * 65536;           // 2 x 16KB dbuf
    char* myV = smem + grp * 65536 + 32768;   // 2 x 16KB dbuf
    u16* Pw = (u16*)(smem + 131072 + wave * 1280);   // [16 rows][40 u16]

    // Q fragments (fp16) — both groups load the same rows
    f16x8 qf[8];
    {
        const size_t off = ((size_t)(bn * 1024 + qr0 + lr)) * 256 + lg * 8;
#pragma unroll
        for (int ck = 0; ck < 8; ck++)
            qf[ck] = *(const f16x8*)(qf_ + off + ck * 32);
    }
    f16x8 onesb;   // B-fragment of ones-column (row-sum via MFMA)
    {
        _Float16 v1 = (lr == 0) ? (_Float16)1.0f : (_Float16)0.0f;
#pragma unroll
        for (int q = 0; q < 8; q++) onesb[q] = v1;
    }

    const int srl = lane >> 5, ss = lane & 31;   // K staging: subrow, slot
    const int vdl = lane >> 2, vg = lane & 3;    // V staging: d-local, group
    // stage tile kt into this group's buffer buf: 8 gl_lds16 per wave.
    auto stage = [&](int buf, int kt) {
        const int kv0 = kt << 5;
        char* baseK = myK + buf * 16384;
        char* baseV = myV + buf * 16384;
#pragma unroll
        for (int ii = 0; ii < 4; ii++) {
            int u = w4 * 4 + ii;                   // 0..15, 1KB units
            int r = u * 2 + srl;                   // K row 0..31
            size_t go = (((size_t)((bn << 10) + kv0 + r)) << 8) +
                        (unsigned)((ss ^ (r & 7)) << 3);
            gl_lds16(kf_ + go, baseK + u * 1024);
            int d = u * 16 + vdl;                  // V d 0..255
            size_t gv = (((size_t)((bn << 8) + d)) << 10) + kv0 +
                        (unsigned)((vg ^ ((d >> 1) & 3)) << 3);
            gl_lds16(vT + gv, baseV + u * 1024);
        }
    };

    f32x4 o[16];
#pragma unroll
    for (int i = 0; i < 16; i++) o[i] = (f32x4){0.f, 0.f, 0.f, 0.f};
    f32x4 ol = (f32x4){0.f, 0.f, 0.f, 0.f};
    float m[4] = {-INFINITY, -INFINITY, -INFINITY, -INFINITY};

    stage(0, ktbase);
    __syncthreads();
    for (int it = 0; it < ni; it++) {
        const int cur = it & 1;
        if (it + 1 < ni) stage(cur ^ 1, ktbase + it + 1);
        const int kt = ktbase + it;
        if ((kt << 5) <= qr0 + 15) {
            const char* kb = myK + cur * 16384;
            f32x4 sc0 = (f32x4){0.f, 0.f, 0.f, 0.f};
            f32x4 sc1 = (f32x4){0.f, 0.f, 0.f, 0.f};
            __builtin_amdgcn_s_setprio(1);
#pragma unroll
            for (int ck = 0; ck < 8; ck++) {
                int sw = ((ck * 4 + lg) ^ (lr & 7)) << 4;
                int a0 = lr * 512 + sw;
                f16x8 k0 = *(const f16x8*)(kb + a0);
                f16x8 k1 = *(const f16x8*)(kb + a0 + 8192);
                sc0 = MFMAH(qf[ck], k0, sc0);
                sc1 = MFMAH(qf[ck], k1, sc1);
            }
            __builtin_amdgcn_s_setprio(0);
            float scl[4];
            const int kvb = kt << 5;
#pragma unroll
            for (int r = 0; r < 4; r++) {
                int qi = qr0 + lg * 4 + r;
                float s0v = (kvb + lr > qi) ? -1e30f : sc0[r];
                float s1v = (kvb + 16 + lr > qi) ? -1e30f : sc1[r];
                float tm = red16_max(fmaxf(s0v, s1v));
                float mn = fmaxf(m[r], tm);
                scl[r] = __expf(m[r] - mn);
                m[r] = mn;
                int row = lg * 4 + r;
                Pw[row * 40 + lr] = f2h(__expf(s0v - mn));
                Pw[row * 40 + 16 + lr] = f2h(__expf(s1v - mn));
            }
#pragma unroll
            for (int f = 0; f < 16; f++) {
                f32x4 t = o[f];
                t[0] *= scl[0]; t[1] *= scl[1]; t[2] *= scl[2]; t[3] *= scl[3];
                o[f] = t;
            }
            ol[0] *= scl[0]; ol[1] *= scl[1]; ol[2] *= scl[2]; ol[3] *= scl[3];
            f16x8 pa = *(const f16x8*)((const char*)Pw + lr * 80 + lg * 16);
            const char* vb = myV + cur * 16384;
            __builtin_amdgcn_s_setprio(1);
#pragma unroll
            for (int db = 0; db < 16; db++) {
                int d = db * 16 + lr;
                f16x8 vf = *(const f16x8*)(vb + d * 64 +
                                           ((lg ^ ((lr >> 1) & 3)) << 4));
                o[db] = MFMAH(pa, vf, o[db]);
            }
            ol = MFMAH(pa, onesb, ol);
            __builtin_amdgcn_s_setprio(0);
        }
        __syncthreads();
    }
    // per-group row sums from ones-column (col 0 lanes)
    float lsum[4];
#pragma unroll
    for (int r = 0; r < 4; r++) lsum[r] = __shfl(ol[r], lane & 48, 64);

    // ---- flash-decoding combine: grp1 -> LDS, grp0 merges ----
    char* cb = smem + 65536;                 // 4 pairs x 16KB: [col][row] f32
    float* mlb = (float*)(smem + 131072);    // 64 rows x {m,l} (P region dead)
    if (grp == 1) {
        char* po = cb + w4 * 16384;
#pragma unroll
        for (int f = 0; f < 16; f++)
            *(f32x4*)(po + (f * 16 + lr) * 64 + lg * 16) = o[f];
        if (lr == 0) {
#pragma unroll
            for (int r = 0; r < 4; r++) {
                int row = lg * 4 + r;
                mlb[(w4 * 16 + row) * 2] = m[r];
                mlb[(w4 * 16 + row) * 2 + 1] = lsum[r];
            }
        }
    }
    __syncthreads();
    if (grp == 0) {
        const char* po = cb + w4 * 16384;
        float e0[4], e1[4], linv[4];
#pragma unroll
        for (int r = 0; r < 4; r++) {
            int row = lg * 4 + r;
            float m1 = mlb[(w4 * 16 + row) * 2];
            float l1 = mlb[(w4 * 16 + row) * 2 + 1];
            float ms = fmaxf(m[r], m1);
            e0[r] = __expf(m[r] - ms);
            e1[r] = __expf(m1 - ms);
            linv[r] = 1.f / (lsum[r] * e0[r] + l1 * e1[r]);
        }
#pragma unroll
        for (int f = 0; f < 16; f++) {
            f32x4 o1 = *(const f32x4*)(po + (f * 16 + lr) * 64 + lg * 16);
#pragma unroll
            for (int r = 0; r < 4; r++)
                o[f][r] = (o[f][r] * e0[r] + o1[r] * e1[r]) * linv[r];
        }
        // fused LayerNorm -> bf16
        float gv[16], bv[16];
#pragma unroll
        for (int f = 0; f < 16; f++) {
            gv[f] = g2[f * 16 + lr];
            bv[f] = b2[f * 16 + lr];
        }
#pragma unroll
        for (int r = 0; r < 4; r++) {
            float s1 = 0.f, s2 = 0.f;
#pragma unroll
            for (int f = 0; f < 16; f++) {
                float x = o[f][r];
                s1 += x; s2 += x * x;
            }
            s1 = red16_sum(s1);
            s2 = red16_sum(s2);
            float mean = s1 * (1.f / 256.f);
            float var = s2 * (1.f / 256.f) - mean * mean;
            float rsv = rsqrtf(var + 1e-5f);
            size_t row = (size_t)(bn * 1024 + qr0 + lg * 4 + r) * 256;
#pragma unroll
            for (int f = 0; f < 16; f++)
                lnatt[row + f * 16 + lr] =
                    f2b((o[f][r] - mean) * rsv * gv[f] + bv[f]);
        }
    }
}

// ---------- K3/K4/K5: LDS-staged GEMM, A(MxK) bf16, BT(NxK) bf16 ----------
template <int K, int NB, int MODE>
__global__ __launch_bounds__(512) void gemmB_kernel(
    const u16* __restrict__ A, const u16* __restrict__ BT,
    u16* __restrict__ outb, const u16* __restrict__ vTr,
    float* __restrict__ outf, int ldOut) {
    extern __shared__ char bsm[];
    const int tid = threadIdx.x;
    const int wave = tid >> 6, lane = tid & 63, lr = lane & 15, lg = lane >> 4;
    constexpr int K2 = K * 2;           // bytes per B column
    constexpr int BN = NB * 16;
    constexpr int TILE = BN * K2;
    const int m0 = blockIdx.x * 128 + wave * 16;
    const int n0 = blockIdx.y * BN;
    {
        const char* bsrc = (const char*)(BT + (size_t)n0 * K);
        constexpr int ITER = TILE / (512 * 16);
#pragma unroll
        for (int it = 0; it < ITER; it++) {
            int o = (it * 512 + tid) * 16;
            int col = o / K2;
            int slot = (o % K2) >> 4;
            int src = col * K2 + ((slot ^ (col & 7)) << 4);
            gl_lds16(bsrc + src, bsm + o);
        }
    }
    __syncthreads();
    f32x4 acc[NB];
#pragma unroll
    for (int nb = 0; nb < NB; nb++) acc[nb] = (f32x4){0.f, 0.f, 0.f, 0.f};
    const u16* ap = A + (size_t)(m0 + lr) * K + lg * 8;
#pragma unroll
    for (int kc = 0; kc < K; kc += 32) {
        bf16x8 a = *(const bf16x8*)(ap + kc);
        int ks = (kc >> 3) + lg;
#pragma unroll
        for (int nb = 0; nb < NB; nb++) {
            int c = nb * 16 + lr;
            bf16x8 bv = *(const bf16x8*)(bsm + c * K2 + ((ks ^ (c & 7)) << 4));
            acc[nb] = MFMA(a, bv, acc[nb]);
        }
    }
    const int g = m0 + lg * 4;
    if (MODE == 0) {
#pragma unroll
        for (int nb = 0; nb < NB; nb++)
#pragma unroll
            for (int r = 0; r < 4; r++)
                outb[(size_t)(g + r) * ldOut + n0 + nb * 16 + lr] =
                    f2b(fmaxf(acc[nb][r], 0.f));
    } else if (MODE == 1) {
        int bn = g >> 10, s = g & 1023;
#pragma unroll
        for (int nb = 0; nb < NB; nb++) {
            int dd = n0 + nb * 16 + lr;
            u16x4 vv = *(const u16x4*)(vTr + ((size_t)bn * 256 + dd) * 1024 + s);
#pragma unroll
            for (int r = 0; r < 4; r++)
                outb[(size_t)(g + r) * 256 + dd] = f2b(acc[nb][r] + h2f(vv[r]));
        }
    } else {
        int bn = g >> 10, s = g & 1023;
        int bb = bn >> 3, nn = bn & 7;
#pragma unroll
        for (int nb = 0; nb < NB; nb++) {
            int cc = n0 + nb * 16 + lr;
            *(f32x4*)(outf + (size_t)bb * 524288 + (size_t)cc * 8192 +
                      (size_t)nn * 1024 + s) = acc[nb];
        }
    }
}

extern "C" void kernel_launch(void* const* d_in, const int* in_sizes, int n_in,
                              void* d_out, int out_size, void* d_ws, size_t ws_size,
                              hipStream_t stream) {
    const float* lf    = (const float*)d_in[0];
    const float* hf    = (const float*)d_in[1];
    const float* Win   = (const float*)d_in[2];
    const float* Wkv   = (const float*)d_in[3];
    const float* gamma = (const float*)d_in[4];
    const float* beta  = (const float*)d_in[5];
    const float* g2    = (const float*)d_in[6];
    const float* b2    = (const float*)d_in[7];
    const float* W1    = (const float*)d_in[8];
    const float* W2    = (const float*)d_in[9];
    const float* Wo    = (const float*)d_in[10];
    float* out = (float*)d_out;

    char* w = (char*)d_ws;
    const size_t MB16 = 16777216;
    u16* qf  = (u16*)(w);                        // fp16 q (16.78 MB)
    u16* kf  = (u16*)(w + MB16);                 // fp16 k
    u16* vT  = (u16*)(w + 2 * MB16);             // fp16 v, (BN,256,1024)
    u16* hb  = (u16*)(w + 3 * MB16);             // bf16 FFN hidden (33.55 MB)
    u16* w1T = (u16*)(w + 3 * MB16 + 33554432);
    u16* w2T = w1T + 131072;
    u16* woT = w2T + 131072;
    u16* wfrag = woT + 16384;                    // 6 x 16384 u16
    u16* wqg = wfrag;
    u16* wkg = wfrag + 32768;
    u16* wvg = wfrag + 65536;
    u16* lnatt = qf;   // reuse: q rows consumed before LN write (bf16)
    u16* epib  = kf;   // reuse: k dead after attention (bf16)

    wconv_kernel<<<dim3(1136), dim3(256), 0, stream>>>(W1, W2, Wo, Win, Wkv,
                                                       w1T, w2T, woT, wfrag);
    proj_kernel<<<dim3(8, 32), dim3(512), 131072, stream>>>(
        lf, hf, wqg, wkg, wvg, gamma, beta, qf, kf, vT);
    attn_kernel<<<dim3(512), dim3(512), 141312, stream>>>(qf, kf, vT, g2, b2,
                                                          lnatt);
    gemmB_kernel<256, 8, 0><<<dim3(256, 4), dim3(512), 65536, stream>>>(
        lnatt, w1T, hb, nullptr, nullptr, 512);
    gemmB_kernel<512, 8, 1><<<dim3(256, 2), dim3(512), 131072, stream>>>(
        hb, w2T, epib, vT, nullptr, 256);
    gemmB_kernel<256, 4, 2><<<dim3(256, 1), dim3(512), 32768, stream>>>(
        epib, woT, nullptr, nullptr, out, 64);
}

// Round 12
// 131.814 us; speedup vs baseline: 4.6083x; 1.0248x over previous
//
#include <hip/hip_runtime.h>

typedef short bf16x8 __attribute__((ext_vector_type(8)));
typedef _Float16 f16x8 __attribute__((ext_vector_type(8)));
typedef float f32x4 __attribute__((ext_vector_type(4)));
typedef unsigned short u16;
typedef unsigned short u16x4 __attribute__((ext_vector_type(4)));

#define MFMA(a, b, c) __builtin_amdgcn_mfma_f32_16x16x32_bf16(a, b, c, 0, 0, 0)
#define MFMAH(a, b, c) __builtin_amdgcn_mfma_f32_16x16x32_f16(a, b, c, 0, 0, 0)

// ---------- helpers ----------
__device__ __forceinline__ u16 f2b(float f) {
    union { float f; unsigned u; } x{f};
    unsigned r = (x.u + 0x7FFFu + ((x.u >> 16) & 1u)) >> 16;
    return (u16)r;
}
__device__ __forceinline__ float b2f(u16 h) {
    union { unsigned u; float f; } x{((unsigned)h) << 16};
    return x.f;
}
__device__ __forceinline__ u16 f2h(float f) {
    _Float16 h = (_Float16)f;
    return *reinterpret_cast<u16*>(&h);
}
__device__ __forceinline__ float h2f(u16 h) {
    _Float16 v = *reinterpret_cast<_Float16*>(&h);
    return (float)v;
}
__device__ __forceinline__ float red16_sum(float v) {
#pragma unroll
    for (int m = 1; m < 16; m <<= 1) v += __shfl_xor(v, m, 64);
    return v;
}
__device__ __forceinline__ float red16_max(float v) {
#pragma unroll
    for (int m = 1; m < 16; m <<= 1) v = fmaxf(v, __shfl_xor(v, m, 64));
    return v;
}
__device__ __forceinline__ void gl_lds16(const void* g, void* l) {
    __builtin_amdgcn_global_load_lds(
        (const __attribute__((address_space(1))) unsigned int*)(g),
        (__attribute__((address_space(3))) unsigned int*)(l), 16, 0, 0);
}

// dims: B=4, C=64, N=8, V=32, W=32, D=256 ; BN=32, S=1024, tokens M=32768

// ---------- K0: weight convert: gemm weights + fragment-packed proj weights ----------
__global__ __launch_bounds__(256) void wconv_kernel(
    const float* __restrict__ W1, const float* __restrict__ W2,
    const float* __restrict__ Wo, const float* __restrict__ Win,
    const float* __restrict__ Wkv, u16* __restrict__ w1T,
    u16* __restrict__ w2T, u16* __restrict__ woT, u16* __restrict__ wfrag) {
    int id = blockIdx.x * 256 + threadIdx.x;
    if (id < 131072) {                       // W1: (256,512) -> (512,256)
        int n = id >> 8, k = id & 255;
        w1T[id] = f2b(W1[k * 512 + n]);
    } else if (id < 262144) {                // W2: (512,256) -> (256,512)
        int j = id - 131072;
        int n = j >> 9, k = j & 511;
        w2T[j] = f2b(W2[k * 256 + n]);
    } else if (id < 278528) {                // W_out: (256,64) -> (64,256)
        int j = id - 262144;
        int n = j >> 8, k = j & 255;
        woT[j] = f2b(Wo[k * 64 + n]);
    } else if (id < 290816) {                // fragment-packed proj weights
        int fid = id - 278528;
        int arr = fid >> 11;                 // 0..5
        int e = fid & 2047;
        int ntck = e >> 6, ln = e & 63;
        int lr = ln & 15, lg2 = ln >> 4;
        int nt = ntck >> 1, ck = ntck & 1;
        int d = nt * 16 + lr;
#pragma unroll
        for (int j = 0; j < 8; j++) {
            int c = ck * 32 + lg2 * 8 + j;
            float x;
            if (arr < 2)       x = Win[c * 256 + d];
            else if (arr < 4)  x = Wkv[c * 512 + d];
            else               x = Wkv[c * 512 + 256 + d];
            u16 h = f2b(x);
            u16 v = (arr & 1) ? f2b(x - b2f(h)) : h;
            wfrag[arr * 16384 + e * 8 + j] = v;
        }
    }
}

// ---------- K1: MFMA projection + shared LN (split-bf16 compute, fp16 emit) ----------
#define PJ_AH 0
#define PJ_AL 16384
#define PJ_WREG 32768
#define PJ_WORK 98304
__global__ __launch_bounds__(512, 1) void proj_kernel(
    const float* __restrict__ lf, const float* __restrict__ hf,
    const u16* __restrict__ wqg, const u16* __restrict__ wkg,
    const u16* __restrict__ wvg, const float* __restrict__ gamma,
    const float* __restrict__ beta, u16* __restrict__ qf_,
    u16* __restrict__ kf_, u16* __restrict__ vT) {
    extern __shared__ char sm[];
    const int tid = threadIdx.x;
    const int wave = tid >> 6, lane = tid & 63, lr = lane & 15, lg = lane >> 4;
    const int st = blockIdx.x, bn = blockIdx.y;
    const int b = bn >> 3, n = bn & 7;
    const int s0 = st * 128;
    const size_t baseF = (size_t)b * 524288 + (size_t)n * 1024 + s0;

    float gam[16], bet[16];
#pragma unroll
    for (int nt = 0; nt < 16; nt++) {
        gam[nt] = gamma[nt * 16 + lr];
        bet[nt] = beta[nt * 16 + lr];
    }

    auto stage32 = [&](const float* srcbase, int chalf) {
#pragma unroll
        for (int call = 0; call < 2; call++) {
            int unit = call * 8 + wave;
            int obase = unit << 10;
            int e = unit * 256 + lane * 4;
            int cl = e >> 7, si = e & 127;
            gl_lds16(srcbase + (size_t)(chalf * 32 + cl) * 8192 + si,
                     sm + PJ_WORK + obase);
        }
    };
    auto stageW = [&](const u16* wsrc) {
#pragma unroll
        for (int call = 0; call < 8; call++) {
            int obase = (call * 8 + wave) << 10;
            gl_lds16((const char*)wsrc + obase + lane * 16, sm + PJ_WREG + obase);
        }
    };
    auto buildA = [&](int slotbase) {
        int g = wave >> 1;
        int s = ((wave & 1) << 6) | lane;
        float x[8];
#pragma unroll
        for (int cc = 0; cc < 8; cc++)
            x[cc] = *(const float*)(sm + PJ_WORK + ((g * 8 + cc) << 9) + (s << 2));
        bf16x8 ph, pl;
#pragma unroll
        for (int cc = 0; cc < 8; cc++) {
            u16 h = f2b(x[cc]);
            ph[cc] = (short)h;
            pl[cc] = (short)f2b(x[cc] - b2f(h));
        }
        int slp = (slotbase + g) ^ (s & 7);
        *(bf16x8*)(sm + PJ_AH + (s << 7) + (slp << 4)) = ph;
        *(bf16x8*)(sm + PJ_AL + (s << 7) + (slp << 4)) = pl;
    };
    auto loadA = [&](bf16x8* aH, bf16x8* aL) {
        int tl = wave * 16 + lr;
#pragma unroll
        for (int ck = 0; ck < 2; ck++) {
            int off = (tl << 7) + ((((ck << 2) | lg) ^ (tl & 7)) << 4);
            aH[ck] = *(const bf16x8*)(sm + PJ_AH + off);
            aL[ck] = *(const bf16x8*)(sm + PJ_AL + off);
        }
    };
    auto pass3 = [&](const bf16x8* aH, const bf16x8* aL, f32x4* acc) {
#pragma unroll
        for (int nt = 0; nt < 16; nt++) acc[nt] = (f32x4){0.f, 0.f, 0.f, 0.f};
#pragma unroll
        for (int nt = 0; nt < 16; nt++) {
#pragma unroll
            for (int ck = 0; ck < 2; ck++) {
                int wo = (((nt << 1) | ck) << 10) + (lane << 4);
                bf16x8 bh = *(const bf16x8*)(sm + PJ_WREG + wo);
                bf16x8 bl = *(const bf16x8*)(sm + PJ_WREG + 32768 + wo);
                acc[nt] = MFMA(aH[ck], bh, acc[nt]);
                acc[nt] = MFMA(aL[ck], bh, acc[nt]);
                acc[nt] = MFMA(aH[ck], bl, acc[nt]);
            }
        }
    };
    auto lnstats = [&](const f32x4* acc, float* mean, float* rs) {
#pragma unroll
        for (int r = 0; r < 4; r++) {
            float s1 = 0.f, s2 = 0.f;
#pragma unroll
            for (int nt = 0; nt < 16; nt++) {
                float xv = acc[nt][r];
                s1 += xv; s2 += xv * xv;
            }
            s1 = red16_sum(s1);
            s2 = red16_sum(s2);
            float mn = s1 * (1.f / 256.f);
            float var = s2 * (1.f / 256.f) - mn * mn;
            mean[r] = mn;
            rs[r] = rsqrtf(var + 1e-5f);
        }
    };
    // LN + fp16 emission via per-wave 4KB bounce, 16B-coalesced stores
    auto emit = [&](const f32x4* acc, const float* mean, const float* rs,
                    u16* dst) {
        char* bw = sm + PJ_WORK + wave * 4096;
        const int gtok = bn * 1024 + s0 + wave * 16;
#pragma unroll
        for (int hh = 0; hh < 2; hh++) {
#pragma unroll
            for (int ntl = 0; ntl < 8; ntl++) {
                int nt = hh * 8 + ntl;
#pragma unroll
                for (int r = 0; r < 4; r++) {
                    float y = (acc[nt][r] - mean[r]) * rs[r] * gam[nt] + bet[nt];
                    int tl = lg * 4 + r;
                    int dl = ntl * 16 + lr;
                    int sl = dl >> 3;
                    *(u16*)(bw + tl * 256 + ((sl ^ ((tl >> 2) & 3)) << 4) +
                            (dl & 7) * 2) = f2h(y);
                }
            }
#pragma unroll
            for (int p = 0; p < 4; p++) {
                int row = lane >> 2, slq = (lane & 3) + p * 4;
                bf16x8 v8 = *(const bf16x8*)(bw + row * 256 +
                                             ((slq ^ ((row >> 2) & 3)) << 4));
                *(bf16x8*)(dst + (size_t)(gtok + row) * 256 + hh * 128 +
                           slq * 8) = v8;
            }
        }
    };

    f32x4 acc[16];
    float mean[4], rs[4];
    bf16x8 aH[2], aL[2];

    // ---- lf -> q ----
    stage32(lf + baseF, 0);  __syncthreads();     // P0
    buildA(0);               __syncthreads();     // P1
    stage32(lf + baseF, 1);
    stageW(wqg);             __syncthreads();     // P2
    buildA(4);               __syncthreads();     // P3
    loadA(aH, aL);
    pass3(aH, aL, acc);
    lnstats(acc, mean, rs);  __syncthreads();     // P4
    stageW(wkg);                                  // P5
    emit(acc, mean, rs, qf_);
    __syncthreads();
    // ---- hf -> k, v ----
    stage32(hf + baseF, 0);  __syncthreads();     // P6
    buildA(0);               __syncthreads();     // P7
    stage32(hf + baseF, 1);  __syncthreads();     // P8
    buildA(4);               __syncthreads();     // P9
    loadA(aH, aL);
    pass3(aH, aL, acc);
    lnstats(acc, mean, rs);  __syncthreads();     // P10
    stageW(wvg);                                  // P11
    emit(acc, mean, rs, kf_);
    __syncthreads();
    pass3(aH, aL, acc);                           // P12: v
#pragma unroll
    for (int nt = 0; nt < 16; nt++) {
        u16x4 pv;
#pragma unroll
        for (int r = 0; r < 4; r++) pv[r] = f2h(acc[nt][r]);
        *(u16x4*)(vT + ((size_t)(bn * 256) + nt * 16 + lr) * 1024 + s0 +
                  wave * 16 + lg * 4) = pv;
    }
}

// ---------- K2: causal flash attention, fp16, intra-block split-K + T4 ----------
// 512 blocks x 512 threads (8 waves). Block b: bn = b&31, strip = 15-(b>>5)
// (LPT). Wave-group 0 (waves 0-3): k-tiles [0, s+1); group 1: [s+1, 2s+2);
// partials merged in LDS (flash-decoding). Uniform s+1 iterations.
// T4 schedule per iter: stage(next) -> s_waitcnt vmcnt(8) (next tile's 8
// loads stay IN FLIGHT across the barrier) -> raw s_barrier -> compute(cur).
// Safety: barrier(i) orders all waves' reads of buf[(i+1)&1] (iter i-1)
// before stage(i+1)'s writes land (WAR); per-wave vmcnt(8) before barrier
// completes every wave's tile-i loads (RAW); ni & stage-cond are uniform.
// LDS 138KB: grp0 K/V dbuf @0 (64KB), grp1 @65536 (64KB; o-partial buffer
// after loop), P @131072 (8x1280B; first 512B = m/l exchange after loop).
__global__ __launch_bounds__(512) void attn_kernel(
    const u16* __restrict__ qf_, const u16* __restrict__ kf_,
    const u16* __restrict__ vT, const float* __restrict__ g2,
    const float* __restrict__ b2, u16* __restrict__ lnatt) {
    extern __shared__ char smem[];
    const int tid = threadIdx.x;
    const int wave = tid >> 6, lane = tid & 63, lr = lane & 15, lg = lane >> 4;
    const int grp = wave >> 2, w4 = wave & 3;
    const int b = blockIdx.x;
    const int bn = b & 31;
    const int strip = 15 - (b >> 5);
    const int qr0 = strip * 64 + w4 * 16;
    const int ni = strip + 1;                 // iterations per group
    const int ktbase = grp * ni;
    char* myK = smem + grp * 65536;           // 2 x 16KB dbuf
    char* myV = smem + grp * 65536 + 32768;   // 2 x 16KB dbuf
    u16* Pw = (u16*)(smem + 131072 + wave * 1280);   // [16 rows][40 u16]

    // Q fragments (fp16) — both groups load the same rows
    f16x8 qf[8];
    {
        const size_t off = ((size_t)(bn * 1024 + qr0 + lr)) * 256 + lg * 8;
#pragma unroll
        for (int ck = 0; ck < 8; ck++)
            qf[ck] = *(const f16x8*)(qf_ + off + ck * 32);
    }
    f16x8 onesb;   // B-fragment of ones-column (row-sum via MFMA)
    {
        _Float16 v1 = (lr == 0) ? (_Float16)1.0f : (_Float16)0.0f;
#pragma unroll
        for (int q = 0; q < 8; q++) onesb[q] = v1;
    }

    const int srl = lane >> 5, ss = lane & 31;   // K staging: subrow, slot
    const int vdl = lane >> 2, vg = lane & 3;    // V staging: d-local, group
    // stage tile kt into this group's buffer buf: 8 gl_lds16 per wave.
    auto stage = [&](int buf, int kt) {
        const int kv0 = kt << 5;
        char* baseK = myK + buf * 16384;
        char* baseV = myV + buf * 16384;
#pragma unroll
        for (int ii = 0; ii < 4; ii++) {
            int u = w4 * 4 + ii;                   // 0..15, 1KB units
            int r = u * 2 + srl;                   // K row 0..31
            size_t go = (((size_t)((bn << 10) + kv0 + r)) << 8) +
                        (unsigned)((ss ^ (r & 7)) << 3);
            gl_lds16(kf_ + go, baseK + u * 1024);
            int d = u * 16 + vdl;                  // V d 0..255
            size_t gv = (((size_t)((bn << 8) + d)) << 10) + kv0 +
                        (unsigned)((vg ^ ((d >> 1) & 3)) << 3);
            gl_lds16(vT + gv, baseV + u * 1024);
        }
    };

    f32x4 o[16];
#pragma unroll
    for (int i = 0; i < 16; i++) o[i] = (f32x4){0.f, 0.f, 0.f, 0.f};
    f32x4 ol = (f32x4){0.f, 0.f, 0.f, 0.f};
    float m[4] = {-INFINITY, -INFINITY, -INFINITY, -INFINITY};

    stage(0, ktbase);
    for (int it = 0; it < ni; it++) {
        const int cur = it & 1;
        if (it + 1 < ni) {                     // uniform across block
            stage(cur ^ 1, ktbase + it + 1);
            asm volatile("s_waitcnt vmcnt(8)" ::: "memory");
        } else {
            asm volatile("s_waitcnt vmcnt(0)" ::: "memory");
        }
        __builtin_amdgcn_s_barrier();
        asm volatile("" ::: "memory");
        const int kt = ktbase + it;
        if ((kt << 5) <= qr0 + 15) {
            const char* kb = myK + cur * 16384;
            f32x4 sc0 = (f32x4){0.f, 0.f, 0.f, 0.f};
            f32x4 sc1 = (f32x4){0.f, 0.f, 0.f, 0.f};
            __builtin_amdgcn_s_setprio(1);
#pragma unroll
            for (int ck = 0; ck < 8; ck++) {
                int sw = ((ck * 4 + lg) ^ (lr & 7)) << 4;
                int a0 = lr * 512 + sw;
                f16x8 k0 = *(const f16x8*)(kb + a0);
                f16x8 k1 = *(const f16x8*)(kb + a0 + 8192);
                sc0 = MFMAH(qf[ck], k0, sc0);
                sc1 = MFMAH(qf[ck], k1, sc1);
            }
            __builtin_amdgcn_s_setprio(0);
            float scl[4];
            const int kvb = kt << 5;
#pragma unroll
            for (int r = 0; r < 4; r++) {
                int qi = qr0 + lg * 4 + r;
                float s0v = (kvb + lr > qi) ? -1e30f : sc0[r];
                float s1v = (kvb + 16 + lr > qi) ? -1e30f : sc1[r];
                float tm = red16_max(fmaxf(s0v, s1v));
                float mn = fmaxf(m[r], tm);
                scl[r] = __expf(m[r] - mn);
                m[r] = mn;
                int row = lg * 4 + r;
                Pw[row * 40 + lr] = f2h(__expf(s0v - mn));
                Pw[row * 40 + 16 + lr] = f2h(__expf(s1v - mn));
            }
#pragma unroll
            for (int f = 0; f < 16; f++) {
                f32x4 t = o[f];
                t[0] *= scl[0]; t[1] *= scl[1]; t[2] *= scl[2]; t[3] *= scl[3];
                o[f] = t;
            }
            ol[0] *= scl[0]; ol[1] *= scl[1]; ol[2] *= scl[2]; ol[3] *= scl[3];
            f16x8 pa = *(const f16x8*)((const char*)Pw + lr * 80 + lg * 16);
            const char* vb = myV + cur * 16384;
            __builtin_amdgcn_s_setprio(1);
#pragma unroll
            for (int db = 0; db < 16; db++) {
                int d = db * 16 + lr;
                f16x8 vf = *(const f16x8*)(vb + d * 64 +
                                           ((lg ^ ((lr >> 1) & 3)) << 4));
                o[db] = MFMAH(pa, vf, o[db]);
            }
            ol = MFMAH(pa, onesb, ol);
            __builtin_amdgcn_s_setprio(0);
        }
    }
    __syncthreads();   // loop done: protects combine's reuse of grp1 K/V LDS
    // per-group row sums from ones-column (col 0 lanes)
    float lsum[4];
#pragma unroll
    for (int r = 0; r < 4; r++) lsum[r] = __shfl(ol[r], lane & 48, 64);

    // ---- flash-decoding combine: grp1 -> LDS, grp0 merges ----
    char* cb = smem + 65536;                 // 4 pairs x 16KB: [col][row] f32
    float* mlb = (float*)(smem + 131072);    // 64 rows x {m,l} (P region dead)
    if (grp == 1) {
        char* po = cb + w4 * 16384;
#pragma unroll
        for (int f = 0; f < 16; f++)
            *(f32x4*)(po + (f * 16 + lr) * 64 + lg * 16) = o[f];
        if (lr == 0) {
#pragma unroll
            for (int r = 0; r < 4; r++) {
                int row = lg * 4 + r;
                mlb[(w4 * 16 + row) * 2] = m[r];
                mlb[(w4 * 16 + row) * 2 + 1] = lsum[r];
            }
        }
    }
    __syncthreads();
    if (grp == 0) {
        const char* po = cb + w4 * 16384;
        float e0[4], e1[4], linv[4];
#pragma unroll
        for (int r = 0; r < 4; r++) {
            int row = lg * 4 + r;
            float m1 = mlb[(w4 * 16 + row) * 2];
            float l1 = mlb[(w4 * 16 + row) * 2 + 1];
            float ms = fmaxf(m[r], m1);
            e0[r] = __expf(m[r] - ms);
            e1[r] = __expf(m1 - ms);
            linv[r] = 1.f / (lsum[r] * e0[r] + l1 * e1[r]);
        }
#pragma unroll
        for (int f = 0; f < 16; f++) {
            f32x4 o1 = *(const f32x4*)(po + (f * 16 + lr) * 64 + lg * 16);
#pragma unroll
            for (int r = 0; r < 4; r++)
                o[f][r] = (o[f][r] * e0[r] + o1[r] * e1[r]) * linv[r];
        }
        // fused LayerNorm -> bf16
        float gv[16], bv[16];
#pragma unroll
        for (int f = 0; f < 16; f++) {
            gv[f] = g2[f * 16 + lr];
            bv[f] = b2[f * 16 + lr];
        }
#pragma unroll
        for (int r = 0; r < 4; r++) {
            float s1 = 0.f, s2 = 0.f;
#pragma unroll
            for (int f = 0; f < 16; f++) {
                float x = o[f][r];
                s1 += x; s2 += x * x;
            }
            s1 = red16_sum(s1);
            s2 = red16_sum(s2);
            float mean = s1 * (1.f / 256.f);
            float var = s2 * (1.f / 256.f) - mean * mean;
            float rsv = rsqrtf(var + 1e-5f);
            size_t row = (size_t)(bn * 1024 + qr0 + lg * 4 + r) * 256;
#pragma unroll
            for (int f = 0; f < 16; f++)
                lnatt[row + f * 16 + lr] =
                    f2b((o[f][r] - mean) * rsv * gv[f] + bv[f]);
        }
    }
}

// ---------- K3/K4/K5: LDS-staged GEMM, A(MxK) bf16, BT(NxK) bf16 ----------
template <int K, int NB, int MODE>
__global__ __launch_bounds__(512) void gemmB_kernel(
    const u16* __restrict__ A, const u16* __restrict__ BT,
    u16* __restrict__ outb, const u16* __restrict__ vTr,
    float* __restrict__ outf, int ldOut) {
    extern __shared__ char bsm[];
    const int tid = threadIdx.x;
    const int wave = tid >> 6, lane = tid & 63, lr = lane & 15, lg = lane >> 4;
    constexpr int K2 = K * 2;           // bytes per B column
    constexpr int BN = NB * 16;
    constexpr int TILE = BN * K2;
    const int m0 = blockIdx.x * 128 + wave * 16;
    const int n0 = blockIdx.y * BN;
    {
        const char* bsrc = (const char*)(BT + (size_t)n0 * K);
        constexpr int ITER = TILE / (512 * 16);
#pragma unroll
        for (int it = 0; it < ITER; it++) {
            int o = (it * 512 + tid) * 16;
            int col = o / K2;
            int slot = (o % K2) >> 4;
            int src = col * K2 + ((slot ^ (col & 7)) << 4);
            gl_lds16(bsrc + src, bsm + o);
        }
    }
    __syncthreads();
    f32x4 acc[NB];
#pragma unroll
    for (int nb = 0; nb < NB; nb++) acc[nb] = (f32x4){0.f, 0.f, 0.f, 0.f};
    const u16* ap = A + (size_t)(m0 + lr) * K + lg * 8;
#pragma unroll
    for (int kc = 0; kc < K; kc += 32) {
        bf16x8 a = *(const bf16x8*)(ap + kc);
        int ks = (kc >> 3) + lg;
#pragma unroll
        for (int nb = 0; nb < NB; nb++) {
            int c = nb * 16 + lr;
            bf16x8 bv = *(const bf16x8*)(bsm + c * K2 + ((ks ^ (c & 7)) << 4));
            acc[nb] = MFMA(a, bv, acc[nb]);
        }
    }
    const int g = m0 + lg * 4;
    if (MODE == 0) {
#pragma unroll
        for (int nb = 0; nb < NB; nb++)
#pragma unroll
            for (int r = 0; r < 4; r++)
                outb[(size_t)(g + r) * ldOut + n0 + nb * 16 + lr] =
                    f2b(fmaxf(acc[nb][r], 0.f));
    } else if (MODE == 1) {
        int bn = g >> 10, s = g & 1023;
#pragma unroll
        for (int nb = 0; nb < NB; nb++) {
            int dd = n0 + nb * 16 + lr;
            u16x4 vv = *(const u16x4*)(vTr + ((size_t)bn * 256 + dd) * 1024 + s);
#pragma unroll
            for (int r = 0; r < 4; r++)
                outb[(size_t)(g + r) * 256 + dd] = f2b(acc[nb][r] + h2f(vv[r]));
        }
    } else {
        int bn = g >> 10, s = g & 1023;
        int bb = bn >> 3, nn = bn & 7;
#pragma unroll
        for (int nb = 0; nb < NB; nb++) {
            int cc = n0 + nb * 16 + lr;
            *(f32x4*)(outf + (size_t)bb * 524288 + (size_t)cc * 8192 +
                      (size_t)nn * 1024 + s) = acc[nb];
        }
    }
}

extern "C" void kernel_launch(void* const* d_in, const int* in_sizes, int n_in,
                              void* d_out, int out_size, void* d_ws, size_t ws_size,
                              hipStream_t stream) {
    const float* lf    = (const float*)d_in[0];
    const float* hf    = (const float*)d_in[1];
    const float* Win   = (const float*)d_in[2];
    const float* Wkv   = (const float*)d_in[3];
    const float* gamma = (const float*)d_in[4];
    const float* beta  = (const float*)d_in[5];
    const float* g2    = (const float*)d_in[6];
    const float* b2    = (const float*)d_in[7];
    const float* W1    = (const float*)d_in[8];
    const float* W2    = (const float*)d_in[9];
    const float* Wo    = (const float*)d_in[10];
    float* out = (float*)d_out;

    char* w = (char*)d_ws;
    const size_t MB16 = 16777216;
    u16* qf  = (u16*)(w);                        // fp16 q (16.78 MB)
    u16* kf  = (u16*)(w + MB16);                 // fp16 k
    u16* vT  = (u16*)(w + 2 * MB16);             // fp16 v, (BN,256,1024)
    u16* hb  = (u16*)(w + 3 * MB16);             // bf16 FFN hidden (33.55 MB)
    u16* w1T = (u16*)(w + 3 * MB16 + 33554432);
    u16* w2T = w1T + 131072;
    u16* woT = w2T + 131072;
    u16* wfrag = woT + 16384;                    // 6 x 16384 u16
    u16* wqg = wfrag;
    u16* wkg = wfrag + 32768;
    u16* wvg = wfrag + 65536;
    u16* lnatt = qf;   // reuse: q rows consumed before LN write (bf16)
    u16* epib  = kf;   // reuse: k dead after attention (bf16)

    wconv_kernel<<<dim3(1136), dim3(256), 0, stream>>>(W1, W2, Wo, Win, Wkv,
                                                       w1T, w2T, woT, wfrag);
    proj_kernel<<<dim3(8, 32), dim3(512), 131072, stream>>>(
        lf, hf, wqg, wkg, wvg, gamma, beta, qf, kf, vT);
    attn_kernel<<<dim3(512), dim3(512), 141312, stream>>>(qf, kf, vT, g2, b2,
                                                          lnatt);
    gemmB_kernel<256, 8, 0><<<dim3(256, 4), dim3(512), 65536, stream>>>(
        lnatt, w1T, hb, nullptr, nullptr, 512);
    gemmB_kernel<512, 8, 1><<<dim3(256, 2), dim3(512), 131072, stream>>>(
        hb, w2T, epib, vT, nullptr, 256);
    gemmB_kernel<256, 4, 2><<<dim3(256, 1), dim3(512), 32768, stream>>>(
        epib, woT, nullptr, nullptr, out, 64);
}

// Round 13
// 125.869 us; speedup vs baseline: 4.8260x; 1.0472x over previous
//
#include <hip/hip_runtime.h>

typedef short bf16x8 __attribute__((ext_vector_type(8)));
typedef _Float16 f16x8 __attribute__((ext_vector_type(8)));
typedef float f32x4 __attribute__((ext_vector_type(4)));
typedef unsigned short u16;
typedef unsigned short u16x4 __attribute__((ext_vector_type(4)));

#define MFMA(a, b, c) __builtin_amdgcn_mfma_f32_16x16x32_bf16(a, b, c, 0, 0, 0)
#define MFMAH(a, b, c) __builtin_amdgcn_mfma_f32_16x16x32_f16(a, b, c, 0, 0, 0)

// ---------- helpers ----------
__device__ __forceinline__ u16 f2b(float f) {
    union { float f; unsigned u; } x{f};
    unsigned r = (x.u + 0x7FFFu + ((x.u >> 16) & 1u)) >> 16;
    return (u16)r;
}
__device__ __forceinline__ float b2f(u16 h) {
    union { unsigned u; float f; } x{((unsigned)h) << 16};
    return x.f;
}
__device__ __forceinline__ u16 f2h(float f) {
    _Float16 h = (_Float16)f;
    return *reinterpret_cast<u16*>(&h);
}
__device__ __forceinline__ float h2f(u16 h) {
    _Float16 v = *reinterpret_cast<_Float16*>(&h);
    return (float)v;
}
__device__ __forceinline__ float red16_sum(float v) {
#pragma unroll
    for (int m = 1; m < 16; m <<= 1) v += __shfl_xor(v, m, 64);
    return v;
}
__device__ __forceinline__ float red16_max(float v) {
#pragma unroll
    for (int m = 1; m < 16; m <<= 1) v = fmaxf(v, __shfl_xor(v, m, 64));
    return v;
}
__device__ __forceinline__ void gl_lds16(const void* g, void* l) {
    __builtin_amdgcn_global_load_lds(
        (const __attribute__((address_space(1))) unsigned int*)(g),
        (__attribute__((address_space(3))) unsigned int*)(l), 16, 0, 0);
}

// dims: B=4, C=64, N=8, V=32, W=32, D=256 ; BN=32, S=1024, tokens M=32768

// ---------- K0: weight convert: gemm weights + fragment-packed proj weights ----------
// wfrag: 3 arrays x 16384 u16 (32KB each): wq,wk,wv fp16,
// layout [ntck 0..31][lane 0..63][8].
__global__ __launch_bounds__(256) void wconv_kernel(
    const float* __restrict__ W1, const float* __restrict__ W2,
    const float* __restrict__ Wo, const float* __restrict__ Win,
    const float* __restrict__ Wkv, u16* __restrict__ w1T,
    u16* __restrict__ w2T, u16* __restrict__ woT, u16* __restrict__ wfrag) {
    int id = blockIdx.x * 256 + threadIdx.x;
    if (id < 131072) {                       // W1: (256,512) -> (512,256)
        int n = id >> 8, k = id & 255;
        w1T[id] = f2b(W1[k * 512 + n]);
    } else if (id < 262144) {                // W2: (512,256) -> (256,512)
        int j = id - 131072;
        int n = j >> 9, k = j & 511;
        w2T[j] = f2b(W2[k * 256 + n]);
    } else if (id < 278528) {                // W_out: (256,64) -> (64,256)
        int j = id - 262144;
        int n = j >> 8, k = j & 255;
        woT[j] = f2b(Wo[k * 64 + n]);
    } else if (id < 284672) {                // fragment-packed proj weights (fp16)
        int fid = id - 278528;
        int arr = fid >> 11;                 // 0..2 : q, k, v
        int e = fid & 2047;
        int ntck = e >> 6, ln = e & 63;
        int lr = ln & 15, lg2 = ln >> 4;
        int nt = ntck >> 1, ck = ntck & 1;
        int d = nt * 16 + lr;
#pragma unroll
        for (int j = 0; j < 8; j++) {
            int c = ck * 32 + lg2 * 8 + j;
            float x;
            if (arr == 0)      x = Win[c * 256 + d];
            else if (arr == 1) x = Wkv[c * 512 + d];
            else               x = Wkv[c * 512 + 256 + d];
            wfrag[arr * 16384 + e * 8 + j] = f2h(x);
        }
    }
}

// ---------- K1: MFMA projection + shared LN (fp16 single-pass) ----------
// grid (8 st, 32 bn), 512 threads = 8 waves; each wave owns 16 tokens.
// LDS 80KB: A 0..16K (fp16 token-major fragments, XOR-slot swizzle);
// WREG 16K..48K (fp16 weight frags); WORK 48K..80K (16KB fp32 staging /
// 8x4KB emit bounce).
#define PJ_A 0
#define PJ_WREG 16384
#define PJ_WORK 49152
__global__ __launch_bounds__(512, 1) void proj_kernel(
    const float* __restrict__ lf, const float* __restrict__ hf,
    const u16* __restrict__ wqg, const u16* __restrict__ wkg,
    const u16* __restrict__ wvg, const float* __restrict__ gamma,
    const float* __restrict__ beta, u16* __restrict__ qf_,
    u16* __restrict__ kf_, u16* __restrict__ vT) {
    extern __shared__ char sm[];
    const int tid = threadIdx.x;
    const int wave = tid >> 6, lane = tid & 63, lr = lane & 15, lg = lane >> 4;
    const int st = blockIdx.x, bn = blockIdx.y;
    const int b = bn >> 3, n = bn & 7;
    const int s0 = st * 128;
    const size_t baseF = (size_t)b * 524288 + (size_t)n * 1024 + s0;

    float gam[16], bet[16];
#pragma unroll
    for (int nt = 0; nt < 16; nt++) {
        gam[nt] = gamma[nt * 16 + lr];
        bet[nt] = beta[nt * 16 + lr];
    }

    // stage 32 c-rows x 128 s (16KB fp32) into WORK: [c_local][512B]
    auto stage32 = [&](const float* srcbase, int chalf) {
#pragma unroll
        for (int call = 0; call < 2; call++) {
            int unit = call * 8 + wave;                // 0..15, 1KB each
            int obase = unit << 10;
            int e = unit * 256 + lane * 4;
            int cl = e >> 7, si = e & 127;             // cl 0..31
            gl_lds16(srcbase + (size_t)(chalf * 32 + cl) * 8192 + si,
                     sm + PJ_WORK + obase);
        }
    };
    // stage 32KB of fp16 fragment-packed weights into WREG
    auto stageW = [&](const u16* wsrc) {
#pragma unroll
        for (int call = 0; call < 4; call++) {
            int obase = (call * 8 + wave) << 10;       // 0..31KB
            gl_lds16((const char*)wsrc + obase + lane * 16, sm + PJ_WREG + obase);
        }
    };
    // transpose+convert WORK fp32 -> A fp16, logical slots slotbase..+3
    auto buildA = [&](int slotbase) {
        int g = wave >> 1;                             // 0..3
        int s = ((wave & 1) << 6) | lane;              // token 0..127
        float x[8];
#pragma unroll
        for (int cc = 0; cc < 8; cc++)
            x[cc] = *(const float*)(sm + PJ_WORK + ((g * 8 + cc) << 9) + (s << 2));
        f16x8 ph;
#pragma unroll
        for (int cc = 0; cc < 8; cc++) ph[cc] = (_Float16)x[cc];
        int slp = (slotbase + g) ^ (s & 7);
        *(f16x8*)(sm + PJ_A + (s << 7) + (slp << 4)) = ph;
    };
    // load this wave's A fragments (2 k-chunks)
    auto loadA = [&](f16x8* aF) {
        int tl = wave * 16 + lr;
#pragma unroll
        for (int ck = 0; ck < 2; ck++) {
            int off = (tl << 7) + ((((ck << 2) | lg) ^ (tl & 7)) << 4);
            aF[ck] = *(const f16x8*)(sm + PJ_A + off);
        }
    };
    // single-pass fp16 MFMA over K=64
    auto pass1 = [&](const f16x8* aF, f32x4* acc) {
#pragma unroll
        for (int nt = 0; nt < 16; nt++) acc[nt] = (f32x4){0.f, 0.f, 0.f, 0.f};
#pragma unroll
        for (int nt = 0; nt < 16; nt++) {
#pragma unroll
            for (int ck = 0; ck < 2; ck++) {
                int wo = (((nt << 1) | ck) << 10) + (lane << 4);
                f16x8 bh = *(const f16x8*)(sm + PJ_WREG + wo);
                acc[nt] = MFMAH(aF[ck], bh, acc[nt]);
            }
        }
    };
    auto lnstats = [&](const f32x4* acc, float* mean, float* rs) {
#pragma unroll
        for (int r = 0; r < 4; r++) {
            float s1 = 0.f, s2 = 0.f;
#pragma unroll
            for (int nt = 0; nt < 16; nt++) {
                float xv = acc[nt][r];
                s1 += xv; s2 += xv * xv;
            }
            s1 = red16_sum(s1);
            s2 = red16_sum(s2);
            float mn = s1 * (1.f / 256.f);
            float var = s2 * (1.f / 256.f) - mn * mn;
            mean[r] = mn;
            rs[r] = rsqrtf(var + 1e-5f);
        }
    };
    // LN + fp16 emission via per-wave 4KB bounce, 16B-coalesced stores
    auto emit = [&](const f32x4* acc, const float* mean, const float* rs,
                    u16* dst) {
        char* bw = sm + PJ_WORK + wave * 4096;
        const int gtok = bn * 1024 + s0 + wave * 16;
#pragma unroll
        for (int hh = 0; hh < 2; hh++) {
#pragma unroll
            for (int ntl = 0; ntl < 8; ntl++) {
                int nt = hh * 8 + ntl;
#pragma unroll
                for (int r = 0; r < 4; r++) {
                    float y = (acc[nt][r] - mean[r]) * rs[r] * gam[nt] + bet[nt];
                    int tl = lg * 4 + r;
                    int dl = ntl * 16 + lr;
                    int sl = dl >> 3;
                    *(u16*)(bw + tl * 256 + ((sl ^ ((tl >> 2) & 3)) << 4) +
                            (dl & 7) * 2) = f2h(y);
                }
            }
#pragma unroll
            for (int p = 0; p < 4; p++) {
                int row = lane >> 2, slq = (lane & 3) + p * 4;
                bf16x8 v8 = *(const bf16x8*)(bw + row * 256 +
                                             ((slq ^ ((row >> 2) & 3)) << 4));
                *(bf16x8*)(dst + (size_t)(gtok + row) * 256 + hh * 128 +
                           slq * 8) = v8;
            }
        }
    };

    f32x4 acc[16];
    float mean[4], rs[4];
    f16x8 aF[2];

    // ---- lf -> q ----
    stage32(lf + baseF, 0);  __syncthreads();     // P0
    buildA(0);               __syncthreads();     // P1
    stage32(lf + baseF, 1);
    stageW(wqg);             __syncthreads();     // P2
    buildA(4);               __syncthreads();     // P3
    loadA(aF);
    pass1(aF, acc);
    lnstats(acc, mean, rs);  __syncthreads();     // P4 (all done reading WREG)
    stageW(wkg);                                  // P5: overwrite WREG w/ k
    emit(acc, mean, rs, qf_);
    __syncthreads();                              // drains stageW + emit
    // ---- hf -> k, v ----
    stage32(hf + baseF, 0);  __syncthreads();     // P6
    buildA(0);               __syncthreads();     // P7
    stage32(hf + baseF, 1);  __syncthreads();     // P8
    buildA(4);               __syncthreads();     // P9
    loadA(aF);
    pass1(aF, acc);
    lnstats(acc, mean, rs);  __syncthreads();     // P10 (done reading WREG k)
    stageW(wvg);                                  // P11: overwrite WREG w/ v
    emit(acc, mean, rs, kf_);
    __syncthreads();                              // drains stageW + emit
    pass1(aF, acc);                               // P12: v (same hf A-frags)
#pragma unroll
    for (int nt = 0; nt < 16; nt++) {
        u16x4 pv;
#pragma unroll
        for (int r = 0; r < 4; r++) pv[r] = f2h(acc[nt][r]);
        *(u16x4*)(vT + ((size_t)(bn * 256) + nt * 16 + lr) * 1024 + s0 +
                  wave * 16 + lg * 4) = pv;
    }
}

// ---------- K2: causal flash attention, fp16, intra-block split-K + T4 ----------
// (unchanged from R12 — 57us, deterministic, passing)
__global__ __launch_bounds__(512) void attn_kernel(
    const u16* __restrict__ qf_, const u16* __restrict__ kf_,
    const u16* __restrict__ vT, const float* __restrict__ g2,
    const float* __restrict__ b2, u16* __restrict__ lnatt) {
    extern __shared__ char smem[];
    const int tid = threadIdx.x;
    const int wave = tid >> 6, lane = tid & 63, lr = lane & 15, lg = lane >> 4;
    const int grp = wave >> 2, w4 = wave & 3;
    const int b = blockIdx.x;
    const int bn = b & 31;
    const int strip = 15 - (b >> 5);
    const int qr0 = strip * 64 + w4 * 16;
    const int ni = strip + 1;                 // iterations per group
    const int ktbase = grp * ni;
    char* myK = smem + grp * 65536;           // 2 x 16KB dbuf
    char* myV = smem + grp * 65536 + 32768;   // 2 x 16KB dbuf
    u16* Pw = (u16*)(smem + 131072 + wave * 1280);   // [16 rows][40 u16]

    f16x8 qf[8];
    {
        const size_t off = ((size_t)(bn * 1024 + qr0 + lr)) * 256 + lg * 8;
#pragma unroll
        for (int ck = 0; ck < 8; ck++)
            qf[ck] = *(const f16x8*)(qf_ + off + ck * 32);
    }
    f16x8 onesb;   // B-fragment of ones-column (row-sum via MFMA)
    {
        _Float16 v1 = (lr == 0) ? (_Float16)1.0f : (_Float16)0.0f;
#pragma unroll
        for (int q = 0; q < 8; q++) onesb[q] = v1;
    }

    const int srl = lane >> 5, ss = lane & 31;   // K staging: subrow, slot
    const int vdl = lane >> 2, vg = lane & 3;    // V staging: d-local, group
    auto stage = [&](int buf, int kt) {
        const int kv0 = kt << 5;
        char* baseK = myK + buf * 16384;
        char* baseV = myV + buf * 16384;
#pragma unroll
        for (int ii = 0; ii < 4; ii++) {
            int u = w4 * 4 + ii;                   // 0..15, 1KB units
            int r = u * 2 + srl;                   // K row 0..31
            size_t go = (((size_t)((bn << 10) + kv0 + r)) << 8) +
                        (unsigned)((ss ^ (r & 7)) << 3);
            gl_lds16(kf_ + go, baseK + u * 1024);
            int d = u * 16 + vdl;                  // V d 0..255
            size_t gv = (((size_t)((bn << 8) + d)) << 10) + kv0 +
                        (unsigned)((vg ^ ((d >> 1) & 3)) << 3);
            gl_lds16(vT + gv, baseV + u * 1024);
        }
    };

    f32x4 o[16];
#pragma unroll
    for (int i = 0; i < 16; i++) o[i] = (f32x4){0.f, 0.f, 0.f, 0.f};
    f32x4 ol = (f32x4){0.f, 0.f, 0.f, 0.f};
    float m[4] = {-INFINITY, -INFINITY, -INFINITY, -INFINITY};

    stage(0, ktbase);
    for (int it = 0; it < ni; it++) {
        const int cur = it & 1;
        if (it + 1 < ni) {                     // uniform across block
            stage(cur ^ 1, ktbase + it + 1);
            asm volatile("s_waitcnt vmcnt(8)" ::: "memory");
        } else {
            asm volatile("s_waitcnt vmcnt(0)" ::: "memory");
        }
        __builtin_amdgcn_s_barrier();
        asm volatile("" ::: "memory");
        const int kt = ktbase + it;
        if ((kt << 5) <= qr0 + 15) {
            const char* kb = myK + cur * 16384;
            f32x4 sc0 = (f32x4){0.f, 0.f, 0.f, 0.f};
            f32x4 sc1 = (f32x4){0.f, 0.f, 0.f, 0.f};
            __builtin_amdgcn_s_setprio(1);
#pragma unroll
            for (int ck = 0; ck < 8; ck++) {
                int sw = ((ck * 4 + lg) ^ (lr & 7)) << 4;
                int a0 = lr * 512 + sw;
                f16x8 k0 = *(const f16x8*)(kb + a0);
                f16x8 k1 = *(const f16x8*)(kb + a0 + 8192);
                sc0 = MFMAH(qf[ck], k0, sc0);
                sc1 = MFMAH(qf[ck], k1, sc1);
            }
            __builtin_amdgcn_s_setprio(0);
            float scl[4];
            const int kvb = kt << 5;
#pragma unroll
            for (int r = 0; r < 4; r++) {
                int qi = qr0 + lg * 4 + r;
                float s0v = (kvb + lr > qi) ? -1e30f : sc0[r];
                float s1v = (kvb + 16 + lr > qi) ? -1e30f : sc1[r];
                float tm = red16_max(fmaxf(s0v, s1v));
                float mn = fmaxf(m[r], tm);
                scl[r] = __expf(m[r] - mn);
                m[r] = mn;
                int row = lg * 4 + r;
                Pw[row * 40 + lr] = f2h(__expf(s0v - mn));
                Pw[row * 40 + 16 + lr] = f2h(__expf(s1v - mn));
            }
#pragma unroll
            for (int f = 0; f < 16; f++) {
                f32x4 t = o[f];
                t[0] *= scl[0]; t[1] *= scl[1]; t[2] *= scl[2]; t[3] *= scl[3];
                o[f] = t;
            }
            ol[0] *= scl[0]; ol[1] *= scl[1]; ol[2] *= scl[2]; ol[3] *= scl[3];
            f16x8 pa = *(const f16x8*)((const char*)Pw + lr * 80 + lg * 16);
            const char* vb = myV + cur * 16384;
            __builtin_amdgcn_s_setprio(1);
#pragma unroll
            for (int db = 0; db < 16; db++) {
                int d = db * 16 + lr;
                f16x8 vf = *(const f16x8*)(vb + d * 64 +
                                           ((lg ^ ((lr >> 1) & 3)) << 4));
                o[db] = MFMAH(pa, vf, o[db]);
            }
            ol = MFMAH(pa, onesb, ol);
            __builtin_amdgcn_s_setprio(0);
        }
    }
    __syncthreads();   // loop done: protects combine's reuse of grp1 K/V LDS
    float lsum[4];
#pragma unroll
    for (int r = 0; r < 4; r++) lsum[r] = __shfl(ol[r], lane & 48, 64);

    // ---- flash-decoding combine: grp1 -> LDS, grp0 merges ----
    char* cb = smem + 65536;                 // 4 pairs x 16KB: [col][row] f32
    float* mlb = (float*)(smem + 131072);    // 64 rows x {m,l} (P region dead)
    if (grp == 1) {
        char* po = cb + w4 * 16384;
#pragma unroll
        for (int f = 0; f < 16; f++)
            *(f32x4*)(po + (f * 16 + lr) * 64 + lg * 16) = o[f];
        if (lr == 0) {
#pragma unroll
            for (int r = 0; r < 4; r++) {
                int row = lg * 4 + r;
                mlb[(w4 * 16 + row) * 2] = m[r];
                mlb[(w4 * 16 + row) * 2 + 1] = lsum[r];
            }
        }
    }
    __syncthreads();
    if (grp == 0) {
        const char* po = cb + w4 * 16384;
        float e0[4], e1[4], linv[4];
#pragma unroll
        for (int r = 0; r < 4; r++) {
            int row = lg * 4 + r;
            float m1 = mlb[(w4 * 16 + row) * 2];
            float l1 = mlb[(w4 * 16 + row) * 2 + 1];
            float ms = fmaxf(m[r], m1);
            e0[r] = __expf(m[r] - ms);
            e1[r] = __expf(m1 - ms);
            linv[r] = 1.f / (lsum[r] * e0[r] + l1 * e1[r]);
        }
#pragma unroll
        for (int f = 0; f < 16; f++) {
            f32x4 o1 = *(const f32x4*)(po + (f * 16 + lr) * 64 + lg * 16);
#pragma unroll
            for (int r = 0; r < 4; r++)
                o[f][r] = (o[f][r] * e0[r] + o1[r] * e1[r]) * linv[r];
        }
        float gv[16], bv[16];
#pragma unroll
        for (int f = 0; f < 16; f++) {
            gv[f] = g2[f * 16 + lr];
            bv[f] = b2[f * 16 + lr];
        }
#pragma unroll
        for (int r = 0; r < 4; r++) {
            float s1 = 0.f, s2 = 0.f;
#pragma unroll
            for (int f = 0; f < 16; f++) {
                float x = o[f][r];
                s1 += x; s2 += x * x;
            }
            s1 = red16_sum(s1);
            s2 = red16_sum(s2);
            float mean = s1 * (1.f / 256.f);
            float var = s2 * (1.f / 256.f) - mean * mean;
            float rsv = rsqrtf(var + 1e-5f);
            size_t row = (size_t)(bn * 1024 + qr0 + lg * 4 + r) * 256;
#pragma unroll
            for (int f = 0; f < 16; f++)
                lnatt[row + f * 16 + lr] =
                    f2b((o[f][r] - mean) * rsv * gv[f] + bv[f]);
        }
    }
}

// ---------- K3/K4/K5: LDS-staged GEMM, A(MxK) bf16, BT(NxK) bf16 ----------
template <int K, int NB, int MODE>
__global__ __launch_bounds__(512) void gemmB_kernel(
    const u16* __restrict__ A, const u16* __restrict__ BT,
    u16* __restrict__ outb, const u16* __restrict__ vTr,
    float* __restrict__ outf, int ldOut) {
    extern __shared__ char bsm[];
    const int tid = threadIdx.x;
    const int wave = tid >> 6, lane = tid & 63, lr = lane & 15, lg = lane >> 4;
    constexpr int K2 = K * 2;           // bytes per B column
    constexpr int BN = NB * 16;
    constexpr int TILE = BN * K2;
    const int m0 = blockIdx.x * 128 + wave * 16;
    const int n0 = blockIdx.y * BN;
    {
        const char* bsrc = (const char*)(BT + (size_t)n0 * K);
        constexpr int ITER = TILE / (512 * 16);
#pragma unroll
        for (int it = 0; it < ITER; it++) {
            int o = (it * 512 + tid) * 16;
            int col = o / K2;
            int slot = (o % K2) >> 4;
            int src = col * K2 + ((slot ^ (col & 7)) << 4);
            gl_lds16(bsrc + src, bsm + o);
        }
    }
    __syncthreads();
    f32x4 acc[NB];
#pragma unroll
    for (int nb = 0; nb < NB; nb++) acc[nb] = (f32x4){0.f, 0.f, 0.f, 0.f};
    const u16* ap = A + (size_t)(m0 + lr) * K + lg * 8;
#pragma unroll
    for (int kc = 0; kc < K; kc += 32) {
        bf16x8 a = *(const bf16x8*)(ap + kc);
        int ks = (kc >> 3) + lg;
#pragma unroll
        for (int nb = 0; nb < NB; nb++) {
            int c = nb * 16 + lr;
            bf16x8 bv = *(const bf16x8*)(bsm + c * K2 + ((ks ^ (c & 7)) << 4));
            acc[nb] = MFMA(a, bv, acc[nb]);
        }
    }
    const int g = m0 + lg * 4;
    if (MODE == 0) {
#pragma unroll
        for (int nb = 0; nb < NB; nb++)
#pragma unroll
            for (int r = 0; r < 4; r++)
                outb[(size_t)(g + r) * ldOut + n0 + nb * 16 + lr] =
                    f2b(fmaxf(acc[nb][r], 0.f));
    } else if (MODE == 1) {
        int bn = g >> 10, s = g & 1023;
#pragma unroll
        for (int nb = 0; nb < NB; nb++) {
            int dd = n0 + nb * 16 + lr;
            u16x4 vv = *(const u16x4*)(vTr + ((size_t)bn * 256 + dd) * 1024 + s);
#pragma unroll
            for (int r = 0; r < 4; r++)
                outb[(size_t)(g + r) * 256 + dd] = f2b(acc[nb][r] + h2f(vv[r]));
        }
    } else {
        int bn = g >> 10, s = g & 1023;
        int bb = bn >> 3, nn = bn & 7;
#pragma unroll
        for (int nb = 0; nb < NB; nb++) {
            int cc = n0 + nb * 16 + lr;
            *(f32x4*)(outf + (size_t)bb * 524288 + (size_t)cc * 8192 +
                      (size_t)nn * 1024 + s) = acc[nb];
        }
    }
}

extern "C" void kernel_launch(void* const* d_in, const int* in_sizes, int n_in,
                              void* d_out, int out_size, void* d_ws, size_t ws_size,
                              hipStream_t stream) {
    const float* lf    = (const float*)d_in[0];
    const float* hf    = (const float*)d_in[1];
    const float* Win   = (const float*)d_in[2];
    const float* Wkv   = (const float*)d_in[3];
    const float* gamma = (const float*)d_in[4];
    const float* beta  = (const float*)d_in[5];
    const float* g2    = (const float*)d_in[6];
    const float* b2    = (const float*)d_in[7];
    const float* W1    = (const float*)d_in[8];
    const float* W2    = (const float*)d_in[9];
    const float* Wo    = (const float*)d_in[10];
    float* out = (float*)d_out;

    char* w = (char*)d_ws;
    const size_t MB16 = 16777216;
    u16* qf  = (u16*)(w);                        // fp16 q (16.78 MB)
    u16* kf  = (u16*)(w + MB16);                 // fp16 k
    u16* vT  = (u16*)(w + 2 * MB16);             // fp16 v, (BN,256,1024)
    u16* hb  = (u16*)(w + 3 * MB16);             // bf16 FFN hidden (33.55 MB)
    u16* w1T = (u16*)(w + 3 * MB16 + 33554432);
    u16* w2T = w1T + 131072;
    u16* woT = w2T + 131072;
    u16* wfrag = woT + 16384;                    // 3 x 16384 u16 (fp16)
    u16* wqg = wfrag;
    u16* wkg = wfrag + 16384;
    u16* wvg = wfrag + 32768;
    u16* lnatt = qf;   // reuse: q rows consumed before LN write (bf16)
    u16* epib  = kf;   // reuse: k dead after attention (bf16)

    wconv_kernel<<<dim3(1136), dim3(256), 0, stream>>>(W1, W2, Wo, Win, Wkv,
                                                       w1T, w2T, woT, wfrag);
    proj_kernel<<<dim3(8, 32), dim3(512), 81920, stream>>>(
        lf, hf, wqg, wkg, wvg, gamma, beta, qf, kf, vT);
    attn_kernel<<<dim3(512), dim3(512), 141312, stream>>>(qf, kf, vT, g2, b2,
                                                          lnatt);
    gemmB_kernel<256, 8, 0><<<dim3(256, 4), dim3(512), 65536, stream>>>(
        lnatt, w1T, hb, nullptr, nullptr, 512);
    gemmB_kernel<512, 8, 1><<<dim3(256, 2), dim3(512), 131072, stream>>>(
        hb, w2T, epib, vT, nullptr, 256);
    gemmB_kernel<256, 4, 2><<<dim3(256, 1), dim3(512), 32768, stream>>>(
        epib, woT, nullptr, nullptr, out, 64);
}